// Round 13
// baseline (799.427 us; speedup 1.0000x reference)
//
#include <hip/hip_runtime.h>
#include <math.h>

// ---------------------------------------------------------------------------
// MambaPredictor forward. R12 fix: stack-zero coverage 2048->3072 (grid 460).
// R12's replay-only failure was un-zeroed stack elements 2048..3071
// accumulating atomicAdds across graph replays. Math already validated.
// B=4 L=1024 NF=64 DM=256 DS=16 SCS=8 NL=4 DI=512 DTR=16 DC=4 NFM=6 NH=4
// ---------------------------------------------------------------------------

typedef short short8v __attribute__((ext_vector_type(8)));
typedef float f32x4   __attribute__((ext_vector_type(4)));

__device__ __forceinline__ float geluf(float x){ return 0.5f*x*(1.0f + erff(x*0.70710678118654752f)); }
__device__ __forceinline__ float softplusf_(float x){ return (x > 20.f) ? x : log1pf(expf(x)); }
__device__ __forceinline__ unsigned short f2bf(float f){
  unsigned int u = __float_as_uint(f);
  unsigned int r = (u + 0x7FFFu + ((u >> 16) & 1u)) >> 16;
  return (unsigned short)r;
}

__device__ __forceinline__ void sc_region(int r, int& z, int& roff, int& s){
  if (r < 64){ z=0; roff=0; s=5; }
  else if (r < 192){ z=1; roff=64; s=20; }
  else { z=2; roff=192; s=50; }
}

// ---------------- merged fp32 -> bf16 weight convert (6 segments) ----------
__global__ __launch_bounds__(256) void k_f2b_all(
    const float* s0, unsigned short* d0,
    const float* s1, unsigned short* d1,
    const float* s2, unsigned short* d2,
    const float* s3, unsigned short* d3,
    const float* s4, unsigned short* d4,
    const float* s5, unsigned short* d5)
{
  int blk = blockIdx.x;
  const float* s; unsigned short* d; int base;
  if      (blk < 1024){ s=s0; d=d0; base=0; }
  else if (blk < 1536){ s=s1; d=d1; base=1024; }
  else if (blk < 1632){ s=s2; d=d2; base=1536; }
  else if (blk < 2400){ s=s3; d=d3; base=1632; }
  else if (blk < 2784){ s=s4; d=d4; base=2400; }
  else                { s=s5; d=d5; base=2784; }
  int i = ((blk - base)*256 + threadIdx.x)*4;
  float4 v = *(const float4*)(s + i);
  *(ushort4*)(d + i) = make_ushort4(f2bf(v.x), f2bf(v.y), f2bf(v.z), f2bf(v.w));
}

// ---------------- initial: h = gelu(LN(x @ in_w^T + in_b)) -----------------
__global__ __launch_bounds__(256) void k_inproj(
    const float* __restrict__ x, const float* __restrict__ w,
    const float* __restrict__ b, const float* __restrict__ g,
    const float* __restrict__ beta, float* __restrict__ h)
{
  __shared__ float xr[64];
  __shared__ float r1[4], r2[4];
  int row = blockIdx.x;
  int tid = threadIdx.x;
  if (tid < 64) xr[tid] = x[row*64 + tid];
  __syncthreads();
  float acc = b[tid];
  const float* wr = w + tid*64;
  #pragma unroll
  for (int k = 0; k < 64; k++) acc += xr[k]*wr[k];
  float s1 = acc, s2 = acc*acc;
  #pragma unroll
  for (int o = 32; o > 0; o >>= 1){ s1 += __shfl_down(s1,o,64); s2 += __shfl_down(s2,o,64); }
  if ((tid & 63) == 0){ r1[tid>>6] = s1; r2[tid>>6] = s2; }
  __syncthreads();
  float S1 = r1[0]+r1[1]+r1[2]+r1[3];
  float S2 = r2[0]+r2[1]+r2[2]+r2[3];
  float m = S1*(1.f/256.f);
  float var = S2*(1.f/256.f) - m*m;
  float xn = (acc - m)*rsqrtf(var + 1e-5f)*g[tid] + beta[tid];
  h[row*256 + tid] = geluf(xn);
}

// ---------------- LayerNorm over 256 -> bf16 (main layers) -----------------
__global__ __launch_bounds__(256) void k_ln(
    const float* __restrict__ src, const float* __restrict__ g, const float* __restrict__ beta,
    unsigned short* __restrict__ dst)
{
  __shared__ float r1[4], r2[4];
  int r = blockIdx.x, tid = threadIdx.x;
  float v = src[r*256 + tid];
  float s1 = v, s2 = v*v;
  #pragma unroll
  for (int o = 32; o > 0; o >>= 1){ s1 += __shfl_down(s1,o,64); s2 += __shfl_down(s2,o,64); }
  if ((tid & 63) == 0){ r1[tid>>6] = s1; r2[tid>>6] = s2; }
  __syncthreads();
  float S1 = r1[0]+r1[1]+r1[2]+r1[3];
  float S2 = r2[0]+r2[1]+r2[2]+r2[3];
  float m = S1*(1.f/256.f);
  float var = S2*(1.f/256.f) - m*m;
  dst[r*256 + tid] = f2bf((v - m)*rsqrtf(var + 1e-5f)*g[tid] + beta[tid]);
}

// ---------------- scale LN (grid 460: 448 LN rows + 12 stack-zero blocks) --
__global__ __launch_bounds__(256) void k_ln_sc(
    const float* __restrict__ h, const float* __restrict__ gb, const float* __restrict__ bb,
    unsigned short* __restrict__ dst, float* __restrict__ stack)
{
  __shared__ float r1[4], r2[4];
  int r = blockIdx.x, tid = threadIdx.x;
  if (r >= 448){
    int idx = (r - 448)*256 + tid;
    if (idx < 3072) stack[idx] = 0.f;
    return;
  }
  int z, roff, s; sc_region(r, z, roff, s);
  int local = r - roff;
  if (local >= 4*s) return;
  int b = local / s, t = local % s;
  float v = h[(b*1024 + (1024 - s) + t)*256 + tid];
  const float* g = gb + z*256; const float* be = bb + z*256;
  float s1 = v, s2 = v*v;
  #pragma unroll
  for (int o = 32; o > 0; o >>= 1){ s1 += __shfl_down(s1,o,64); s2 += __shfl_down(s2,o,64); }
  if ((tid & 63) == 0){ r1[tid>>6] = s1; r2[tid>>6] = s2; }
  __syncthreads();
  float S1 = r1[0]+r1[1]+r1[2]+r1[3];
  float S2 = r2[0]+r2[1]+r2[2]+r2[3];
  float m = S1*(1.f/256.f);
  float var = S2*(1.f/256.f) - m*m;
  dst[r*256 + tid] = f2bf((v - m)*rsqrtf(var + 1e-5f)*g[tid] + be[tid]);
}

// ---------------- MFMA GEMM: C = A(M,K)bf16 @ W(N,K)bf16^T, fp32 acc -------
template<int MODE, int SCB>
__global__ __launch_bounds__(256) void k_mm64(
    const unsigned short* __restrict__ A, const unsigned short* __restrict__ Wb,
    float* __restrict__ C,
    const float* __restrict__ resid,
    float* __restrict__ pool_out,
    int M, int N, int K, int wstr)
{
  int tid = threadIdx.x;
  int wave = tid >> 6, lane = tid & 63;
  int mh = wave & 1, nh = wave >> 1;
  int m0 = blockIdx.y*64 + mh*32;
  int n0 = blockIdx.x*64 + nh*32;
  int z = 0, roff = 0, sc = 0;
  const unsigned short* W = Wb;
  if (SCB){ sc_region(blockIdx.y*64, z, roff, sc); W += z*wstr; }
  int lrow = lane & 15, kc = lane >> 4;
  f32x4 acc[2][2] = {{{0.f,0.f,0.f,0.f},{0.f,0.f,0.f,0.f}},{{0.f,0.f,0.f,0.f},{0.f,0.f,0.f,0.f}}};
  for (int k0 = 0; k0 < K; k0 += 32){
    short8v a[2], b[2];
    #pragma unroll
    for (int mi = 0; mi < 2; mi++){
      int r = m0 + mi*16 + lrow; r = min(r, M-1);
      a[mi] = *(const short8v*)(A + r*K + k0 + kc*8);
    }
    #pragma unroll
    for (int ni = 0; ni < 2; ni++){
      int c = n0 + ni*16 + lrow;
      b[ni] = *(const short8v*)(W + c*K + k0 + kc*8);
    }
    #pragma unroll
    for (int mi = 0; mi < 2; mi++)
      #pragma unroll
      for (int ni = 0; ni < 2; ni++)
        acc[mi][ni] = __builtin_amdgcn_mfma_f32_16x16x32_bf16(a[mi], b[ni], acc[mi][ni], 0, 0, 0);
  }
  int rb = kc*4;
  #pragma unroll
  for (int mi = 0; mi < 2; mi++){
    #pragma unroll
    for (int rr = 0; rr < 4; rr++){
      int grow = m0 + mi*16 + rb + rr;
      if (grow >= M) continue;
      #pragma unroll
      for (int ni = 0; ni < 2; ni++){
        int gcol = n0 + ni*16 + lrow;
        float v = acc[mi][ni][rr];
        if (MODE == 0){
          C[grow*N + gcol] = v;
        } else if (MODE == 1){
          C[grow*N + gcol] = resid[grow*256 + gcol] + v;
        } else {
          int local = grow - roff;
          if (local < 4*sc){
            int bb2 = local / sc, t = local % sc;
            float rv = resid[(bb2*1024 + (1024 - sc) + t)*256 + gcol] + v;
            atomicAdd(&pool_out[bb2*768 + z*256 + gcol], rv*(1.f/(float)sc));
          }
        }
      }
    }
  }
}

// ---- fused conv+SiLU + split-K xp GEMM + dt --------------------------------
template<int NT, int SCB>
__global__ __launch_bounds__(256) void k_cxpdt(
    const float* __restrict__ uz,
    const float* __restrict__ cwb, const float* __restrict__ cbb,
    float* __restrict__ uc,
    const unsigned short* __restrict__ Wb, float* __restrict__ xdout,
    const float* __restrict__ dtwb, const float* __restrict__ dtbb,
    float* __restrict__ dtout)
{
  const int K = 512;
  const int NC = NT*16;
  __shared__ unsigned short sucb[16][520];
  __shared__ float pacc[4][16][NC];
  __shared__ float sxd[16][16];
  int tid = threadIdx.x;
  int wave = tid >> 6, lane = tid & 63;
  int bm0 = blockIdx.x*16;
  const unsigned short* W = Wb;
  const float* dtw = dtwb;
  const float* dtb = dtbb;
  const float* cw0 = cwb;
  const float* cb0 = cbb;
  if (SCB){
    int z, roff, s; sc_region(bm0, z, roff, s);
    W += z*(NC*K); dtw += z*8192; dtb += z*512;
    cw0 = cwb + z*2048; cb0 = cbb + z*512;
  }
  for (int e = tid; e < 16*512; e += 256){
    int r = e >> 9, d = e & 511;
    int row = bm0 + r;
    int t; bool valid = true;
    if (SCB){
      int z, roff, s; sc_region(row, z, roff, s);
      int local = row - roff;
      valid = local < 4*s;
      t = valid ? (local % s) : 0;
    } else {
      t = row & 1023;
    }
    float sv = 0.f;
    if (valid){
      float acc = cb0[d];
      const float* w = cw0 + d*4;
      #pragma unroll
      for (int k = 0; k < 4; k++){
        int ts = t - 3 + k;
        if (ts >= 0) acc += uz[(long)(row - (3-k))*1024 + d]*w[k];
      }
      sv = acc/(1.f + expf(-acc));
    }
    uc[(long)row*512 + d] = sv;
    sucb[r][d] = f2bf(sv);
  }
  __syncthreads();
  int lrow = lane & 15, kc = lane >> 4;
  int kbase = wave*128;
  f32x4 acc[NT];
  #pragma unroll
  for (int ni = 0; ni < NT; ni++) acc[ni] = (f32x4){0.f,0.f,0.f,0.f};
  #pragma unroll
  for (int k0 = 0; k0 < 128; k0 += 32){
    short8v a = *(const short8v*)&sucb[lrow][kbase + k0 + kc*8];
    #pragma unroll
    for (int ni = 0; ni < NT; ni++){
      short8v b = *(const short8v*)(W + (ni*16 + lrow)*K + kbase + k0 + kc*8);
      acc[ni] = __builtin_amdgcn_mfma_f32_16x16x32_bf16(a, b, acc[ni], 0, 0, 0);
    }
  }
  int rb = kc*4;
  #pragma unroll
  for (int rr = 0; rr < 4; rr++)
    #pragma unroll
    for (int ni = 0; ni < NT; ni++)
      pacc[wave][rb + rr][ni*16 + lrow] = acc[ni][rr];
  __syncthreads();
  for (int e = tid; e < 16*NC; e += 256){
    int r = e / NC, c = e % NC;
    float v = pacc[0][r][c] + pacc[1][r][c] + pacc[2][r][c] + pacc[3][r][c];
    xdout[(bm0 + r)*NC + c] = v;
    if (c < 16) sxd[r][c] = v;
  }
  __syncthreads();
  int d0 = tid, d1 = tid + 256;
  float w0[16], w1[16];
  #pragma unroll
  for (int j = 0; j < 16; j++){ w0[j] = dtw[d0*16 + j]; w1[j] = dtw[d1*16 + j]; }
  float b0 = dtb[d0], b1 = dtb[d1];
  #pragma unroll
  for (int r = 0; r < 16; r++){
    float a0 = b0, a1 = b1;
    #pragma unroll
    for (int j = 0; j < 16; j++){
      float xv = sxd[r][j];
      a0 = fmaf(xv, w0[j], a0);
      a1 = fmaf(xv, w1[j], a1);
    }
    dtout[(bm0 + r)*512 + d0] = softplusf_(a0);
    dtout[(bm0 + r)*512 + d1] = softplusf_(a1);
  }
}

// ============ chunked scan: p1 (256-thr staging) + p2 + parallel corr ======
__global__ __launch_bounds__(256) void k_scan_p1y(
    const float* __restrict__ dt, const float* __restrict__ uc,
    const float* __restrict__ xd, const float* __restrict__ Alog,
    float* __restrict__ hend, float* __restrict__ sdtb,
    float* __restrict__ yloc, float* __restrict__ Scum)
{
  const int CL = 64, NCH = 16;
  __shared__ float sdt[64][64], suc[64][64];
  __shared__ float sBC[64][32];
  int tid = threadIdx.x;
  int dblk = blockIdx.x;
  int b = blockIdx.y, ch = blockIdx.z;
  int t0 = ch*CL;
  for (int e = tid; e < CL*16; e += 256){
    int t = e >> 4, q = (e & 15)*4;
    long off = (long)(b*1024 + t0 + t)*512 + dblk*64 + q;
    *(float4*)&sdt[t][q] = *(const float4*)(dt + off);
    *(float4*)&suc[t][q] = *(const float4*)(uc + off);
  }
  for (int e = tid; e < CL*8; e += 256){
    int t = e >> 3, q = (e & 7)*4;
    *(float4*)&sBC[t][q] = *(const float4*)(xd + (long)(b*1024 + t0 + t)*48 + 16 + q);
  }
  __syncthreads();
  if (tid < 64){
    int d = dblk*64 + tid;
    float A[16];
    #pragma unroll
    for (int n = 0; n < 16; n++) A[n] = -__expf(Alog[d*16 + n]);
    float h[16];
    #pragma unroll
    for (int n = 0; n < 16; n++) h[n] = 0.f;
    float Ss = 0.f;
    #pragma unroll 2
    for (int t = 0; t < CL; t++){
      float dtv = sdt[t][tid];
      float uv  = suc[t][tid];
      Ss += dtv;
      float du = dtv*uv;
      float y = 0.f;
      #pragma unroll
      for (int n = 0; n < 16; n++){
        h[n] = fmaf(__expf(dtv*A[n]), h[n], du*sBC[t][n]);
        y = fmaf(h[n], sBC[t][16+n], y);
      }
      long row = (long)(b*1024 + t0 + t);
      yloc[row*512 + d] = y;
      Scum[row*512 + d] = Ss;
    }
    int base = ((b*NCH + ch)*512 + d)*16;
    #pragma unroll
    for (int q = 0; q < 4; q++)
      *(float4*)(hend + base + q*4) = make_float4(h[q*4], h[q*4+1], h[q*4+2], h[q*4+3]);
    sdtb[(b*NCH + ch)*512 + d] = Ss;
  }
}

__global__ __launch_bounds__(256) void k_scomb(
    const float* __restrict__ hend, const float* __restrict__ sdtb,
    const float* __restrict__ Alog, float* __restrict__ hstart,
    float* __restrict__ Aneg)
{
  const int NCH = 16;
  int idx = blockIdx.x*256 + threadIdx.x;
  int low = idx & 8191;
  int d = (idx >> 4) & 511, b = idx >> 13;
  float A = -__expf(Alog[low]);
  if (b == 0) Aneg[low] = A;
  float hs = 0.f;
  hstart[(b*NCH)*8192 + low] = 0.f;
  for (int c = 0; c < NCH-1; c++){
    float S  = sdtb[(b*NCH + c)*512 + d];
    float he = hend[(b*NCH + c)*8192 + low];
    hs = fmaf(__expf(A*S), hs, he);
    hstart[(b*NCH + c + 1)*8192 + low] = hs;
  }
}

__global__ __launch_bounds__(256) void k_corr(
    const float* __restrict__ yloc, const float* __restrict__ Scum,
    const float* __restrict__ hstart, const float* __restrict__ Aneg,
    const float* __restrict__ xd, const float* __restrict__ uc,
    const float* __restrict__ uz, const float* __restrict__ Dp,
    unsigned short* __restrict__ yg)
{
  __shared__ float sC[16];
  int row = blockIdx.x, tid = threadIdx.x;
  int b = row >> 10, t = row & 1023, ch = t >> 6;
  if (tid < 16) sC[tid] = xd[row*48 + 32 + tid];
  __syncthreads();
  #pragma unroll
  for (int rep = 0; rep < 2; rep++){
    int d = tid + rep*256;
    float Ss = Scum[row*512 + d];
    float y  = yloc[row*512 + d];
    const float* hs = hstart + ((b*16 + ch)*512 + d)*16;
    const float* An = Aneg + d*16;
    #pragma unroll
    for (int n = 0; n < 16; n++)
      y = fmaf(__expf(An[n]*Ss)*hs[n], sC[n], y);
    float uv = uc[row*512 + d];
    y = fmaf(uv, Dp[d], y);
    float zv = uz[(long)row*1024 + 512 + d];
    yg[row*512 + d] = f2bf(y*(zv/(1.f + __expf(-zv))));
  }
}

// ---------------- scale scan (DS=8, z-batched, single chunk) ---------------
__global__ __launch_bounds__(64) void k_scan_sc(
    const float* __restrict__ dt, const float* __restrict__ uc,
    const float* __restrict__ uz, const float* __restrict__ xd,
    const float* __restrict__ Alogb, const float* __restrict__ Dpb,
    unsigned short* __restrict__ yg)
{
  __shared__ float sdt[52][64], suc[52][64], sz[52][64];
  __shared__ float sBC[52][16];
  int tid = threadIdx.x;
  int dblk = blockIdx.x;
  int d = dblk*64 + tid;
  int b = blockIdx.y, z = blockIdx.z;
  int s = (z==0) ? 5 : (z==1) ? 20 : 50;
  int roff = (z==0) ? 0 : (z==1) ? 64 : 192;
  const float* Alog = Alogb + z*4096;
  const float* Dp   = Dpb + z*512;
  float A[8];
  #pragma unroll
  for (int n = 0; n < 8; n++) A[n] = -__expf(Alog[d*8 + n]);
  float Dv = Dp[d];
  for (int e = tid; e < s*16; e += 64){
    int t = e >> 4, q = (e & 15)*4;
    long row = (long)(roff + b*s + t);
    *(float4*)&sdt[t][q] = *(const float4*)(dt + row*512 + dblk*64 + q);
    *(float4*)&suc[t][q] = *(const float4*)(uc + row*512 + dblk*64 + q);
    *(float4*)&sz[t][q]  = *(const float4*)(uz + row*1024 + 512 + dblk*64 + q);
  }
  for (int e = tid; e < s*4; e += 64){
    int t = e >> 2, q = (e & 3)*4;
    long row = (long)(roff + b*s + t);
    *(float4*)&sBC[t][q] = *(const float4*)(xd + row*32 + 16 + q);
  }
  __syncthreads();
  float h[8];
  #pragma unroll
  for (int n = 0; n < 8; n++) h[n] = 0.f;
  for (int t = 0; t < s; t++){
    float dtv = sdt[t][tid];
    float uv  = suc[t][tid];
    float zv  = sz[t][tid];
    float du = dtv*uv;
    float y = 0.f;
    #pragma unroll
    for (int n = 0; n < 8; n++){
      h[n] = fmaf(__expf(dtv*A[n]), h[n], du*sBC[t][n]);
      y = fmaf(h[n], sBC[t][8+n], y);
    }
    y = fmaf(uv, Dv, y);
    float gate = zv/(1.f + __expf(-zv));
    yg[(long)(roff + b*s + t)*512 + d] = f2bf(y*gate);
  }
}

// ================== tail kernels (wide, multi-kernel) ======================
template<int M, int ACT, int RES>
__global__ __launch_bounds__(256) void k_tw(
    const float* __restrict__ A, const float* __restrict__ W,
    const float* __restrict__ bias, float* __restrict__ out,
    const float* __restrict__ resid, int N, int K, int ostride, int ocoff)
{
  extern __shared__ float sx[];
  int tid = threadIdx.x;
  for (int e = tid*4; e < M*K; e += 1024)
    *(float4*)&sx[e] = *(const float4*)(A + e);
  __syncthreads();
  int wave = tid >> 6, lane = tid & 63;
  int c = blockIdx.x*4 + wave;
  if (c >= N) return;
  float acc[M];
  #pragma unroll
  for (int r = 0; r < M; r++) acc[r] = 0.f;
  for (int k = lane*4; k < K; k += 256){
    float4 w4 = *(const float4*)(W + c*K + k);
    #pragma unroll
    for (int r = 0; r < M; r++){
      float4 x4 = *(float4*)&sx[r*K + k];
      acc[r] = fmaf(x4.x,w4.x,fmaf(x4.y,w4.y,fmaf(x4.z,w4.z,fmaf(x4.w,w4.w,acc[r]))));
    }
  }
  #pragma unroll
  for (int r = 0; r < M; r++){
    #pragma unroll
    for (int o = 32; o > 0; o >>= 1) acc[r] += __shfl_down(acc[r], o, 64);
  }
  if (lane == 0){
    float bv = bias[c];
    #pragma unroll
    for (int r = 0; r < M; r++){
      float v = acc[r] + bv;
      if (ACT == 1) v = geluf(v);
      if (RES == 1) v += resid[r*256 + c];
      out[r*ostride + ocoff + c] = v;
    }
  }
}

__global__ __launch_bounds__(256) void k_t_ln(
    const float* __restrict__ src, const float* __restrict__ g, const float* __restrict__ b,
    float* __restrict__ dst)
{
  __shared__ float r1[4], r2[4];
  int r = blockIdx.x, tid = threadIdx.x;
  float v = src[r*256 + tid];
  float s1 = v, s2 = v*v;
  #pragma unroll
  for (int o = 32; o > 0; o >>= 1){ s1 += __shfl_down(s1,o,64); s2 += __shfl_down(s2,o,64); }
  if ((tid & 63) == 0){ r1[tid>>6] = s1; r2[tid>>6] = s2; }
  __syncthreads();
  float S1 = r1[0]+r1[1]+r1[2]+r1[3];
  float S2 = r2[0]+r2[1]+r2[2]+r2[3];
  float m = S1*(1.f/256.f);
  float var = S2*(1.f/256.f) - m*m;
  dst[r*256 + tid] = (v - m)*rsqrtf(var + 1e-5f)*g[tid] + b[tid];
}

__global__ __launch_bounds__(256) void k_t_att(
    const float* __restrict__ qkv, float* __restrict__ ov)
{
  __shared__ float att[36];
  int b = blockIdx.x, tid = threadIdx.x;
  if (tid < 36){
    int hh = tid/9, r = (tid%9)/3, c = tid%3;
    float s = 0.f;
    const float* qp = qkv + (b*3 + r)*768 + hh*64;
    const float* kp = qkv + (b*3 + c)*768 + 256 + hh*64;
    for (int k = 0; k < 64; k++) s += qp[k]*kp[k];
    att[hh*9 + r*3 + c] = s*0.125f;
  }
  __syncthreads();
  if (tid < 12){
    int hh = tid/3, r = tid%3;
    float a0 = att[hh*9+r*3+0], a1 = att[hh*9+r*3+1], a2 = att[hh*9+r*3+2];
    float m = fmaxf(a0, fmaxf(a1, a2));
    float e0 = expf(a0-m), e1 = expf(a1-m), e2 = expf(a2-m);
    float s = e0+e1+e2;
    att[hh*9+r*3+0] = e0/s; att[hh*9+r*3+1] = e1/s; att[hh*9+r*3+2] = e2/s;
  }
  __syncthreads();
  for (int e = tid; e < 768; e += 256){
    int p = e >> 8, i = e & 255, hh = i >> 6;
    ov[(b*3 + p)*256 + i] = att[hh*9+p*3+0]*qkv[(b*3+0)*768+512+i]
                          + att[hh*9+p*3+1]*qkv[(b*3+1)*768+512+i]
                          + att[hh*9+p*3+2]*qkv[(b*3+2)*768+512+i];
  }
}

__global__ __launch_bounds__(256) void k_t_final(
    const float* __restrict__ fusedv, const float* __restrict__ s2f, float* __restrict__ finalv)
{
  int b = blockIdx.x, c = threadIdx.x;
  finalv[b*256 + c] = fusedv[b*256 + c] +
    (s2f[(b*3+0)*256 + c] + s2f[(b*3+1)*256 + c] + s2f[(b*3+2)*256 + c])*(1.f/3.f);
}

__global__ __launch_bounds__(64) void k_t_fin(
    const float* __restrict__ evraw, const float* __restrict__ ttraw, float* __restrict__ out)
{
  __shared__ float ev[7];
  __shared__ float S;
  int b = blockIdx.x, tid = threadIdx.x;
  if (tid < 7) ev[tid] = softplusf_(evraw[b*7 + tid]);
  __syncthreads();
  if (tid == 0){
    float s = 0.f;
    for (int j = 0; j < 7; j++) s += ev[j] + 1.f;
    S = s;
  }
  __syncthreads();
  float* ob = out + b*162;
  if (tid < 7){
    float al = ev[tid] + 1.f;
    ob[tid] = al / S;
    ob[7 + tid] = ev[tid];
    ob[14 + tid] = al;
  }
  if (tid == 0) ob[21] = 7.f / S;
  if (tid < 6){
    ob[22 + tid] = softplusf_(ttraw[b*12 + tid]);
    ob[28 + tid] = expf(0.5f*ttraw[b*12 + 6 + tid]);
  }
}

// ---------------------------------------------------------------------------
extern "C" void kernel_launch(void* const* d_in, const int* in_sizes, int n_in,
                              void* d_out, int out_size, void* d_ws, size_t ws_size,
                              hipStream_t stream)
{
  const float* x         = (const float*)d_in[0];
  const float* in_w      = (const float*)d_in[1];
  const float* in_b      = (const float*)d_in[2];
  const float* in_ln_g   = (const float*)d_in[3];
  const float* in_ln_b   = (const float*)d_in[4];
  const float* mb_ln_g   = (const float*)d_in[5];
  const float* mb_ln_b   = (const float*)d_in[6];
  const float* mb_in_w   = (const float*)d_in[7];
  const float* mb_conv_w = (const float*)d_in[8];
  const float* mb_conv_b = (const float*)d_in[9];
  const float* mb_xp_w   = (const float*)d_in[10];
  const float* mb_dt_w   = (const float*)d_in[11];
  const float* mb_dt_b   = (const float*)d_in[12];
  const float* mb_Alog   = (const float*)d_in[13];
  const float* mb_D      = (const float*)d_in[14];
  const float* mb_out_w  = (const float*)d_in[15];
  const float* sc_ln_g   = (const float*)d_in[16];
  const float* sc_ln_b   = (const float*)d_in[17];
  const float* sc_in_w   = (const float*)d_in[18];
  const float* sc_conv_w = (const float*)d_in[19];
  const float* sc_conv_b = (const float*)d_in[20];
  const float* sc_xp_w   = (const float*)d_in[21];
  const float* sc_dt_w   = (const float*)d_in[22];
  const float* sc_dt_b   = (const float*)d_in[23];
  const float* sc_Alog   = (const float*)d_in[24];
  const float* sc_D      = (const float*)d_in[25];
  const float* sc_out_w  = (const float*)d_in[26];
  const float* fus_qkv_w = (const float*)d_in[27];
  const float* fus_qkv_b = (const float*)d_in[28];
  const float* fus_out_w = (const float*)d_in[29];
  const float* fus_out_b = (const float*)d_in[30];
  const float* ms_out_w  = (const float*)d_in[31];
  const float* ms_out_b  = (const float*)d_in[32];
  const float* sa_ln1_g  = (const float*)d_in[33];
  const float* sa_ln1_b  = (const float*)d_in[34];
  const float* sa_ln2_g  = (const float*)d_in[35];
  const float* sa_ln2_b  = (const float*)d_in[36];
  const float* sa_qkv_w  = (const float*)d_in[37];
  const float* sa_qkv_b  = (const float*)d_in[38];
  const float* sa_out_w  = (const float*)d_in[39];
  const float* sa_out_b  = (const float*)d_in[40];
  const float* sa_ff1_w  = (const float*)d_in[41];
  const float* sa_ff1_b  = (const float*)d_in[42];
  const float* sa_ff2_w  = (const float*)d_in[43];
  const float* sa_ff2_b  = (const float*)d_in[44];
  const float* ev1_w     = (const float*)d_in[45];
  const float* ev1_b     = (const float*)d_in[46];
  const float* ev2_w     = (const float*)d_in[47];
  const float* ev2_b     = (const float*)d_in[48];
  const float* ttf1_w    = (const float*)d_in[49];
  const float* ttf1_b    = (const float*)d_in[50];
  const float* ttf2_w    = (const float*)d_in[51];
  const float* ttf2_b    = (const float*)d_in[52];
  const float* emb_w     = (const float*)d_in[53];
  const float* emb_b     = (const float*)d_in[54];

  float* ws = (float*)d_ws;
  float* h     = ws;                        // 1,048,576
  float* uz    = h    + 1048576;            // 4,194,304
  float* uc    = uz   + 4194304;            // 2,097,152
  float* dtb_  = uc   + 2097152;            // 2,097,152
  float* xd    = dtb_ + 2097152;            // 196,608
  float* stack = xd   + 196608;             // 4,096
  float* hend   = stack + 4096;          // 524,288
  float* hstart = hend + 524288;         // 524,288
  float* sdtb   = hstart + 524288;       // 32,768
  float* yloc   = sdtb + 32768;          // 2,097,152
  float* Scum   = yloc + 2097152;        // 2,097,152
  float* Aneg   = Scum + 2097152;        // 8,192
  float* qkvF   = Aneg + 8192;   // 9216
  float* ovF    = qkvF + 9216;   // 3072
  float* moF    = ovF  + 3072;   // 3072
  float* fusedv = moF  + 3072;   // 1024
  float* lnbuf  = fusedv + 1024; // 3072
  float* qkvS   = lnbuf + 3072;  // 9216
  float* ovS    = qkvS + 9216;   // 3072
  float* s2     = ovS  + 3072;   // 3072
  float* ln2r   = s2   + 3072;   // 3072
  float* hid    = ln2r + 3072;   // 12288
  float* s2f    = hid  + 12288;  // 3072
  float* finalv = s2f  + 3072;   // 1024
  float* evh    = finalv + 1024; // 1024
  float* tth    = evh  + 1024;   // 512
  float* evraw  = tth  + 512;    // 32
  float* ttraw  = evraw + 32;    // 64
  float* fp32_end = ttraw + 64;
  unsigned short* bfb = (unsigned short*)fp32_end;
  unsigned short* xnb    = bfb;                  // 1,048,576
  unsigned short* ygb    = xnb + 1048576;        // 2,097,152
  unsigned short* wmbin  = ygb + 2097152;        // 1,048,576
  unsigned short* wmbout = wmbin + 1048576;      // 524,288
  unsigned short* wmbxp  = wmbout + 524288;      // 98,304
  unsigned short* wscin  = wmbxp + 98304;        // 786,432
  unsigned short* wscout = wscin + 786432;       // 393,216
  unsigned short* wscxp  = wscout + 393216;      // 49,152

  k_f2b_all<<<2832, 256, 0, stream>>>(mb_in_w, wmbin, mb_out_w, wmbout, mb_xp_w, wmbxp,
                                      sc_in_w, wscin, sc_out_w, wscout, sc_xp_w, wscxp);

  k_inproj<<<4096, 256, 0, stream>>>(x, in_w, in_b, in_ln_g, in_ln_b, h);

  for (int l = 0; l < 4; l++){
    const float* Al = mb_Alog + l*8192;
    k_ln<<<4096, 256, 0, stream>>>(h, mb_ln_g + l*256, mb_ln_b + l*256, xnb);
    {
      dim3 g(16, 64);
      k_mm64<0,0><<<g, 256, 0, stream>>>(xnb, wmbin + l*262144, uz,
                                         nullptr, nullptr, 4096, 1024, 256, 0);
    }
    k_cxpdt<3,0><<<256, 256, 0, stream>>>(uz, mb_conv_w + l*2048, mb_conv_b + l*512, uc,
                                          wmbxp + l*24576, xd,
                                          mb_dt_w + l*8192, mb_dt_b + l*512, dtb_);
    {
      dim3 g(8, 4, 16);
      k_scan_p1y<<<g, 256, 0, stream>>>(dtb_, uc, xd, Al, hend, sdtb, yloc, Scum);
      k_scomb<<<128, 256, 0, stream>>>(hend, sdtb, Al, hstart, Aneg);
      k_corr<<<4096, 256, 0, stream>>>(yloc, Scum, hstart, Aneg, xd, uc, uz,
                                       mb_D + l*512, ygb);
    }
    {
      dim3 g(4, 64);
      k_mm64<1,0><<<g, 256, 0, stream>>>(ygb, wmbout + l*131072, h,
                                         h, nullptr, 4096, 256, 512, 0);
    }
  }

  // ---- scale mambas (batched), pooled -> stack ----
  k_ln_sc<<<460, 256, 0, stream>>>(h, sc_ln_g, sc_ln_b, xnb, stack);
  {
    dim3 g(16, 7);
    k_mm64<0,1><<<g, 256, 0, stream>>>(xnb, wscin, uz, nullptr, nullptr,
                                       448, 1024, 256, 262144);
  }
  k_cxpdt<2,1><<<28, 256, 0, stream>>>(uz, sc_conv_w, sc_conv_b, uc,
                                       wscxp, xd, sc_dt_w, sc_dt_b, dtb_);
  {
    dim3 g(8, 4, 3);
    k_scan_sc<<<g, 64, 0, stream>>>(dtb_, uc, uz, xd, sc_Alog, sc_D, ygb);
  }
  {
    dim3 g(4, 7);
    k_mm64<2,1><<<g, 256, 0, stream>>>(ygb, wscout, nullptr, h, stack,
                                       448, 256, 512, 131072);
  }

  // ---- tail (wide multi-kernel) ----
  float* dout = (float*)d_out;
  k_tw<12,0,0><<<192, 256, 12*256*4, stream>>>(stack, fus_qkv_w, fus_qkv_b, qkvF, nullptr, 768, 256, 768, 0);
  k_t_att<<<4, 256, 0, stream>>>(qkvF, ovF);
  k_tw<12,0,0><<<64, 256, 12*256*4, stream>>>(ovF, fus_out_w, fus_out_b, moF, nullptr, 256, 256, 256, 0);
  k_tw<4,0,0><<<64, 256, 4*768*4, stream>>>(moF, ms_out_w, ms_out_b, fusedv, nullptr, 256, 768, 256, 0);
  k_t_ln<<<12, 256, 0, stream>>>(stack, sa_ln1_g, sa_ln1_b, lnbuf);
  k_tw<12,0,0><<<192, 256, 12*256*4, stream>>>(lnbuf, sa_qkv_w, sa_qkv_b, qkvS, nullptr, 768, 256, 768, 0);
  k_t_att<<<4, 256, 0, stream>>>(qkvS, ovS);
  k_tw<12,0,1><<<64, 256, 12*256*4, stream>>>(ovS, sa_out_w, sa_out_b, s2, stack, 256, 256, 256, 0);
  k_t_ln<<<12, 256, 0, stream>>>(s2, sa_ln2_g, sa_ln2_b, ln2r);
  k_tw<12,1,0><<<256, 256, 12*256*4, stream>>>(ln2r, sa_ff1_w, sa_ff1_b, hid, nullptr, 1024, 256, 1024, 0);
  k_tw<12,0,1><<<64, 256, 12*1024*4, stream>>>(hid, sa_ff2_w, sa_ff2_b, s2f, s2, 256, 1024, 256, 0);
  k_t_final<<<4, 256, 0, stream>>>(fusedv, s2f, finalv);
  k_tw<4,1,0><<<64, 256, 4*256*4, stream>>>(finalv, ev1_w, ev1_b, evh, nullptr, 256, 256, 256, 0);
  k_tw<4,0,0><<<2, 256, 4*256*4, stream>>>(evh, ev2_w, ev2_b, evraw, nullptr, 7, 256, 7, 0);
  k_tw<4,1,0><<<32, 256, 4*256*4, stream>>>(finalv, ttf1_w, ttf1_b, tth, nullptr, 128, 256, 128, 0);
  k_tw<4,0,0><<<3, 256, 4*128*4, stream>>>(tth, ttf2_w, ttf2_b, ttraw, nullptr, 12, 128, 12, 0);
  k_tw<4,0,0><<<32, 256, 4*256*4, stream>>>(finalv, emb_w, emb_b, dout, nullptr, 128, 256, 162, 34);
  k_t_fin<<<4, 64, 0, stream>>>(evraw, ttraw, dout);
}

// Round 14
// 706.953 us; speedup vs baseline: 1.1308x; 1.1308x over previous
//
#include <hip/hip_runtime.h>
#include <math.h>

// ---------------------------------------------------------------------------
// MambaPredictor forward. R13: revert conv fusion (3rd width-vs-fusion lesson:
// conv is latency-bound and needs 4096-block width). Keep R13's ln_sc stack
// fix + 256-thread scan p1. Structure = R9 + fixes.
// B=4 L=1024 NF=64 DM=256 DS=16 SCS=8 NL=4 DI=512 DTR=16 DC=4 NFM=6 NH=4
// ---------------------------------------------------------------------------

typedef short short8v __attribute__((ext_vector_type(8)));
typedef float f32x4   __attribute__((ext_vector_type(4)));

__device__ __forceinline__ float geluf(float x){ return 0.5f*x*(1.0f + erff(x*0.70710678118654752f)); }
__device__ __forceinline__ float softplusf_(float x){ return (x > 20.f) ? x : log1pf(expf(x)); }
__device__ __forceinline__ unsigned short f2bf(float f){
  unsigned int u = __float_as_uint(f);
  unsigned int r = (u + 0x7FFFu + ((u >> 16) & 1u)) >> 16;
  return (unsigned short)r;
}

__device__ __forceinline__ void sc_region(int r, int& z, int& roff, int& s){
  if (r < 64){ z=0; roff=0; s=5; }
  else if (r < 192){ z=1; roff=64; s=20; }
  else { z=2; roff=192; s=50; }
}

// ---------------- merged fp32 -> bf16 weight convert (6 segments) ----------
__global__ __launch_bounds__(256) void k_f2b_all(
    const float* s0, unsigned short* d0,
    const float* s1, unsigned short* d1,
    const float* s2, unsigned short* d2,
    const float* s3, unsigned short* d3,
    const float* s4, unsigned short* d4,
    const float* s5, unsigned short* d5)
{
  int blk = blockIdx.x;
  const float* s; unsigned short* d; int base;
  if      (blk < 1024){ s=s0; d=d0; base=0; }
  else if (blk < 1536){ s=s1; d=d1; base=1024; }
  else if (blk < 1632){ s=s2; d=d2; base=1536; }
  else if (blk < 2400){ s=s3; d=d3; base=1632; }
  else if (blk < 2784){ s=s4; d=d4; base=2400; }
  else                { s=s5; d=d5; base=2784; }
  int i = ((blk - base)*256 + threadIdx.x)*4;
  float4 v = *(const float4*)(s + i);
  *(ushort4*)(d + i) = make_ushort4(f2bf(v.x), f2bf(v.y), f2bf(v.z), f2bf(v.w));
}

// ---------------- initial: h = gelu(LN(x @ in_w^T + in_b)) -----------------
__global__ __launch_bounds__(256) void k_inproj(
    const float* __restrict__ x, const float* __restrict__ w,
    const float* __restrict__ b, const float* __restrict__ g,
    const float* __restrict__ beta, float* __restrict__ h)
{
  __shared__ float xr[64];
  __shared__ float r1[4], r2[4];
  int row = blockIdx.x;
  int tid = threadIdx.x;
  if (tid < 64) xr[tid] = x[row*64 + tid];
  __syncthreads();
  float acc = b[tid];
  const float* wr = w + tid*64;
  #pragma unroll
  for (int k = 0; k < 64; k++) acc += xr[k]*wr[k];
  float s1 = acc, s2 = acc*acc;
  #pragma unroll
  for (int o = 32; o > 0; o >>= 1){ s1 += __shfl_down(s1,o,64); s2 += __shfl_down(s2,o,64); }
  if ((tid & 63) == 0){ r1[tid>>6] = s1; r2[tid>>6] = s2; }
  __syncthreads();
  float S1 = r1[0]+r1[1]+r1[2]+r1[3];
  float S2 = r2[0]+r2[1]+r2[2]+r2[3];
  float m = S1*(1.f/256.f);
  float var = S2*(1.f/256.f) - m*m;
  float xn = (acc - m)*rsqrtf(var + 1e-5f)*g[tid] + beta[tid];
  h[row*256 + tid] = geluf(xn);
}

// ---------------- LayerNorm over 256 -> bf16 (main layers) -----------------
__global__ __launch_bounds__(256) void k_ln(
    const float* __restrict__ src, const float* __restrict__ g, const float* __restrict__ beta,
    unsigned short* __restrict__ dst)
{
  __shared__ float r1[4], r2[4];
  int r = blockIdx.x, tid = threadIdx.x;
  float v = src[r*256 + tid];
  float s1 = v, s2 = v*v;
  #pragma unroll
  for (int o = 32; o > 0; o >>= 1){ s1 += __shfl_down(s1,o,64); s2 += __shfl_down(s2,o,64); }
  if ((tid & 63) == 0){ r1[tid>>6] = s1; r2[tid>>6] = s2; }
  __syncthreads();
  float S1 = r1[0]+r1[1]+r1[2]+r1[3];
  float S2 = r2[0]+r2[1]+r2[2]+r2[3];
  float m = S1*(1.f/256.f);
  float var = S2*(1.f/256.f) - m*m;
  dst[r*256 + tid] = f2bf((v - m)*rsqrtf(var + 1e-5f)*g[tid] + beta[tid]);
}

// ---------------- scale LN (grid 460: 448 LN rows + 12 stack-zero blocks) --
__global__ __launch_bounds__(256) void k_ln_sc(
    const float* __restrict__ h, const float* __restrict__ gb, const float* __restrict__ bb,
    unsigned short* __restrict__ dst, float* __restrict__ stack)
{
  __shared__ float r1[4], r2[4];
  int r = blockIdx.x, tid = threadIdx.x;
  if (r >= 448){
    int idx = (r - 448)*256 + tid;
    if (idx < 3072) stack[idx] = 0.f;
    return;
  }
  int z, roff, s; sc_region(r, z, roff, s);
  int local = r - roff;
  if (local >= 4*s) return;
  int b = local / s, t = local % s;
  float v = h[(b*1024 + (1024 - s) + t)*256 + tid];
  const float* g = gb + z*256; const float* be = bb + z*256;
  float s1 = v, s2 = v*v;
  #pragma unroll
  for (int o = 32; o > 0; o >>= 1){ s1 += __shfl_down(s1,o,64); s2 += __shfl_down(s2,o,64); }
  if ((tid & 63) == 0){ r1[tid>>6] = s1; r2[tid>>6] = s2; }
  __syncthreads();
  float S1 = r1[0]+r1[1]+r1[2]+r1[3];
  float S2 = r2[0]+r2[1]+r2[2]+r2[3];
  float m = S1*(1.f/256.f);
  float var = S2*(1.f/256.f) - m*m;
  dst[r*256 + tid] = f2bf((v - m)*rsqrtf(var + 1e-5f)*g[tid] + be[tid]);
}

// ---------------- MFMA GEMM: C = A(M,K)bf16 @ W(N,K)bf16^T, fp32 acc -------
template<int MODE, int SCB>
__global__ __launch_bounds__(256) void k_mm64(
    const unsigned short* __restrict__ A, const unsigned short* __restrict__ Wb,
    float* __restrict__ C,
    const float* __restrict__ resid,
    float* __restrict__ pool_out,
    int M, int N, int K, int wstr)
{
  int tid = threadIdx.x;
  int wave = tid >> 6, lane = tid & 63;
  int mh = wave & 1, nh = wave >> 1;
  int m0 = blockIdx.y*64 + mh*32;
  int n0 = blockIdx.x*64 + nh*32;
  int z = 0, roff = 0, sc = 0;
  const unsigned short* W = Wb;
  if (SCB){ sc_region(blockIdx.y*64, z, roff, sc); W += z*wstr; }
  int lrow = lane & 15, kc = lane >> 4;
  f32x4 acc[2][2] = {{{0.f,0.f,0.f,0.f},{0.f,0.f,0.f,0.f}},{{0.f,0.f,0.f,0.f},{0.f,0.f,0.f,0.f}}};
  for (int k0 = 0; k0 < K; k0 += 32){
    short8v a[2], b[2];
    #pragma unroll
    for (int mi = 0; mi < 2; mi++){
      int r = m0 + mi*16 + lrow; r = min(r, M-1);
      a[mi] = *(const short8v*)(A + r*K + k0 + kc*8);
    }
    #pragma unroll
    for (int ni = 0; ni < 2; ni++){
      int c = n0 + ni*16 + lrow;
      b[ni] = *(const short8v*)(W + c*K + k0 + kc*8);
    }
    #pragma unroll
    for (int mi = 0; mi < 2; mi++)
      #pragma unroll
      for (int ni = 0; ni < 2; ni++)
        acc[mi][ni] = __builtin_amdgcn_mfma_f32_16x16x32_bf16(a[mi], b[ni], acc[mi][ni], 0, 0, 0);
  }
  int rb = kc*4;
  #pragma unroll
  for (int mi = 0; mi < 2; mi++){
    #pragma unroll
    for (int rr = 0; rr < 4; rr++){
      int grow = m0 + mi*16 + rb + rr;
      if (grow >= M) continue;
      #pragma unroll
      for (int ni = 0; ni < 2; ni++){
        int gcol = n0 + ni*16 + lrow;
        float v = acc[mi][ni][rr];
        if (MODE == 0){
          C[grow*N + gcol] = v;
        } else if (MODE == 1){
          C[grow*N + gcol] = resid[grow*256 + gcol] + v;
        } else {
          int local = grow - roff;
          if (local < 4*sc){
            int bb2 = local / sc, t = local % sc;
            float rv = resid[(bb2*1024 + (1024 - sc) + t)*256 + gcol] + v;
            atomicAdd(&pool_out[bb2*768 + z*256 + gcol], rv*(1.f/(float)sc));
          }
        }
      }
    }
  }
}

// ---------------- depthwise causal conv (DC=4) + SiLU (wide: row/block) ----
__global__ __launch_bounds__(256) void k_conv(
    const float* __restrict__ uz, const float* __restrict__ cw, const float* __restrict__ cb,
    float* __restrict__ uc, unsigned short* __restrict__ ucb)
{
  int row = blockIdx.x;
  int t = row & 1023;
  int tid = threadIdx.x;
  for (int d = tid; d < 512; d += 256){
    float acc = cb[d];
    const float* w = cw + d*4;
    #pragma unroll
    for (int k = 0; k < 4; k++){
      int ts = t - 3 + k;
      if (ts >= 0) acc += uz[(long)(row - (3-k))*1024 + d]*w[k];
    }
    float s = acc/(1.f + expf(-acc));
    uc[(long)row*512 + d] = s;
    ucb[(long)row*512 + d] = f2bf(s);
  }
}

__global__ __launch_bounds__(256) void k_conv_sc(
    const float* __restrict__ uz, const float* __restrict__ cwb, const float* __restrict__ cbb,
    float* __restrict__ uc, unsigned short* __restrict__ ucb)
{
  int row = blockIdx.x;
  int z, roff, s; sc_region(row, z, roff, s);
  int local = row - roff;
  if (local >= 4*s) return;
  int t = local % s;
  const float* cw = cwb + z*2048;
  const float* cb = cbb + z*512;
  int tid = threadIdx.x;
  for (int d = tid; d < 512; d += 256){
    float acc = cb[d];
    const float* w = cw + d*4;
    #pragma unroll
    for (int k = 0; k < 4; k++){
      int ts = t - 3 + k;
      if (ts >= 0) acc += uz[(long)(row - (3-k))*1024 + d]*w[k];
    }
    float sv = acc/(1.f + expf(-acc));
    uc[(long)row*512 + d] = sv;
    ucb[(long)row*512 + d] = f2bf(sv);
  }
}

// ---- split-K wide xp GEMM + fused dt (reads bf16 ucb from global) ---------
template<int NT, int SCB>
__global__ __launch_bounds__(256) void k_xpdt(
    const unsigned short* __restrict__ A, const unsigned short* __restrict__ Wb,
    float* __restrict__ xdout,
    const float* __restrict__ dtwb, const float* __restrict__ dtbb,
    float* __restrict__ dtout, int M)
{
  const int K = 512;
  const int NC = NT*16;
  __shared__ float pacc[4][16][NC];
  __shared__ float sxd[16][16];
  int tid = threadIdx.x;
  int wave = tid >> 6, lane = tid & 63;
  int bm0 = blockIdx.x*16;
  const unsigned short* W = Wb;
  const float* dtw = dtwb;
  const float* dtb = dtbb;
  if (SCB){
    int z, roff, s; sc_region(bm0, z, roff, s);
    W += z*(NC*K); dtw += z*8192; dtb += z*512;
  }
  int lrow = lane & 15, kc = lane >> 4;
  int kbase = wave*128;
  f32x4 acc[NT];
  #pragma unroll
  for (int ni = 0; ni < NT; ni++) acc[ni] = (f32x4){0.f,0.f,0.f,0.f};
  #pragma unroll
  for (int k0 = 0; k0 < 128; k0 += 32){
    short8v a = *(const short8v*)(A + (long)(bm0 + lrow)*K + kbase + k0 + kc*8);
    #pragma unroll
    for (int ni = 0; ni < NT; ni++){
      short8v b = *(const short8v*)(W + (ni*16 + lrow)*K + kbase + k0 + kc*8);
      acc[ni] = __builtin_amdgcn_mfma_f32_16x16x32_bf16(a, b, acc[ni], 0, 0, 0);
    }
  }
  int rb = kc*4;
  #pragma unroll
  for (int rr = 0; rr < 4; rr++)
    #pragma unroll
    for (int ni = 0; ni < NT; ni++)
      pacc[wave][rb + rr][ni*16 + lrow] = acc[ni][rr];
  __syncthreads();
  for (int e = tid; e < 16*NC; e += 256){
    int r = e / NC, c = e % NC;
    float v = pacc[0][r][c] + pacc[1][r][c] + pacc[2][r][c] + pacc[3][r][c];
    xdout[(bm0 + r)*NC + c] = v;
    if (c < 16) sxd[r][c] = v;
  }
  __syncthreads();
  int d0 = tid, d1 = tid + 256;
  float w0[16], w1[16];
  #pragma unroll
  for (int j = 0; j < 16; j++){ w0[j] = dtw[d0*16 + j]; w1[j] = dtw[d1*16 + j]; }
  float b0 = dtb[d0], b1 = dtb[d1];
  #pragma unroll
  for (int r = 0; r < 16; r++){
    float a0 = b0, a1 = b1;
    #pragma unroll
    for (int j = 0; j < 16; j++){
      float xv = sxd[r][j];
      a0 = fmaf(xv, w0[j], a0);
      a1 = fmaf(xv, w1[j], a1);
    }
    dtout[(bm0 + r)*512 + d0] = softplusf_(a0);
    dtout[(bm0 + r)*512 + d1] = softplusf_(a1);
  }
}

// ============ chunked scan: p1 (256-thr staging) + p2 + parallel corr ======
__global__ __launch_bounds__(256) void k_scan_p1y(
    const float* __restrict__ dt, const float* __restrict__ uc,
    const float* __restrict__ xd, const float* __restrict__ Alog,
    float* __restrict__ hend, float* __restrict__ sdtb,
    float* __restrict__ yloc, float* __restrict__ Scum)
{
  const int CL = 64, NCH = 16;
  __shared__ float sdt[64][64], suc[64][64];
  __shared__ float sBC[64][32];
  int tid = threadIdx.x;
  int dblk = blockIdx.x;
  int b = blockIdx.y, ch = blockIdx.z;
  int t0 = ch*CL;
  for (int e = tid; e < CL*16; e += 256){
    int t = e >> 4, q = (e & 15)*4;
    long off = (long)(b*1024 + t0 + t)*512 + dblk*64 + q;
    *(float4*)&sdt[t][q] = *(const float4*)(dt + off);
    *(float4*)&suc[t][q] = *(const float4*)(uc + off);
  }
  for (int e = tid; e < CL*8; e += 256){
    int t = e >> 3, q = (e & 7)*4;
    *(float4*)&sBC[t][q] = *(const float4*)(xd + (long)(b*1024 + t0 + t)*48 + 16 + q);
  }
  __syncthreads();
  if (tid < 64){
    int d = dblk*64 + tid;
    float A[16];
    #pragma unroll
    for (int n = 0; n < 16; n++) A[n] = -__expf(Alog[d*16 + n]);
    float h[16];
    #pragma unroll
    for (int n = 0; n < 16; n++) h[n] = 0.f;
    float Ss = 0.f;
    #pragma unroll 2
    for (int t = 0; t < CL; t++){
      float dtv = sdt[t][tid];
      float uv  = suc[t][tid];
      Ss += dtv;
      float du = dtv*uv;
      float y = 0.f;
      #pragma unroll
      for (int n = 0; n < 16; n++){
        h[n] = fmaf(__expf(dtv*A[n]), h[n], du*sBC[t][n]);
        y = fmaf(h[n], sBC[t][16+n], y);
      }
      long row = (long)(b*1024 + t0 + t);
      yloc[row*512 + d] = y;
      Scum[row*512 + d] = Ss;
    }
    int base = ((b*NCH + ch)*512 + d)*16;
    #pragma unroll
    for (int q = 0; q < 4; q++)
      *(float4*)(hend + base + q*4) = make_float4(h[q*4], h[q*4+1], h[q*4+2], h[q*4+3]);
    sdtb[(b*NCH + ch)*512 + d] = Ss;
  }
}

__global__ __launch_bounds__(256) void k_scomb(
    const float* __restrict__ hend, const float* __restrict__ sdtb,
    const float* __restrict__ Alog, float* __restrict__ hstart,
    float* __restrict__ Aneg)
{
  const int NCH = 16;
  int idx = blockIdx.x*256 + threadIdx.x;
  int low = idx & 8191;
  int d = (idx >> 4) & 511, b = idx >> 13;
  float A = -__expf(Alog[low]);
  if (b == 0) Aneg[low] = A;
  float hs = 0.f;
  hstart[(b*NCH)*8192 + low] = 0.f;
  for (int c = 0; c < NCH-1; c++){
    float S  = sdtb[(b*NCH + c)*512 + d];
    float he = hend[(b*NCH + c)*8192 + low];
    hs = fmaf(__expf(A*S), hs, he);
    hstart[(b*NCH + c + 1)*8192 + low] = hs;
  }
}

__global__ __launch_bounds__(256) void k_corr(
    const float* __restrict__ yloc, const float* __restrict__ Scum,
    const float* __restrict__ hstart, const float* __restrict__ Aneg,
    const float* __restrict__ xd, const float* __restrict__ uc,
    const float* __restrict__ uz, const float* __restrict__ Dp,
    unsigned short* __restrict__ yg)
{
  __shared__ float sC[16];
  int row = blockIdx.x, tid = threadIdx.x;
  int b = row >> 10, t = row & 1023, ch = t >> 6;
  if (tid < 16) sC[tid] = xd[row*48 + 32 + tid];
  __syncthreads();
  #pragma unroll
  for (int rep = 0; rep < 2; rep++){
    int d = tid + rep*256;
    float Ss = Scum[row*512 + d];
    float y  = yloc[row*512 + d];
    const float* hs = hstart + ((b*16 + ch)*512 + d)*16;
    const float* An = Aneg + d*16;
    #pragma unroll
    for (int n = 0; n < 16; n++)
      y = fmaf(__expf(An[n]*Ss)*hs[n], sC[n], y);
    float uv = uc[row*512 + d];
    y = fmaf(uv, Dp[d], y);
    float zv = uz[(long)row*1024 + 512 + d];
    yg[row*512 + d] = f2bf(y*(zv/(1.f + __expf(-zv))));
  }
}

// ---------------- scale scan (DS=8, z-batched, single chunk) ---------------
__global__ __launch_bounds__(64) void k_scan_sc(
    const float* __restrict__ dt, const float* __restrict__ uc,
    const float* __restrict__ uz, const float* __restrict__ xd,
    const float* __restrict__ Alogb, const float* __restrict__ Dpb,
    unsigned short* __restrict__ yg)
{
  __shared__ float sdt[52][64], suc[52][64], sz[52][64];
  __shared__ float sBC[52][16];
  int tid = threadIdx.x;
  int dblk = blockIdx.x;
  int d = dblk*64 + tid;
  int b = blockIdx.y, z = blockIdx.z;
  int s = (z==0) ? 5 : (z==1) ? 20 : 50;
  int roff = (z==0) ? 0 : (z==1) ? 64 : 192;
  const float* Alog = Alogb + z*4096;
  const float* Dp   = Dpb + z*512;
  float A[8];
  #pragma unroll
  for (int n = 0; n < 8; n++) A[n] = -__expf(Alog[d*8 + n]);
  float Dv = Dp[d];
  for (int e = tid; e < s*16; e += 64){
    int t = e >> 4, q = (e & 15)*4;
    long row = (long)(roff + b*s + t);
    *(float4*)&sdt[t][q] = *(const float4*)(dt + row*512 + dblk*64 + q);
    *(float4*)&suc[t][q] = *(const float4*)(uc + row*512 + dblk*64 + q);
    *(float4*)&sz[t][q]  = *(const float4*)(uz + row*1024 + 512 + dblk*64 + q);
  }
  for (int e = tid; e < s*4; e += 64){
    int t = e >> 2, q = (e & 3)*4;
    long row = (long)(roff + b*s + t);
    *(float4*)&sBC[t][q] = *(const float4*)(xd + row*32 + 16 + q);
  }
  __syncthreads();
  float h[8];
  #pragma unroll
  for (int n = 0; n < 8; n++) h[n] = 0.f;
  for (int t = 0; t < s; t++){
    float dtv = sdt[t][tid];
    float uv  = suc[t][tid];
    float zv  = sz[t][tid];
    float du = dtv*uv;
    float y = 0.f;
    #pragma unroll
    for (int n = 0; n < 8; n++){
      h[n] = fmaf(__expf(dtv*A[n]), h[n], du*sBC[t][n]);
      y = fmaf(h[n], sBC[t][8+n], y);
    }
    y = fmaf(uv, Dv, y);
    float gate = zv/(1.f + __expf(-zv));
    yg[(long)(roff + b*s + t)*512 + d] = f2bf(y*gate);
  }
}

// ================== tail kernels (wide, multi-kernel) ======================
template<int M, int ACT, int RES>
__global__ __launch_bounds__(256) void k_tw(
    const float* __restrict__ A, const float* __restrict__ W,
    const float* __restrict__ bias, float* __restrict__ out,
    const float* __restrict__ resid, int N, int K, int ostride, int ocoff)
{
  extern __shared__ float sx[];
  int tid = threadIdx.x;
  for (int e = tid*4; e < M*K; e += 1024)
    *(float4*)&sx[e] = *(const float4*)(A + e);
  __syncthreads();
  int wave = tid >> 6, lane = tid & 63;
  int c = blockIdx.x*4 + wave;
  if (c >= N) return;
  float acc[M];
  #pragma unroll
  for (int r = 0; r < M; r++) acc[r] = 0.f;
  for (int k = lane*4; k < K; k += 256){
    float4 w4 = *(const float4*)(W + c*K + k);
    #pragma unroll
    for (int r = 0; r < M; r++){
      float4 x4 = *(float4*)&sx[r*K + k];
      acc[r] = fmaf(x4.x,w4.x,fmaf(x4.y,w4.y,fmaf(x4.z,w4.z,fmaf(x4.w,w4.w,acc[r]))));
    }
  }
  #pragma unroll
  for (int r = 0; r < M; r++){
    #pragma unroll
    for (int o = 32; o > 0; o >>= 1) acc[r] += __shfl_down(acc[r], o, 64);
  }
  if (lane == 0){
    float bv = bias[c];
    #pragma unroll
    for (int r = 0; r < M; r++){
      float v = acc[r] + bv;
      if (ACT == 1) v = geluf(v);
      if (RES == 1) v += resid[r*256 + c];
      out[r*ostride + ocoff + c] = v;
    }
  }
}

__global__ __launch_bounds__(256) void k_t_ln(
    const float* __restrict__ src, const float* __restrict__ g, const float* __restrict__ b,
    float* __restrict__ dst)
{
  __shared__ float r1[4], r2[4];
  int r = blockIdx.x, tid = threadIdx.x;
  float v = src[r*256 + tid];
  float s1 = v, s2 = v*v;
  #pragma unroll
  for (int o = 32; o > 0; o >>= 1){ s1 += __shfl_down(s1,o,64); s2 += __shfl_down(s2,o,64); }
  if ((tid & 63) == 0){ r1[tid>>6] = s1; r2[tid>>6] = s2; }
  __syncthreads();
  float S1 = r1[0]+r1[1]+r1[2]+r1[3];
  float S2 = r2[0]+r2[1]+r2[2]+r2[3];
  float m = S1*(1.f/256.f);
  float var = S2*(1.f/256.f) - m*m;
  dst[r*256 + tid] = (v - m)*rsqrtf(var + 1e-5f)*g[tid] + b[tid];
}

__global__ __launch_bounds__(256) void k_t_att(
    const float* __restrict__ qkv, float* __restrict__ ov)
{
  __shared__ float att[36];
  int b = blockIdx.x, tid = threadIdx.x;
  if (tid < 36){
    int hh = tid/9, r = (tid%9)/3, c = tid%3;
    float s = 0.f;
    const float* qp = qkv + (b*3 + r)*768 + hh*64;
    const float* kp = qkv + (b*3 + c)*768 + 256 + hh*64;
    for (int k = 0; k < 64; k++) s += qp[k]*kp[k];
    att[hh*9 + r*3 + c] = s*0.125f;
  }
  __syncthreads();
  if (tid < 12){
    int hh = tid/3, r = tid%3;
    float a0 = att[hh*9+r*3+0], a1 = att[hh*9+r*3+1], a2 = att[hh*9+r*3+2];
    float m = fmaxf(a0, fmaxf(a1, a2));
    float e0 = expf(a0-m), e1 = expf(a1-m), e2 = expf(a2-m);
    float s = e0+e1+e2;
    att[hh*9+r*3+0] = e0/s; att[hh*9+r*3+1] = e1/s; att[hh*9+r*3+2] = e2/s;
  }
  __syncthreads();
  for (int e = tid; e < 768; e += 256){
    int p = e >> 8, i = e & 255, hh = i >> 6;
    ov[(b*3 + p)*256 + i] = att[hh*9+p*3+0]*qkv[(b*3+0)*768+512+i]
                          + att[hh*9+p*3+1]*qkv[(b*3+1)*768+512+i]
                          + att[hh*9+p*3+2]*qkv[(b*3+2)*768+512+i];
  }
}

__global__ __launch_bounds__(256) void k_t_final(
    const float* __restrict__ fusedv, const float* __restrict__ s2f, float* __restrict__ finalv)
{
  int b = blockIdx.x, c = threadIdx.x;
  finalv[b*256 + c] = fusedv[b*256 + c] +
    (s2f[(b*3+0)*256 + c] + s2f[(b*3+1)*256 + c] + s2f[(b*3+2)*256 + c])*(1.f/3.f);
}

__global__ __launch_bounds__(64) void k_t_fin(
    const float* __restrict__ evraw, const float* __restrict__ ttraw, float* __restrict__ out)
{
  __shared__ float ev[7];
  __shared__ float S;
  int b = blockIdx.x, tid = threadIdx.x;
  if (tid < 7) ev[tid] = softplusf_(evraw[b*7 + tid]);
  __syncthreads();
  if (tid == 0){
    float s = 0.f;
    for (int j = 0; j < 7; j++) s += ev[j] + 1.f;
    S = s;
  }
  __syncthreads();
  float* ob = out + b*162;
  if (tid < 7){
    float al = ev[tid] + 1.f;
    ob[tid] = al / S;
    ob[7 + tid] = ev[tid];
    ob[14 + tid] = al;
  }
  if (tid == 0) ob[21] = 7.f / S;
  if (tid < 6){
    ob[22 + tid] = softplusf_(ttraw[b*12 + tid]);
    ob[28 + tid] = expf(0.5f*ttraw[b*12 + 6 + tid]);
  }
}

// ---------------------------------------------------------------------------
extern "C" void kernel_launch(void* const* d_in, const int* in_sizes, int n_in,
                              void* d_out, int out_size, void* d_ws, size_t ws_size,
                              hipStream_t stream)
{
  const float* x         = (const float*)d_in[0];
  const float* in_w      = (const float*)d_in[1];
  const float* in_b      = (const float*)d_in[2];
  const float* in_ln_g   = (const float*)d_in[3];
  const float* in_ln_b   = (const float*)d_in[4];
  const float* mb_ln_g   = (const float*)d_in[5];
  const float* mb_ln_b   = (const float*)d_in[6];
  const float* mb_in_w   = (const float*)d_in[7];
  const float* mb_conv_w = (const float*)d_in[8];
  const float* mb_conv_b = (const float*)d_in[9];
  const float* mb_xp_w   = (const float*)d_in[10];
  const float* mb_dt_w   = (const float*)d_in[11];
  const float* mb_dt_b   = (const float*)d_in[12];
  const float* mb_Alog   = (const float*)d_in[13];
  const float* mb_D      = (const float*)d_in[14];
  const float* mb_out_w  = (const float*)d_in[15];
  const float* sc_ln_g   = (const float*)d_in[16];
  const float* sc_ln_b   = (const float*)d_in[17];
  const float* sc_in_w   = (const float*)d_in[18];
  const float* sc_conv_w = (const float*)d_in[19];
  const float* sc_conv_b = (const float*)d_in[20];
  const float* sc_xp_w   = (const float*)d_in[21];
  const float* sc_dt_w   = (const float*)d_in[22];
  const float* sc_dt_b   = (const float*)d_in[23];
  const float* sc_Alog   = (const float*)d_in[24];
  const float* sc_D      = (const float*)d_in[25];
  const float* sc_out_w  = (const float*)d_in[26];
  const float* fus_qkv_w = (const float*)d_in[27];
  const float* fus_qkv_b = (const float*)d_in[28];
  const float* fus_out_w = (const float*)d_in[29];
  const float* fus_out_b = (const float*)d_in[30];
  const float* ms_out_w  = (const float*)d_in[31];
  const float* ms_out_b  = (const float*)d_in[32];
  const float* sa_ln1_g  = (const float*)d_in[33];
  const float* sa_ln1_b  = (const float*)d_in[34];
  const float* sa_ln2_g  = (const float*)d_in[35];
  const float* sa_ln2_b  = (const float*)d_in[36];
  const float* sa_qkv_w  = (const float*)d_in[37];
  const float* sa_qkv_b  = (const float*)d_in[38];
  const float* sa_out_w  = (const float*)d_in[39];
  const float* sa_out_b  = (const float*)d_in[40];
  const float* sa_ff1_w  = (const float*)d_in[41];
  const float* sa_ff1_b  = (const float*)d_in[42];
  const float* sa_ff2_w  = (const float*)d_in[43];
  const float* sa_ff2_b  = (const float*)d_in[44];
  const float* ev1_w     = (const float*)d_in[45];
  const float* ev1_b     = (const float*)d_in[46];
  const float* ev2_w     = (const float*)d_in[47];
  const float* ev2_b     = (const float*)d_in[48];
  const float* ttf1_w    = (const float*)d_in[49];
  const float* ttf1_b    = (const float*)d_in[50];
  const float* ttf2_w    = (const float*)d_in[51];
  const float* ttf2_b    = (const float*)d_in[52];
  const float* emb_w     = (const float*)d_in[53];
  const float* emb_b     = (const float*)d_in[54];

  float* ws = (float*)d_ws;
  float* h     = ws;                        // 1,048,576
  float* uz    = h    + 1048576;            // 4,194,304
  float* uc    = uz   + 4194304;            // 2,097,152
  float* dtb_  = uc   + 2097152;            // 2,097,152
  float* xd    = dtb_ + 2097152;            // 196,608
  float* stack = xd   + 196608;             // 4,096
  float* hend   = stack + 4096;          // 524,288
  float* hstart = hend + 524288;         // 524,288
  float* sdtb   = hstart + 524288;       // 32,768
  float* yloc   = sdtb + 32768;          // 2,097,152
  float* Scum   = yloc + 2097152;        // 2,097,152
  float* Aneg   = Scum + 2097152;        // 8,192
  float* qkvF   = Aneg + 8192;   // 9216
  float* ovF    = qkvF + 9216;   // 3072
  float* moF    = ovF  + 3072;   // 3072
  float* fusedv = moF  + 3072;   // 1024
  float* lnbuf  = fusedv + 1024; // 3072
  float* qkvS   = lnbuf + 3072;  // 9216
  float* ovS    = qkvS + 9216;   // 3072
  float* s2     = ovS  + 3072;   // 3072
  float* ln2r   = s2   + 3072;   // 3072
  float* hid    = ln2r + 3072;   // 12288
  float* s2f    = hid  + 12288;  // 3072
  float* finalv = s2f  + 3072;   // 1024
  float* evh    = finalv + 1024; // 1024
  float* tth    = evh  + 1024;   // 512
  float* evraw  = tth  + 512;    // 32
  float* ttraw  = evraw + 32;    // 64
  float* fp32_end = ttraw + 64;
  unsigned short* bfb = (unsigned short*)fp32_end;
  unsigned short* xnb    = bfb;                  // 1,048,576
  unsigned short* ucb    = xnb + 1048576;        // 2,097,152
  unsigned short* ygb    = ucb + 2097152;        // 2,097,152
  unsigned short* wmbin  = ygb + 2097152;        // 1,048,576
  unsigned short* wmbout = wmbin + 1048576;      // 524,288
  unsigned short* wmbxp  = wmbout + 524288;      // 98,304
  unsigned short* wscin  = wmbxp + 98304;        // 786,432
  unsigned short* wscout = wscin + 786432;       // 393,216
  unsigned short* wscxp  = wscout + 393216;      // 49,152

  k_f2b_all<<<2832, 256, 0, stream>>>(mb_in_w, wmbin, mb_out_w, wmbout, mb_xp_w, wmbxp,
                                      sc_in_w, wscin, sc_out_w, wscout, sc_xp_w, wscxp);

  k_inproj<<<4096, 256, 0, stream>>>(x, in_w, in_b, in_ln_g, in_ln_b, h);

  for (int l = 0; l < 4; l++){
    const float* Al = mb_Alog + l*8192;
    k_ln<<<4096, 256, 0, stream>>>(h, mb_ln_g + l*256, mb_ln_b + l*256, xnb);
    {
      dim3 g(16, 64);
      k_mm64<0,0><<<g, 256, 0, stream>>>(xnb, wmbin + l*262144, uz,
                                         nullptr, nullptr, 4096, 1024, 256, 0);
    }
    k_conv<<<4096, 256, 0, stream>>>(uz, mb_conv_w + l*2048, mb_conv_b + l*512, uc, ucb);
    k_xpdt<3,0><<<256, 256, 0, stream>>>(ucb, wmbxp + l*24576, xd,
                                         mb_dt_w + l*8192, mb_dt_b + l*512, dtb_, 4096);
    {
      dim3 g(8, 4, 16);
      k_scan_p1y<<<g, 256, 0, stream>>>(dtb_, uc, xd, Al, hend, sdtb, yloc, Scum);
      k_scomb<<<128, 256, 0, stream>>>(hend, sdtb, Al, hstart, Aneg);
      k_corr<<<4096, 256, 0, stream>>>(yloc, Scum, hstart, Aneg, xd, uc, uz,
                                       mb_D + l*512, ygb);
    }
    {
      dim3 g(4, 64);
      k_mm64<1,0><<<g, 256, 0, stream>>>(ygb, wmbout + l*131072, h,
                                         h, nullptr, 4096, 256, 512, 0);
    }
  }

  // ---- scale mambas (batched), pooled -> stack ----
  k_ln_sc<<<460, 256, 0, stream>>>(h, sc_ln_g, sc_ln_b, xnb, stack);
  {
    dim3 g(16, 7);
    k_mm64<0,1><<<g, 256, 0, stream>>>(xnb, wscin, uz, nullptr, nullptr,
                                       448, 1024, 256, 262144);
  }
  k_conv_sc<<<448, 256, 0, stream>>>(uz, sc_conv_w, sc_conv_b, uc, ucb);
  k_xpdt<2,1><<<28, 256, 0, stream>>>(ucb, wscxp, xd, sc_dt_w, sc_dt_b, dtb_, 448);
  {
    dim3 g(8, 4, 3);
    k_scan_sc<<<g, 64, 0, stream>>>(dtb_, uc, uz, xd, sc_Alog, sc_D, ygb);
  }
  {
    dim3 g(4, 7);
    k_mm64<2,1><<<g, 256, 0, stream>>>(ygb, wscout, nullptr, h, stack,
                                       448, 256, 512, 131072);
  }

  // ---- tail (wide multi-kernel) ----
  float* dout = (float*)d_out;
  k_tw<12,0,0><<<192, 256, 12*256*4, stream>>>(stack, fus_qkv_w, fus_qkv_b, qkvF, nullptr, 768, 256, 768, 0);
  k_t_att<<<4, 256, 0, stream>>>(qkvF, ovF);
  k_tw<12,0,0><<<64, 256, 12*256*4, stream>>>(ovF, fus_out_w, fus_out_b, moF, nullptr, 256, 256, 256, 0);
  k_tw<4,0,0><<<64, 256, 4*768*4, stream>>>(moF, ms_out_w, ms_out_b, fusedv, nullptr, 256, 768, 256, 0);
  k_t_ln<<<12, 256, 0, stream>>>(stack, sa_ln1_g, sa_ln1_b, lnbuf);
  k_tw<12,0,0><<<192, 256, 12*256*4, stream>>>(lnbuf, sa_qkv_w, sa_qkv_b, qkvS, nullptr, 768, 256, 768, 0);
  k_t_att<<<4, 256, 0, stream>>>(qkvS, ovS);
  k_tw<12,0,1><<<64, 256, 12*256*4, stream>>>(ovS, sa_out_w, sa_out_b, s2, stack, 256, 256, 256, 0);
  k_t_ln<<<12, 256, 0, stream>>>(s2, sa_ln2_g, sa_ln2_b, ln2r);
  k_tw<12,1,0><<<256, 256, 12*256*4, stream>>>(ln2r, sa_ff1_w, sa_ff1_b, hid, nullptr, 1024, 256, 1024, 0);
  k_tw<12,0,1><<<64, 256, 12*1024*4, stream>>>(hid, sa_ff2_w, sa_ff2_b, s2f, s2, 256, 1024, 256, 0);
  k_t_final<<<4, 256, 0, stream>>>(fusedv, s2f, finalv);
  k_tw<4,1,0><<<64, 256, 4*256*4, stream>>>(finalv, ev1_w, ev1_b, evh, nullptr, 256, 256, 256, 0);
  k_tw<4,0,0><<<2, 256, 4*256*4, stream>>>(evh, ev2_w, ev2_b, evraw, nullptr, 7, 256, 7, 0);
  k_tw<4,1,0><<<32, 256, 4*256*4, stream>>>(finalv, ttf1_w, ttf1_b, tth, nullptr, 128, 256, 128, 0);
  k_tw<4,0,0><<<3, 256, 4*128*4, stream>>>(tth, ttf2_w, ttf2_b, ttraw, nullptr, 12, 128, 12, 0);
  k_tw<4,0,0><<<32, 256, 4*256*4, stream>>>(finalv, emb_w, emb_b, dout, nullptr, 128, 256, 162, 34);
  k_t_fin<<<4, 64, 0, stream>>>(evraw, ttraw, dout);
}

// Round 15
// 624.075 us; speedup vs baseline: 1.2810x; 1.1328x over previous
//
#include <hip/hip_runtime.h>
#include <math.h>

// ---------------------------------------------------------------------------
// MambaPredictor forward. R14: k_xpdt widened to 8-wave split-K (K=64/wave,
// 512-thread blocks) -- was 4 waves/CU latency-bound at 10% occupancy.
// Everything else = R14 (passing, 707 us).
// B=4 L=1024 NF=64 DM=256 DS=16 SCS=8 NL=4 DI=512 DTR=16 DC=4 NFM=6 NH=4
// ---------------------------------------------------------------------------

typedef short short8v __attribute__((ext_vector_type(8)));
typedef float f32x4   __attribute__((ext_vector_type(4)));

__device__ __forceinline__ float geluf(float x){ return 0.5f*x*(1.0f + erff(x*0.70710678118654752f)); }
__device__ __forceinline__ float softplusf_(float x){ return (x > 20.f) ? x : log1pf(expf(x)); }
__device__ __forceinline__ unsigned short f2bf(float f){
  unsigned int u = __float_as_uint(f);
  unsigned int r = (u + 0x7FFFu + ((u >> 16) & 1u)) >> 16;
  return (unsigned short)r;
}

__device__ __forceinline__ void sc_region(int r, int& z, int& roff, int& s){
  if (r < 64){ z=0; roff=0; s=5; }
  else if (r < 192){ z=1; roff=64; s=20; }
  else { z=2; roff=192; s=50; }
}

// ---------------- merged fp32 -> bf16 weight convert (6 segments) ----------
__global__ __launch_bounds__(256) void k_f2b_all(
    const float* s0, unsigned short* d0,
    const float* s1, unsigned short* d1,
    const float* s2, unsigned short* d2,
    const float* s3, unsigned short* d3,
    const float* s4, unsigned short* d4,
    const float* s5, unsigned short* d5)
{
  int blk = blockIdx.x;
  const float* s; unsigned short* d; int base;
  if      (blk < 1024){ s=s0; d=d0; base=0; }
  else if (blk < 1536){ s=s1; d=d1; base=1024; }
  else if (blk < 1632){ s=s2; d=d2; base=1536; }
  else if (blk < 2400){ s=s3; d=d3; base=1632; }
  else if (blk < 2784){ s=s4; d=d4; base=2400; }
  else                { s=s5; d=d5; base=2784; }
  int i = ((blk - base)*256 + threadIdx.x)*4;
  float4 v = *(const float4*)(s + i);
  *(ushort4*)(d + i) = make_ushort4(f2bf(v.x), f2bf(v.y), f2bf(v.z), f2bf(v.w));
}

// ---------------- initial: h = gelu(LN(x @ in_w^T + in_b)) -----------------
__global__ __launch_bounds__(256) void k_inproj(
    const float* __restrict__ x, const float* __restrict__ w,
    const float* __restrict__ b, const float* __restrict__ g,
    const float* __restrict__ beta, float* __restrict__ h)
{
  __shared__ float xr[64];
  __shared__ float r1[4], r2[4];
  int row = blockIdx.x;
  int tid = threadIdx.x;
  if (tid < 64) xr[tid] = x[row*64 + tid];
  __syncthreads();
  float acc = b[tid];
  const float* wr = w + tid*64;
  #pragma unroll
  for (int k = 0; k < 64; k++) acc += xr[k]*wr[k];
  float s1 = acc, s2 = acc*acc;
  #pragma unroll
  for (int o = 32; o > 0; o >>= 1){ s1 += __shfl_down(s1,o,64); s2 += __shfl_down(s2,o,64); }
  if ((tid & 63) == 0){ r1[tid>>6] = s1; r2[tid>>6] = s2; }
  __syncthreads();
  float S1 = r1[0]+r1[1]+r1[2]+r1[3];
  float S2 = r2[0]+r2[1]+r2[2]+r2[3];
  float m = S1*(1.f/256.f);
  float var = S2*(1.f/256.f) - m*m;
  float xn = (acc - m)*rsqrtf(var + 1e-5f)*g[tid] + beta[tid];
  h[row*256 + tid] = geluf(xn);
}

// ---------------- LayerNorm over 256 -> bf16 (main layers) -----------------
__global__ __launch_bounds__(256) void k_ln(
    const float* __restrict__ src, const float* __restrict__ g, const float* __restrict__ beta,
    unsigned short* __restrict__ dst)
{
  __shared__ float r1[4], r2[4];
  int r = blockIdx.x, tid = threadIdx.x;
  float v = src[r*256 + tid];
  float s1 = v, s2 = v*v;
  #pragma unroll
  for (int o = 32; o > 0; o >>= 1){ s1 += __shfl_down(s1,o,64); s2 += __shfl_down(s2,o,64); }
  if ((tid & 63) == 0){ r1[tid>>6] = s1; r2[tid>>6] = s2; }
  __syncthreads();
  float S1 = r1[0]+r1[1]+r1[2]+r1[3];
  float S2 = r2[0]+r2[1]+r2[2]+r2[3];
  float m = S1*(1.f/256.f);
  float var = S2*(1.f/256.f) - m*m;
  dst[r*256 + tid] = f2bf((v - m)*rsqrtf(var + 1e-5f)*g[tid] + beta[tid]);
}

// ---------------- scale LN (grid 460: 448 LN rows + 12 stack-zero blocks) --
__global__ __launch_bounds__(256) void k_ln_sc(
    const float* __restrict__ h, const float* __restrict__ gb, const float* __restrict__ bb,
    unsigned short* __restrict__ dst, float* __restrict__ stack)
{
  __shared__ float r1[4], r2[4];
  int r = blockIdx.x, tid = threadIdx.x;
  if (r >= 448){
    int idx = (r - 448)*256 + tid;
    if (idx < 3072) stack[idx] = 0.f;
    return;
  }
  int z, roff, s; sc_region(r, z, roff, s);
  int local = r - roff;
  if (local >= 4*s) return;
  int b = local / s, t = local % s;
  float v = h[(b*1024 + (1024 - s) + t)*256 + tid];
  const float* g = gb + z*256; const float* be = bb + z*256;
  float s1 = v, s2 = v*v;
  #pragma unroll
  for (int o = 32; o > 0; o >>= 1){ s1 += __shfl_down(s1,o,64); s2 += __shfl_down(s2,o,64); }
  if ((tid & 63) == 0){ r1[tid>>6] = s1; r2[tid>>6] = s2; }
  __syncthreads();
  float S1 = r1[0]+r1[1]+r1[2]+r1[3];
  float S2 = r2[0]+r2[1]+r2[2]+r2[3];
  float m = S1*(1.f/256.f);
  float var = S2*(1.f/256.f) - m*m;
  dst[r*256 + tid] = f2bf((v - m)*rsqrtf(var + 1e-5f)*g[tid] + be[tid]);
}

// ---------------- MFMA GEMM: C = A(M,K)bf16 @ W(N,K)bf16^T, fp32 acc -------
template<int MODE, int SCB>
__global__ __launch_bounds__(256) void k_mm64(
    const unsigned short* __restrict__ A, const unsigned short* __restrict__ Wb,
    float* __restrict__ C,
    const float* __restrict__ resid,
    float* __restrict__ pool_out,
    int M, int N, int K, int wstr)
{
  int tid = threadIdx.x;
  int wave = tid >> 6, lane = tid & 63;
  int mh = wave & 1, nh = wave >> 1;
  int m0 = blockIdx.y*64 + mh*32;
  int n0 = blockIdx.x*64 + nh*32;
  int z = 0, roff = 0, sc = 0;
  const unsigned short* W = Wb;
  if (SCB){ sc_region(blockIdx.y*64, z, roff, sc); W += z*wstr; }
  int lrow = lane & 15, kc = lane >> 4;
  f32x4 acc[2][2] = {{{0.f,0.f,0.f,0.f},{0.f,0.f,0.f,0.f}},{{0.f,0.f,0.f,0.f},{0.f,0.f,0.f,0.f}}};
  for (int k0 = 0; k0 < K; k0 += 32){
    short8v a[2], b[2];
    #pragma unroll
    for (int mi = 0; mi < 2; mi++){
      int r = m0 + mi*16 + lrow; r = min(r, M-1);
      a[mi] = *(const short8v*)(A + r*K + k0 + kc*8);
    }
    #pragma unroll
    for (int ni = 0; ni < 2; ni++){
      int c = n0 + ni*16 + lrow;
      b[ni] = *(const short8v*)(W + c*K + k0 + kc*8);
    }
    #pragma unroll
    for (int mi = 0; mi < 2; mi++)
      #pragma unroll
      for (int ni = 0; ni < 2; ni++)
        acc[mi][ni] = __builtin_amdgcn_mfma_f32_16x16x32_bf16(a[mi], b[ni], acc[mi][ni], 0, 0, 0);
  }
  int rb = kc*4;
  #pragma unroll
  for (int mi = 0; mi < 2; mi++){
    #pragma unroll
    for (int rr = 0; rr < 4; rr++){
      int grow = m0 + mi*16 + rb + rr;
      if (grow >= M) continue;
      #pragma unroll
      for (int ni = 0; ni < 2; ni++){
        int gcol = n0 + ni*16 + lrow;
        float v = acc[mi][ni][rr];
        if (MODE == 0){
          C[grow*N + gcol] = v;
        } else if (MODE == 1){
          C[grow*N + gcol] = resid[grow*256 + gcol] + v;
        } else {
          int local = grow - roff;
          if (local < 4*sc){
            int bb2 = local / sc, t = local % sc;
            float rv = resid[(bb2*1024 + (1024 - sc) + t)*256 + gcol] + v;
            atomicAdd(&pool_out[bb2*768 + z*256 + gcol], rv*(1.f/(float)sc));
          }
        }
      }
    }
  }
}

// ---------------- depthwise causal conv (DC=4) + SiLU (wide: row/block) ----
__global__ __launch_bounds__(256) void k_conv(
    const float* __restrict__ uz, const float* __restrict__ cw, const float* __restrict__ cb,
    float* __restrict__ uc, unsigned short* __restrict__ ucb)
{
  int row = blockIdx.x;
  int t = row & 1023;
  int tid = threadIdx.x;
  for (int d = tid; d < 512; d += 256){
    float acc = cb[d];
    const float* w = cw + d*4;
    #pragma unroll
    for (int k = 0; k < 4; k++){
      int ts = t - 3 + k;
      if (ts >= 0) acc += uz[(long)(row - (3-k))*1024 + d]*w[k];
    }
    float s = acc/(1.f + expf(-acc));
    uc[(long)row*512 + d] = s;
    ucb[(long)row*512 + d] = f2bf(s);
  }
}

__global__ __launch_bounds__(256) void k_conv_sc(
    const float* __restrict__ uz, const float* __restrict__ cwb, const float* __restrict__ cbb,
    float* __restrict__ uc, unsigned short* __restrict__ ucb)
{
  int row = blockIdx.x;
  int z, roff, s; sc_region(row, z, roff, s);
  int local = row - roff;
  if (local >= 4*s) return;
  int t = local % s;
  const float* cw = cwb + z*2048;
  const float* cb = cbb + z*512;
  int tid = threadIdx.x;
  for (int d = tid; d < 512; d += 256){
    float acc = cb[d];
    const float* w = cw + d*4;
    #pragma unroll
    for (int k = 0; k < 4; k++){
      int ts = t - 3 + k;
      if (ts >= 0) acc += uz[(long)(row - (3-k))*1024 + d]*w[k];
    }
    float sv = acc/(1.f + expf(-acc));
    uc[(long)row*512 + d] = sv;
    ucb[(long)row*512 + d] = f2bf(sv);
  }
}

// ---- split-K wide xp GEMM + fused dt (8-wave, K=64 per wave) ---------------
template<int NT, int SCB>
__global__ __launch_bounds__(512) void k_xpdt(
    const unsigned short* __restrict__ A, const unsigned short* __restrict__ Wb,
    float* __restrict__ xdout,
    const float* __restrict__ dtwb, const float* __restrict__ dtbb,
    float* __restrict__ dtout, int M)
{
  const int K = 512;
  const int NC = NT*16;
  __shared__ float pacc[8][16][NC];
  __shared__ float sxd[16][16];
  int tid = threadIdx.x;
  int wave = tid >> 6, lane = tid & 63;
  int bm0 = blockIdx.x*16;
  const unsigned short* W = Wb;
  const float* dtw = dtwb;
  const float* dtb = dtbb;
  if (SCB){
    int z, roff, s; sc_region(bm0, z, roff, s);
    W += z*(NC*K); dtw += z*8192; dtb += z*512;
  }
  int lrow = lane & 15, kc = lane >> 4;
  int kbase = wave*64;
  f32x4 acc[NT];
  #pragma unroll
  for (int ni = 0; ni < NT; ni++) acc[ni] = (f32x4){0.f,0.f,0.f,0.f};
  #pragma unroll
  for (int k0 = 0; k0 < 64; k0 += 32){
    short8v a = *(const short8v*)(A + (long)(bm0 + lrow)*K + kbase + k0 + kc*8);
    #pragma unroll
    for (int ni = 0; ni < NT; ni++){
      short8v b = *(const short8v*)(W + (ni*16 + lrow)*K + kbase + k0 + kc*8);
      acc[ni] = __builtin_amdgcn_mfma_f32_16x16x32_bf16(a, b, acc[ni], 0, 0, 0);
    }
  }
  int rb = kc*4;
  #pragma unroll
  for (int rr = 0; rr < 4; rr++)
    #pragma unroll
    for (int ni = 0; ni < NT; ni++)
      pacc[wave][rb + rr][ni*16 + lrow] = acc[ni][rr];
  __syncthreads();
  for (int e = tid; e < 16*NC; e += 512){
    int r = e / NC, c = e % NC;
    float v = pacc[0][r][c] + pacc[1][r][c] + pacc[2][r][c] + pacc[3][r][c]
            + pacc[4][r][c] + pacc[5][r][c] + pacc[6][r][c] + pacc[7][r][c];
    xdout[(bm0 + r)*NC + c] = v;
    if (c < 16) sxd[r][c] = v;
  }
  __syncthreads();
  // dt: one d-channel per thread (512 threads = 512 channels)
  int d0 = tid;
  float w0[16];
  #pragma unroll
  for (int j = 0; j < 16; j++) w0[j] = dtw[d0*16 + j];
  float b0 = dtb[d0];
  #pragma unroll
  for (int r = 0; r < 16; r++){
    float a0 = b0;
    #pragma unroll
    for (int j = 0; j < 16; j++)
      a0 = fmaf(sxd[r][j], w0[j], a0);
    dtout[(bm0 + r)*512 + d0] = softplusf_(a0);
  }
}

// ============ chunked scan: p1 (256-thr staging) + p2 + parallel corr ======
__global__ __launch_bounds__(256) void k_scan_p1y(
    const float* __restrict__ dt, const float* __restrict__ uc,
    const float* __restrict__ xd, const float* __restrict__ Alog,
    float* __restrict__ hend, float* __restrict__ sdtb,
    float* __restrict__ yloc, float* __restrict__ Scum)
{
  const int CL = 64, NCH = 16;
  __shared__ float sdt[64][64], suc[64][64];
  __shared__ float sBC[64][32];
  int tid = threadIdx.x;
  int dblk = blockIdx.x;
  int b = blockIdx.y, ch = blockIdx.z;
  int t0 = ch*CL;
  for (int e = tid; e < CL*16; e += 256){
    int t = e >> 4, q = (e & 15)*4;
    long off = (long)(b*1024 + t0 + t)*512 + dblk*64 + q;
    *(float4*)&sdt[t][q] = *(const float4*)(dt + off);
    *(float4*)&suc[t][q] = *(const float4*)(uc + off);
  }
  for (int e = tid; e < CL*8; e += 256){
    int t = e >> 3, q = (e & 7)*4;
    *(float4*)&sBC[t][q] = *(const float4*)(xd + (long)(b*1024 + t0 + t)*48 + 16 + q);
  }
  __syncthreads();
  if (tid < 64){
    int d = dblk*64 + tid;
    float A[16];
    #pragma unroll
    for (int n = 0; n < 16; n++) A[n] = -__expf(Alog[d*16 + n]);
    float h[16];
    #pragma unroll
    for (int n = 0; n < 16; n++) h[n] = 0.f;
    float Ss = 0.f;
    #pragma unroll 2
    for (int t = 0; t < CL; t++){
      float dtv = sdt[t][tid];
      float uv  = suc[t][tid];
      Ss += dtv;
      float du = dtv*uv;
      float y = 0.f;
      #pragma unroll
      for (int n = 0; n < 16; n++){
        h[n] = fmaf(__expf(dtv*A[n]), h[n], du*sBC[t][n]);
        y = fmaf(h[n], sBC[t][16+n], y);
      }
      long row = (long)(b*1024 + t0 + t);
      yloc[row*512 + d] = y;
      Scum[row*512 + d] = Ss;
    }
    int base = ((b*NCH + ch)*512 + d)*16;
    #pragma unroll
    for (int q = 0; q < 4; q++)
      *(float4*)(hend + base + q*4) = make_float4(h[q*4], h[q*4+1], h[q*4+2], h[q*4+3]);
    sdtb[(b*NCH + ch)*512 + d] = Ss;
  }
}

__global__ __launch_bounds__(256) void k_scomb(
    const float* __restrict__ hend, const float* __restrict__ sdtb,
    const float* __restrict__ Alog, float* __restrict__ hstart,
    float* __restrict__ Aneg)
{
  const int NCH = 16;
  int idx = blockIdx.x*256 + threadIdx.x;
  int low = idx & 8191;
  int d = (idx >> 4) & 511, b = idx >> 13;
  float A = -__expf(Alog[low]);
  if (b == 0) Aneg[low] = A;
  float hs = 0.f;
  hstart[(b*NCH)*8192 + low] = 0.f;
  for (int c = 0; c < NCH-1; c++){
    float S  = sdtb[(b*NCH + c)*512 + d];
    float he = hend[(b*NCH + c)*8192 + low];
    hs = fmaf(__expf(A*S), hs, he);
    hstart[(b*NCH + c + 1)*8192 + low] = hs;
  }
}

__global__ __launch_bounds__(256) void k_corr(
    const float* __restrict__ yloc, const float* __restrict__ Scum,
    const float* __restrict__ hstart, const float* __restrict__ Aneg,
    const float* __restrict__ xd, const float* __restrict__ uc,
    const float* __restrict__ uz, const float* __restrict__ Dp,
    unsigned short* __restrict__ yg)
{
  __shared__ float sC[16];
  int row = blockIdx.x, tid = threadIdx.x;
  int b = row >> 10, t = row & 1023, ch = t >> 6;
  if (tid < 16) sC[tid] = xd[row*48 + 32 + tid];
  __syncthreads();
  #pragma unroll
  for (int rep = 0; rep < 2; rep++){
    int d = tid + rep*256;
    float Ss = Scum[row*512 + d];
    float y  = yloc[row*512 + d];
    const float* hs = hstart + ((b*16 + ch)*512 + d)*16;
    const float* An = Aneg + d*16;
    #pragma unroll
    for (int n = 0; n < 16; n++)
      y = fmaf(__expf(An[n]*Ss)*hs[n], sC[n], y);
    float uv = uc[row*512 + d];
    y = fmaf(uv, Dp[d], y);
    float zv = uz[(long)row*1024 + 512 + d];
    yg[row*512 + d] = f2bf(y*(zv/(1.f + __expf(-zv))));
  }
}

// ---------------- scale scan (DS=8, z-batched, single chunk) ---------------
__global__ __launch_bounds__(64) void k_scan_sc(
    const float* __restrict__ dt, const float* __restrict__ uc,
    const float* __restrict__ uz, const float* __restrict__ xd,
    const float* __restrict__ Alogb, const float* __restrict__ Dpb,
    unsigned short* __restrict__ yg)
{
  __shared__ float sdt[52][64], suc[52][64], sz[52][64];
  __shared__ float sBC[52][16];
  int tid = threadIdx.x;
  int dblk = blockIdx.x;
  int d = dblk*64 + tid;
  int b = blockIdx.y, z = blockIdx.z;
  int s = (z==0) ? 5 : (z==1) ? 20 : 50;
  int roff = (z==0) ? 0 : (z==1) ? 64 : 192;
  const float* Alog = Alogb + z*4096;
  const float* Dp   = Dpb + z*512;
  float A[8];
  #pragma unroll
  for (int n = 0; n < 8; n++) A[n] = -__expf(Alog[d*8 + n]);
  float Dv = Dp[d];
  for (int e = tid; e < s*16; e += 64){
    int t = e >> 4, q = (e & 15)*4;
    long row = (long)(roff + b*s + t);
    *(float4*)&sdt[t][q] = *(const float4*)(dt + row*512 + dblk*64 + q);
    *(float4*)&suc[t][q] = *(const float4*)(uc + row*512 + dblk*64 + q);
    *(float4*)&sz[t][q]  = *(const float4*)(uz + row*1024 + 512 + dblk*64 + q);
  }
  for (int e = tid; e < s*4; e += 64){
    int t = e >> 2, q = (e & 3)*4;
    long row = (long)(roff + b*s + t);
    *(float4*)&sBC[t][q] = *(const float4*)(xd + row*32 + 16 + q);
  }
  __syncthreads();
  float h[8];
  #pragma unroll
  for (int n = 0; n < 8; n++) h[n] = 0.f;
  for (int t = 0; t < s; t++){
    float dtv = sdt[t][tid];
    float uv  = suc[t][tid];
    float zv  = sz[t][tid];
    float du = dtv*uv;
    float y = 0.f;
    #pragma unroll
    for (int n = 0; n < 8; n++){
      h[n] = fmaf(__expf(dtv*A[n]), h[n], du*sBC[t][n]);
      y = fmaf(h[n], sBC[t][8+n], y);
    }
    y = fmaf(uv, Dv, y);
    float gate = zv/(1.f + __expf(-zv));
    yg[(long)(roff + b*s + t)*512 + d] = f2bf(y*gate);
  }
}

// ================== tail kernels (wide, multi-kernel) ======================
template<int M, int ACT, int RES>
__global__ __launch_bounds__(256) void k_tw(
    const float* __restrict__ A, const float* __restrict__ W,
    const float* __restrict__ bias, float* __restrict__ out,
    const float* __restrict__ resid, int N, int K, int ostride, int ocoff)
{
  extern __shared__ float sx[];
  int tid = threadIdx.x;
  for (int e = tid*4; e < M*K; e += 1024)
    *(float4*)&sx[e] = *(const float4*)(A + e);
  __syncthreads();
  int wave = tid >> 6, lane = tid & 63;
  int c = blockIdx.x*4 + wave;
  if (c >= N) return;
  float acc[M];
  #pragma unroll
  for (int r = 0; r < M; r++) acc[r] = 0.f;
  for (int k = lane*4; k < K; k += 256){
    float4 w4 = *(const float4*)(W + c*K + k);
    #pragma unroll
    for (int r = 0; r < M; r++){
      float4 x4 = *(float4*)&sx[r*K + k];
      acc[r] = fmaf(x4.x,w4.x,fmaf(x4.y,w4.y,fmaf(x4.z,w4.z,fmaf(x4.w,w4.w,acc[r]))));
    }
  }
  #pragma unroll
  for (int r = 0; r < M; r++){
    #pragma unroll
    for (int o = 32; o > 0; o >>= 1) acc[r] += __shfl_down(acc[r], o, 64);
  }
  if (lane == 0){
    float bv = bias[c];
    #pragma unroll
    for (int r = 0; r < M; r++){
      float v = acc[r] + bv;
      if (ACT == 1) v = geluf(v);
      if (RES == 1) v += resid[r*256 + c];
      out[r*ostride + ocoff + c] = v;
    }
  }
}

__global__ __launch_bounds__(256) void k_t_ln(
    const float* __restrict__ src, const float* __restrict__ g, const float* __restrict__ b,
    float* __restrict__ dst)
{
  __shared__ float r1[4], r2[4];
  int r = blockIdx.x, tid = threadIdx.x;
  float v = src[r*256 + tid];
  float s1 = v, s2 = v*v;
  #pragma unroll
  for (int o = 32; o > 0; o >>= 1){ s1 += __shfl_down(s1,o,64); s2 += __shfl_down(s2,o,64); }
  if ((tid & 63) == 0){ r1[tid>>6] = s1; r2[tid>>6] = s2; }
  __syncthreads();
  float S1 = r1[0]+r1[1]+r1[2]+r1[3];
  float S2 = r2[0]+r2[1]+r2[2]+r2[3];
  float m = S1*(1.f/256.f);
  float var = S2*(1.f/256.f) - m*m;
  dst[r*256 + tid] = (v - m)*rsqrtf(var + 1e-5f)*g[tid] + b[tid];
}

__global__ __launch_bounds__(256) void k_t_att(
    const float* __restrict__ qkv, float* __restrict__ ov)
{
  __shared__ float att[36];
  int b = blockIdx.x, tid = threadIdx.x;
  if (tid < 36){
    int hh = tid/9, r = (tid%9)/3, c = tid%3;
    float s = 0.f;
    const float* qp = qkv + (b*3 + r)*768 + hh*64;
    const float* kp = qkv + (b*3 + c)*768 + 256 + hh*64;
    for (int k = 0; k < 64; k++) s += qp[k]*kp[k];
    att[hh*9 + r*3 + c] = s*0.125f;
  }
  __syncthreads();
  if (tid < 12){
    int hh = tid/3, r = tid%3;
    float a0 = att[hh*9+r*3+0], a1 = att[hh*9+r*3+1], a2 = att[hh*9+r*3+2];
    float m = fmaxf(a0, fmaxf(a1, a2));
    float e0 = expf(a0-m), e1 = expf(a1-m), e2 = expf(a2-m);
    float s = e0+e1+e2;
    att[hh*9+r*3+0] = e0/s; att[hh*9+r*3+1] = e1/s; att[hh*9+r*3+2] = e2/s;
  }
  __syncthreads();
  for (int e = tid; e < 768; e += 256){
    int p = e >> 8, i = e & 255, hh = i >> 6;
    ov[(b*3 + p)*256 + i] = att[hh*9+p*3+0]*qkv[(b*3+0)*768+512+i]
                          + att[hh*9+p*3+1]*qkv[(b*3+1)*768+512+i]
                          + att[hh*9+p*3+2]*qkv[(b*3+2)*768+512+i];
  }
}

__global__ __launch_bounds__(256) void k_t_final(
    const float* __restrict__ fusedv, const float* __restrict__ s2f, float* __restrict__ finalv)
{
  int b = blockIdx.x, c = threadIdx.x;
  finalv[b*256 + c] = fusedv[b*256 + c] +
    (s2f[(b*3+0)*256 + c] + s2f[(b*3+1)*256 + c] + s2f[(b*3+2)*256 + c])*(1.f/3.f);
}

__global__ __launch_bounds__(64) void k_t_fin(
    const float* __restrict__ evraw, const float* __restrict__ ttraw, float* __restrict__ out)
{
  __shared__ float ev[7];
  __shared__ float S;
  int b = blockIdx.x, tid = threadIdx.x;
  if (tid < 7) ev[tid] = softplusf_(evraw[b*7 + tid]);
  __syncthreads();
  if (tid == 0){
    float s = 0.f;
    for (int j = 0; j < 7; j++) s += ev[j] + 1.f;
    S = s;
  }
  __syncthreads();
  float* ob = out + b*162;
  if (tid < 7){
    float al = ev[tid] + 1.f;
    ob[tid] = al / S;
    ob[7 + tid] = ev[tid];
    ob[14 + tid] = al;
  }
  if (tid == 0) ob[21] = 7.f / S;
  if (tid < 6){
    ob[22 + tid] = softplusf_(ttraw[b*12 + tid]);
    ob[28 + tid] = expf(0.5f*ttraw[b*12 + 6 + tid]);
  }
}

// ---------------------------------------------------------------------------
extern "C" void kernel_launch(void* const* d_in, const int* in_sizes, int n_in,
                              void* d_out, int out_size, void* d_ws, size_t ws_size,
                              hipStream_t stream)
{
  const float* x         = (const float*)d_in[0];
  const float* in_w      = (const float*)d_in[1];
  const float* in_b      = (const float*)d_in[2];
  const float* in_ln_g   = (const float*)d_in[3];
  const float* in_ln_b   = (const float*)d_in[4];
  const float* mb_ln_g   = (const float*)d_in[5];
  const float* mb_ln_b   = (const float*)d_in[6];
  const float* mb_in_w   = (const float*)d_in[7];
  const float* mb_conv_w = (const float*)d_in[8];
  const float* mb_conv_b = (const float*)d_in[9];
  const float* mb_xp_w   = (const float*)d_in[10];
  const float* mb_dt_w   = (const float*)d_in[11];
  const float* mb_dt_b   = (const float*)d_in[12];
  const float* mb_Alog   = (const float*)d_in[13];
  const float* mb_D      = (const float*)d_in[14];
  const float* mb_out_w  = (const float*)d_in[15];
  const float* sc_ln_g   = (const float*)d_in[16];
  const float* sc_ln_b   = (const float*)d_in[17];
  const float* sc_in_w   = (const float*)d_in[18];
  const float* sc_conv_w = (const float*)d_in[19];
  const float* sc_conv_b = (const float*)d_in[20];
  const float* sc_xp_w   = (const float*)d_in[21];
  const float* sc_dt_w   = (const float*)d_in[22];
  const float* sc_dt_b   = (const float*)d_in[23];
  const float* sc_Alog   = (const float*)d_in[24];
  const float* sc_D      = (const float*)d_in[25];
  const float* sc_out_w  = (const float*)d_in[26];
  const float* fus_qkv_w = (const float*)d_in[27];
  const float* fus_qkv_b = (const float*)d_in[28];
  const float* fus_out_w = (const float*)d_in[29];
  const float* fus_out_b = (const float*)d_in[30];
  const float* ms_out_w  = (const float*)d_in[31];
  const float* ms_out_b  = (const float*)d_in[32];
  const float* sa_ln1_g  = (const float*)d_in[33];
  const float* sa_ln1_b  = (const float*)d_in[34];
  const float* sa_ln2_g  = (const float*)d_in[35];
  const float* sa_ln2_b  = (const float*)d_in[36];
  const float* sa_qkv_w  = (const float*)d_in[37];
  const float* sa_qkv_b  = (const float*)d_in[38];
  const float* sa_out_w  = (const float*)d_in[39];
  const float* sa_out_b  = (const float*)d_in[40];
  const float* sa_ff1_w  = (const float*)d_in[41];
  const float* sa_ff1_b  = (const float*)d_in[42];
  const float* sa_ff2_w  = (const float*)d_in[43];
  const float* sa_ff2_b  = (const float*)d_in[44];
  const float* ev1_w     = (const float*)d_in[45];
  const float* ev1_b     = (const float*)d_in[46];
  const float* ev2_w     = (const float*)d_in[47];
  const float* ev2_b     = (const float*)d_in[48];
  const float* ttf1_w    = (const float*)d_in[49];
  const float* ttf1_b    = (const float*)d_in[50];
  const float* ttf2_w    = (const float*)d_in[51];
  const float* ttf2_b    = (const float*)d_in[52];
  const float* emb_w     = (const float*)d_in[53];
  const float* emb_b     = (const float*)d_in[54];

  float* ws = (float*)d_ws;
  float* h     = ws;                        // 1,048,576
  float* uz    = h    + 1048576;            // 4,194,304
  float* uc    = uz   + 4194304;            // 2,097,152
  float* dtb_  = uc   + 2097152;            // 2,097,152
  float* xd    = dtb_ + 2097152;            // 196,608
  float* stack = xd   + 196608;             // 4,096
  float* hend   = stack + 4096;          // 524,288
  float* hstart = hend + 524288;         // 524,288
  float* sdtb   = hstart + 524288;       // 32,768
  float* yloc   = sdtb + 32768;          // 2,097,152
  float* Scum   = yloc + 2097152;        // 2,097,152
  float* Aneg   = Scum + 2097152;        // 8,192
  float* qkvF   = Aneg + 8192;   // 9216
  float* ovF    = qkvF + 9216;   // 3072
  float* moF    = ovF  + 3072;   // 3072
  float* fusedv = moF  + 3072;   // 1024
  float* lnbuf  = fusedv + 1024; // 3072
  float* qkvS   = lnbuf + 3072;  // 9216
  float* ovS    = qkvS + 9216;   // 3072
  float* s2     = ovS  + 3072;   // 3072
  float* ln2r   = s2   + 3072;   // 3072
  float* hid    = ln2r + 3072;   // 12288
  float* s2f    = hid  + 12288;  // 3072
  float* finalv = s2f  + 3072;   // 1024
  float* evh    = finalv + 1024; // 1024
  float* tth    = evh  + 1024;   // 512
  float* evraw  = tth  + 512;    // 32
  float* ttraw  = evraw + 32;    // 64
  float* fp32_end = ttraw + 64;
  unsigned short* bfb = (unsigned short*)fp32_end;
  unsigned short* xnb    = bfb;                  // 1,048,576
  unsigned short* ucb    = xnb + 1048576;        // 2,097,152
  unsigned short* ygb    = ucb + 2097152;        // 2,097,152
  unsigned short* wmbin  = ygb + 2097152;        // 1,048,576
  unsigned short* wmbout = wmbin + 1048576;      // 524,288
  unsigned short* wmbxp  = wmbout + 524288;      // 98,304
  unsigned short* wscin  = wmbxp + 98304;        // 786,432
  unsigned short* wscout = wscin + 786432;       // 393,216
  unsigned short* wscxp  = wscout + 393216;      // 49,152

  k_f2b_all<<<2832, 256, 0, stream>>>(mb_in_w, wmbin, mb_out_w, wmbout, mb_xp_w, wmbxp,
                                      sc_in_w, wscin, sc_out_w, wscout, sc_xp_w, wscxp);

  k_inproj<<<4096, 256, 0, stream>>>(x, in_w, in_b, in_ln_g, in_ln_b, h);

  for (int l = 0; l < 4; l++){
    const float* Al = mb_Alog + l*8192;
    k_ln<<<4096, 256, 0, stream>>>(h, mb_ln_g + l*256, mb_ln_b + l*256, xnb);
    {
      dim3 g(16, 64);
      k_mm64<0,0><<<g, 256, 0, stream>>>(xnb, wmbin + l*262144, uz,
                                         nullptr, nullptr, 4096, 1024, 256, 0);
    }
    k_conv<<<4096, 256, 0, stream>>>(uz, mb_conv_w + l*2048, mb_conv_b + l*512, uc, ucb);
    k_xpdt<3,0><<<256, 512, 0, stream>>>(ucb, wmbxp + l*24576, xd,
                                         mb_dt_w + l*8192, mb_dt_b + l*512, dtb_, 4096);
    {
      dim3 g(8, 4, 16);
      k_scan_p1y<<<g, 256, 0, stream>>>(dtb_, uc, xd, Al, hend, sdtb, yloc, Scum);
      k_scomb<<<128, 256, 0, stream>>>(hend, sdtb, Al, hstart, Aneg);
      k_corr<<<4096, 256, 0, stream>>>(yloc, Scum, hstart, Aneg, xd, uc, uz,
                                       mb_D + l*512, ygb);
    }
    {
      dim3 g(4, 64);
      k_mm64<1,0><<<g, 256, 0, stream>>>(ygb, wmbout + l*131072, h,
                                         h, nullptr, 4096, 256, 512, 0);
    }
  }

  // ---- scale mambas (batched), pooled -> stack ----
  k_ln_sc<<<460, 256, 0, stream>>>(h, sc_ln_g, sc_ln_b, xnb, stack);
  {
    dim3 g(16, 7);
    k_mm64<0,1><<<g, 256, 0, stream>>>(xnb, wscin, uz, nullptr, nullptr,
                                       448, 1024, 256, 262144);
  }
  k_conv_sc<<<448, 256, 0, stream>>>(uz, sc_conv_w, sc_conv_b, uc, ucb);
  k_xpdt<2,1><<<28, 512, 0, stream>>>(ucb, wscxp, xd, sc_dt_w, sc_dt_b, dtb_, 448);
  {
    dim3 g(8, 4, 3);
    k_scan_sc<<<g, 64, 0, stream>>>(dtb_, uc, uz, xd, sc_Alog, sc_D, ygb);
  }
  {
    dim3 g(4, 7);
    k_mm64<2,1><<<g, 256, 0, stream>>>(ygb, wscout, nullptr, h, stack,
                                       448, 256, 512, 131072);
  }

  // ---- tail (wide multi-kernel) ----
  float* dout = (float*)d_out;
  k_tw<12,0,0><<<192, 256, 12*256*4, stream>>>(stack, fus_qkv_w, fus_qkv_b, qkvF, nullptr, 768, 256, 768, 0);
  k_t_att<<<4, 256, 0, stream>>>(qkvF, ovF);
  k_tw<12,0,0><<<64, 256, 12*256*4, stream>>>(ovF, fus_out_w, fus_out_b, moF, nullptr, 256, 256, 256, 0);
  k_tw<4,0,0><<<64, 256, 4*768*4, stream>>>(moF, ms_out_w, ms_out_b, fusedv, nullptr, 256, 768, 256, 0);
  k_t_ln<<<12, 256, 0, stream>>>(stack, sa_ln1_g, sa_ln1_b, lnbuf);
  k_tw<12,0,0><<<192, 256, 12*256*4, stream>>>(lnbuf, sa_qkv_w, sa_qkv_b, qkvS, nullptr, 768, 256, 768, 0);
  k_t_att<<<4, 256, 0, stream>>>(qkvS, ovS);
  k_tw<12,0,1><<<64, 256, 12*256*4, stream>>>(ovS, sa_out_w, sa_out_b, s2, stack, 256, 256, 256, 0);
  k_t_ln<<<12, 256, 0, stream>>>(s2, sa_ln2_g, sa_ln2_b, ln2r);
  k_tw<12,1,0><<<256, 256, 12*256*4, stream>>>(ln2r, sa_ff1_w, sa_ff1_b, hid, nullptr, 1024, 256, 1024, 0);
  k_tw<12,0,1><<<64, 256, 12*1024*4, stream>>>(hid, sa_ff2_w, sa_ff2_b, s2f, s2, 256, 1024, 256, 0);
  k_t_final<<<4, 256, 0, stream>>>(fusedv, s2f, finalv);
  k_tw<4,1,0><<<64, 256, 4*256*4, stream>>>(finalv, ev1_w, ev1_b, evh, nullptr, 256, 256, 256, 0);
  k_tw<4,0,0><<<2, 256, 4*256*4, stream>>>(evh, ev2_w, ev2_b, evraw, nullptr, 7, 256, 7, 0);
  k_tw<4,1,0><<<32, 256, 4*256*4, stream>>>(finalv, ttf1_w, ttf1_b, tth, nullptr, 128, 256, 128, 0);
  k_tw<4,0,0><<<3, 256, 4*128*4, stream>>>(tth, ttf2_w, ttf2_b, ttraw, nullptr, 12, 128, 12, 0);
  k_tw<4,0,0><<<32, 256, 4*256*4, stream>>>(finalv, emb_w, emb_b, dout, nullptr, 128, 256, 162, 34);
  k_t_fin<<<4, 64, 0, stream>>>(evraw, ttraw, dout);
}

// Round 16
// 620.713 us; speedup vs baseline: 1.2879x; 1.0054x over previous
//
#include <hip/hip_runtime.h>
#include <math.h>

// ---------------------------------------------------------------------------
// MambaPredictor forward. R15: bf16 u/z dataflow (uu fp32 u-half, zgb bf16
// z-half, ucb bf16 conv out; fp32 uc/uz eliminated) + tail launch merges
// (qkv2/att2/out2/heads). Structure = R15 (passing, 624 us).
// B=4 L=1024 NF=64 DM=256 DS=16 SCS=8 NL=4 DI=512 DTR=16 DC=4 NFM=6 NH=4
// ---------------------------------------------------------------------------

typedef short short8v __attribute__((ext_vector_type(8)));
typedef float f32x4   __attribute__((ext_vector_type(4)));

__device__ __forceinline__ float geluf(float x){ return 0.5f*x*(1.0f + erff(x*0.70710678118654752f)); }
__device__ __forceinline__ float softplusf_(float x){ return (x > 20.f) ? x : log1pf(expf(x)); }
__device__ __forceinline__ unsigned short f2bf(float f){
  unsigned int u = __float_as_uint(f);
  unsigned int r = (u + 0x7FFFu + ((u >> 16) & 1u)) >> 16;
  return (unsigned short)r;
}
__device__ __forceinline__ float bf2f(unsigned short u){
  return __uint_as_float(((unsigned int)u) << 16);
}

__device__ __forceinline__ void sc_region(int r, int& z, int& roff, int& s){
  if (r < 64){ z=0; roff=0; s=5; }
  else if (r < 192){ z=1; roff=64; s=20; }
  else { z=2; roff=192; s=50; }
}

// ---------------- merged fp32 -> bf16 weight convert (6 segments) ----------
__global__ __launch_bounds__(256) void k_f2b_all(
    const float* s0, unsigned short* d0,
    const float* s1, unsigned short* d1,
    const float* s2, unsigned short* d2,
    const float* s3, unsigned short* d3,
    const float* s4, unsigned short* d4,
    const float* s5, unsigned short* d5)
{
  int blk = blockIdx.x;
  const float* s; unsigned short* d; int base;
  if      (blk < 1024){ s=s0; d=d0; base=0; }
  else if (blk < 1536){ s=s1; d=d1; base=1024; }
  else if (blk < 1632){ s=s2; d=d2; base=1536; }
  else if (blk < 2400){ s=s3; d=d3; base=1632; }
  else if (blk < 2784){ s=s4; d=d4; base=2400; }
  else                { s=s5; d=d5; base=2784; }
  int i = ((blk - base)*256 + threadIdx.x)*4;
  float4 v = *(const float4*)(s + i);
  *(ushort4*)(d + i) = make_ushort4(f2bf(v.x), f2bf(v.y), f2bf(v.z), f2bf(v.w));
}

// ---------------- initial: h = gelu(LN(x @ in_w^T + in_b)) -----------------
__global__ __launch_bounds__(256) void k_inproj(
    const float* __restrict__ x, const float* __restrict__ w,
    const float* __restrict__ b, const float* __restrict__ g,
    const float* __restrict__ beta, float* __restrict__ h)
{
  __shared__ float xr[64];
  __shared__ float r1[4], r2[4];
  int row = blockIdx.x;
  int tid = threadIdx.x;
  if (tid < 64) xr[tid] = x[row*64 + tid];
  __syncthreads();
  float acc = b[tid];
  const float* wr = w + tid*64;
  #pragma unroll
  for (int k = 0; k < 64; k++) acc += xr[k]*wr[k];
  float s1 = acc, s2 = acc*acc;
  #pragma unroll
  for (int o = 32; o > 0; o >>= 1){ s1 += __shfl_down(s1,o,64); s2 += __shfl_down(s2,o,64); }
  if ((tid & 63) == 0){ r1[tid>>6] = s1; r2[tid>>6] = s2; }
  __syncthreads();
  float S1 = r1[0]+r1[1]+r1[2]+r1[3];
  float S2 = r2[0]+r2[1]+r2[2]+r2[3];
  float m = S1*(1.f/256.f);
  float var = S2*(1.f/256.f) - m*m;
  float xn = (acc - m)*rsqrtf(var + 1e-5f)*g[tid] + beta[tid];
  h[row*256 + tid] = geluf(xn);
}

// ---------------- LayerNorm over 256 -> bf16 (main layers) -----------------
__global__ __launch_bounds__(256) void k_ln(
    const float* __restrict__ src, const float* __restrict__ g, const float* __restrict__ beta,
    unsigned short* __restrict__ dst)
{
  __shared__ float r1[4], r2[4];
  int r = blockIdx.x, tid = threadIdx.x;
  float v = src[r*256 + tid];
  float s1 = v, s2 = v*v;
  #pragma unroll
  for (int o = 32; o > 0; o >>= 1){ s1 += __shfl_down(s1,o,64); s2 += __shfl_down(s2,o,64); }
  if ((tid & 63) == 0){ r1[tid>>6] = s1; r2[tid>>6] = s2; }
  __syncthreads();
  float S1 = r1[0]+r1[1]+r1[2]+r1[3];
  float S2 = r2[0]+r2[1]+r2[2]+r2[3];
  float m = S1*(1.f/256.f);
  float var = S2*(1.f/256.f) - m*m;
  dst[r*256 + tid] = f2bf((v - m)*rsqrtf(var + 1e-5f)*g[tid] + beta[tid]);
}

// ---------------- scale LN (grid 460: 448 LN rows + 12 stack-zero blocks) --
__global__ __launch_bounds__(256) void k_ln_sc(
    const float* __restrict__ h, const float* __restrict__ gb, const float* __restrict__ bb,
    unsigned short* __restrict__ dst, float* __restrict__ stack)
{
  __shared__ float r1[4], r2[4];
  int r = blockIdx.x, tid = threadIdx.x;
  if (r >= 448){
    int idx = (r - 448)*256 + tid;
    if (idx < 3072) stack[idx] = 0.f;
    return;
  }
  int z, roff, s; sc_region(r, z, roff, s);
  int local = r - roff;
  if (local >= 4*s) return;
  int b = local / s, t = local % s;
  float v = h[(b*1024 + (1024 - s) + t)*256 + tid];
  const float* g = gb + z*256; const float* be = bb + z*256;
  float s1 = v, s2 = v*v;
  #pragma unroll
  for (int o = 32; o > 0; o >>= 1){ s1 += __shfl_down(s1,o,64); s2 += __shfl_down(s2,o,64); }
  if ((tid & 63) == 0){ r1[tid>>6] = s1; r2[tid>>6] = s2; }
  __syncthreads();
  float S1 = r1[0]+r1[1]+r1[2]+r1[3];
  float S2 = r2[0]+r2[1]+r2[2]+r2[3];
  float m = S1*(1.f/256.f);
  float var = S2*(1.f/256.f) - m*m;
  dst[r*256 + tid] = f2bf((v - m)*rsqrtf(var + 1e-5f)*g[tid] + be[tid]);
}

// ---------------- MFMA GEMM: C = A(M,K)bf16 @ W(N,K)bf16^T, fp32 acc -------
// MODE 0 (in-proj, N=1024): u-cols (<512) -> C fp32 stride 512; z-cols -> zgb bf16.
// MODE 1: C = resid + v (out-proj). MODE 2: scale pool atomicAdd.
template<int MODE, int SCB>
__global__ __launch_bounds__(256) void k_mm64(
    const unsigned short* __restrict__ A, const unsigned short* __restrict__ Wb,
    float* __restrict__ C,
    const float* __restrict__ resid,
    float* __restrict__ pool_out,
    unsigned short* __restrict__ zgb,
    int M, int N, int K, int wstr)
{
  int tid = threadIdx.x;
  int wave = tid >> 6, lane = tid & 63;
  int mh = wave & 1, nh = wave >> 1;
  int m0 = blockIdx.y*64 + mh*32;
  int n0 = blockIdx.x*64 + nh*32;
  int z = 0, roff = 0, sc = 0;
  const unsigned short* W = Wb;
  if (SCB){ sc_region(blockIdx.y*64, z, roff, sc); W += z*wstr; }
  int lrow = lane & 15, kc = lane >> 4;
  f32x4 acc[2][2] = {{{0.f,0.f,0.f,0.f},{0.f,0.f,0.f,0.f}},{{0.f,0.f,0.f,0.f},{0.f,0.f,0.f,0.f}}};
  for (int k0 = 0; k0 < K; k0 += 32){
    short8v a[2], b[2];
    #pragma unroll
    for (int mi = 0; mi < 2; mi++){
      int r = m0 + mi*16 + lrow; r = min(r, M-1);
      a[mi] = *(const short8v*)(A + r*K + k0 + kc*8);
    }
    #pragma unroll
    for (int ni = 0; ni < 2; ni++){
      int c = n0 + ni*16 + lrow;
      b[ni] = *(const short8v*)(W + c*K + k0 + kc*8);
    }
    #pragma unroll
    for (int mi = 0; mi < 2; mi++)
      #pragma unroll
      for (int ni = 0; ni < 2; ni++)
        acc[mi][ni] = __builtin_amdgcn_mfma_f32_16x16x32_bf16(a[mi], b[ni], acc[mi][ni], 0, 0, 0);
  }
  int rb = kc*4;
  #pragma unroll
  for (int mi = 0; mi < 2; mi++){
    #pragma unroll
    for (int rr = 0; rr < 4; rr++){
      int grow = m0 + mi*16 + rb + rr;
      if (grow >= M) continue;
      #pragma unroll
      for (int ni = 0; ni < 2; ni++){
        int gcol = n0 + ni*16 + lrow;
        float v = acc[mi][ni][rr];
        if (MODE == 0){
          if (gcol < 512) C[(long)grow*512 + gcol] = v;
          else zgb[(long)grow*512 + (gcol - 512)] = f2bf(v);
        } else if (MODE == 1){
          C[grow*N + gcol] = resid[grow*256 + gcol] + v;
        } else {
          int local = grow - roff;
          if (local < 4*sc){
            int bb2 = local / sc, t = local % sc;
            float rv = resid[(bb2*1024 + (1024 - sc) + t)*256 + gcol] + v;
            atomicAdd(&pool_out[bb2*768 + z*256 + gcol], rv*(1.f/(float)sc));
          }
        }
      }
    }
  }
}

// ---------------- depthwise causal conv (DC=4) + SiLU -> bf16 only ---------
__global__ __launch_bounds__(256) void k_conv(
    const float* __restrict__ uu, const float* __restrict__ cw, const float* __restrict__ cb,
    unsigned short* __restrict__ ucb)
{
  int row = blockIdx.x;
  int t = row & 1023;
  int tid = threadIdx.x;
  for (int d = tid; d < 512; d += 256){
    float acc = cb[d];
    const float* w = cw + d*4;
    #pragma unroll
    for (int k = 0; k < 4; k++){
      int ts = t - 3 + k;
      if (ts >= 0) acc += uu[(long)(row - (3-k))*512 + d]*w[k];
    }
    float s = acc/(1.f + expf(-acc));
    ucb[(long)row*512 + d] = f2bf(s);
  }
}

__global__ __launch_bounds__(256) void k_conv_sc(
    const float* __restrict__ uu, const float* __restrict__ cwb, const float* __restrict__ cbb,
    unsigned short* __restrict__ ucb)
{
  int row = blockIdx.x;
  int z, roff, s; sc_region(row, z, roff, s);
  int local = row - roff;
  if (local >= 4*s) return;
  int t = local % s;
  const float* cw = cwb + z*2048;
  const float* cb = cbb + z*512;
  int tid = threadIdx.x;
  for (int d = tid; d < 512; d += 256){
    float acc = cb[d];
    const float* w = cw + d*4;
    #pragma unroll
    for (int k = 0; k < 4; k++){
      int ts = t - 3 + k;
      if (ts >= 0) acc += uu[(long)(row - (3-k))*512 + d]*w[k];
    }
    float sv = acc/(1.f + expf(-acc));
    ucb[(long)row*512 + d] = f2bf(sv);
  }
}

// ---- split-K wide xp GEMM + fused dt (8-wave, K=64 per wave) ---------------
template<int NT, int SCB>
__global__ __launch_bounds__(512) void k_xpdt(
    const unsigned short* __restrict__ A, const unsigned short* __restrict__ Wb,
    float* __restrict__ xdout,
    const float* __restrict__ dtwb, const float* __restrict__ dtbb,
    float* __restrict__ dtout, int M)
{
  const int K = 512;
  const int NC = NT*16;
  __shared__ float pacc[8][16][NC];
  __shared__ float sxd[16][16];
  int tid = threadIdx.x;
  int wave = tid >> 6, lane = tid & 63;
  int bm0 = blockIdx.x*16;
  const unsigned short* W = Wb;
  const float* dtw = dtwb;
  const float* dtb = dtbb;
  if (SCB){
    int z, roff, s; sc_region(bm0, z, roff, s);
    W += z*(NC*K); dtw += z*8192; dtb += z*512;
  }
  int lrow = lane & 15, kc = lane >> 4;
  int kbase = wave*64;
  f32x4 acc[NT];
  #pragma unroll
  for (int ni = 0; ni < NT; ni++) acc[ni] = (f32x4){0.f,0.f,0.f,0.f};
  #pragma unroll
  for (int k0 = 0; k0 < 64; k0 += 32){
    short8v a = *(const short8v*)(A + (long)(bm0 + lrow)*K + kbase + k0 + kc*8);
    #pragma unroll
    for (int ni = 0; ni < NT; ni++){
      short8v b = *(const short8v*)(W + (ni*16 + lrow)*K + kbase + k0 + kc*8);
      acc[ni] = __builtin_amdgcn_mfma_f32_16x16x32_bf16(a, b, acc[ni], 0, 0, 0);
    }
  }
  int rb = kc*4;
  #pragma unroll
  for (int rr = 0; rr < 4; rr++)
    #pragma unroll
    for (int ni = 0; ni < NT; ni++)
      pacc[wave][rb + rr][ni*16 + lrow] = acc[ni][rr];
  __syncthreads();
  for (int e = tid; e < 16*NC; e += 512){
    int r = e / NC, c = e % NC;
    float v = pacc[0][r][c] + pacc[1][r][c] + pacc[2][r][c] + pacc[3][r][c]
            + pacc[4][r][c] + pacc[5][r][c] + pacc[6][r][c] + pacc[7][r][c];
    xdout[(bm0 + r)*NC + c] = v;
    if (c < 16) sxd[r][c] = v;
  }
  __syncthreads();
  int d0 = tid;
  float w0[16];
  #pragma unroll
  for (int j = 0; j < 16; j++) w0[j] = dtw[d0*16 + j];
  float b0 = dtb[d0];
  #pragma unroll
  for (int r = 0; r < 16; r++){
    float a0 = b0;
    #pragma unroll
    for (int j = 0; j < 16; j++)
      a0 = fmaf(sxd[r][j], w0[j], a0);
    dtout[(bm0 + r)*512 + d0] = softplusf_(a0);
  }
}

// ============ chunked scan: p1 (256-thr staging, bf16 uc) + p2 + corr ======
__global__ __launch_bounds__(256) void k_scan_p1y(
    const float* __restrict__ dt, const unsigned short* __restrict__ ucb,
    const float* __restrict__ xd, const float* __restrict__ Alog,
    float* __restrict__ hend, float* __restrict__ sdtb,
    float* __restrict__ yloc, float* __restrict__ Scum)
{
  const int CL = 64, NCH = 16;
  __shared__ float sdt[64][64], suc[64][64];
  __shared__ float sBC[64][32];
  int tid = threadIdx.x;
  int dblk = blockIdx.x;
  int b = blockIdx.y, ch = blockIdx.z;
  int t0 = ch*CL;
  for (int e = tid; e < CL*16; e += 256){
    int t = e >> 4, q = (e & 15)*4;
    long off = (long)(b*1024 + t0 + t)*512 + dblk*64 + q;
    *(float4*)&sdt[t][q] = *(const float4*)(dt + off);
  }
  for (int e = tid; e < CL*8; e += 256){
    int t = e >> 3, q = (e & 7)*8;
    long off = (long)(b*1024 + t0 + t)*512 + dblk*64 + q;
    short8v u8 = *(const short8v*)(ucb + off);
    #pragma unroll
    for (int j = 0; j < 8; j++) suc[t][q + j] = bf2f((unsigned short)u8[j]);
  }
  for (int e = tid; e < CL*8; e += 256){
    int t = e >> 3, q = (e & 7)*4;
    *(float4*)&sBC[t][q] = *(const float4*)(xd + (long)(b*1024 + t0 + t)*48 + 16 + q);
  }
  __syncthreads();
  if (tid < 64){
    int d = dblk*64 + tid;
    float A[16];
    #pragma unroll
    for (int n = 0; n < 16; n++) A[n] = -__expf(Alog[d*16 + n]);
    float h[16];
    #pragma unroll
    for (int n = 0; n < 16; n++) h[n] = 0.f;
    float Ss = 0.f;
    #pragma unroll 2
    for (int t = 0; t < CL; t++){
      float dtv = sdt[t][tid];
      float uv  = suc[t][tid];
      Ss += dtv;
      float du = dtv*uv;
      float y = 0.f;
      #pragma unroll
      for (int n = 0; n < 16; n++){
        h[n] = fmaf(__expf(dtv*A[n]), h[n], du*sBC[t][n]);
        y = fmaf(h[n], sBC[t][16+n], y);
      }
      long row = (long)(b*1024 + t0 + t);
      yloc[row*512 + d] = y;
      Scum[row*512 + d] = Ss;
    }
    int base = ((b*NCH + ch)*512 + d)*16;
    #pragma unroll
    for (int q = 0; q < 4; q++)
      *(float4*)(hend + base + q*4) = make_float4(h[q*4], h[q*4+1], h[q*4+2], h[q*4+3]);
    sdtb[(b*NCH + ch)*512 + d] = Ss;
  }
}

__global__ __launch_bounds__(256) void k_scomb(
    const float* __restrict__ hend, const float* __restrict__ sdtb,
    const float* __restrict__ Alog, float* __restrict__ hstart,
    float* __restrict__ Aneg)
{
  const int NCH = 16;
  int idx = blockIdx.x*256 + threadIdx.x;
  int low = idx & 8191;
  int d = (idx >> 4) & 511, b = idx >> 13;
  float A = -__expf(Alog[low]);
  if (b == 0) Aneg[low] = A;
  float hs = 0.f;
  hstart[(b*NCH)*8192 + low] = 0.f;
  for (int c = 0; c < NCH-1; c++){
    float S  = sdtb[(b*NCH + c)*512 + d];
    float he = hend[(b*NCH + c)*8192 + low];
    hs = fmaf(__expf(A*S), hs, he);
    hstart[(b*NCH + c + 1)*8192 + low] = hs;
  }
}

__global__ __launch_bounds__(256) void k_corr(
    const float* __restrict__ yloc, const float* __restrict__ Scum,
    const float* __restrict__ hstart, const float* __restrict__ Aneg,
    const float* __restrict__ xd, const unsigned short* __restrict__ ucb,
    const unsigned short* __restrict__ zgb, const float* __restrict__ Dp,
    unsigned short* __restrict__ yg)
{
  __shared__ float sC[16];
  int row = blockIdx.x, tid = threadIdx.x;
  int b = row >> 10, t = row & 1023, ch = t >> 6;
  if (tid < 16) sC[tid] = xd[row*48 + 32 + tid];
  __syncthreads();
  #pragma unroll
  for (int rep = 0; rep < 2; rep++){
    int d = tid + rep*256;
    float Ss = Scum[row*512 + d];
    float y  = yloc[row*512 + d];
    const float* hs = hstart + ((b*16 + ch)*512 + d)*16;
    const float* An = Aneg + d*16;
    #pragma unroll
    for (int n = 0; n < 16; n++)
      y = fmaf(__expf(An[n]*Ss)*hs[n], sC[n], y);
    float uv = bf2f(ucb[(long)row*512 + d]);
    y = fmaf(uv, Dp[d], y);
    float zv = bf2f(zgb[(long)row*512 + d]);
    yg[row*512 + d] = f2bf(y*(zv/(1.f + __expf(-zv))));
  }
}

// ---------------- scale scan (DS=8, z-batched, bf16 u/z) -------------------
__global__ __launch_bounds__(64) void k_scan_sc(
    const float* __restrict__ dt, const unsigned short* __restrict__ ucb,
    const unsigned short* __restrict__ zgb, const float* __restrict__ xd,
    const float* __restrict__ Alogb, const float* __restrict__ Dpb,
    unsigned short* __restrict__ yg)
{
  __shared__ float sdt[52][64], suc[52][64], sz[52][64];
  __shared__ float sBC[52][16];
  int tid = threadIdx.x;
  int dblk = blockIdx.x;
  int d = dblk*64 + tid;
  int b = blockIdx.y, z = blockIdx.z;
  int s = (z==0) ? 5 : (z==1) ? 20 : 50;
  int roff = (z==0) ? 0 : (z==1) ? 64 : 192;
  const float* Alog = Alogb + z*4096;
  const float* Dp   = Dpb + z*512;
  float A[8];
  #pragma unroll
  for (int n = 0; n < 8; n++) A[n] = -__expf(Alog[d*8 + n]);
  float Dv = Dp[d];
  for (int e = tid; e < s*16; e += 64){
    int t = e >> 4, q = (e & 15)*4;
    long row = (long)(roff + b*s + t);
    *(float4*)&sdt[t][q] = *(const float4*)(dt + row*512 + dblk*64 + q);
  }
  for (int e = tid; e < s*8; e += 64){
    int t = e >> 3, q = (e & 7)*8;
    long row = (long)(roff + b*s + t);
    short8v u8 = *(const short8v*)(ucb + row*512 + dblk*64 + q);
    short8v z8 = *(const short8v*)(zgb + row*512 + dblk*64 + q);
    #pragma unroll
    for (int j = 0; j < 8; j++){
      suc[t][q + j] = bf2f((unsigned short)u8[j]);
      sz[t][q + j]  = bf2f((unsigned short)z8[j]);
    }
  }
  for (int e = tid; e < s*4; e += 64){
    int t = e >> 2, q = (e & 3)*4;
    long row = (long)(roff + b*s + t);
    *(float4*)&sBC[t][q] = *(const float4*)(xd + row*32 + 16 + q);
  }
  __syncthreads();
  float h[8];
  #pragma unroll
  for (int n = 0; n < 8; n++) h[n] = 0.f;
  for (int t = 0; t < s; t++){
    float dtv = sdt[t][tid];
    float uv  = suc[t][tid];
    float zv  = sz[t][tid];
    float du = dtv*uv;
    float y = 0.f;
    #pragma unroll
    for (int n = 0; n < 8; n++){
      h[n] = fmaf(__expf(dtv*A[n]), h[n], du*sBC[t][n]);
      y = fmaf(h[n], sBC[t][8+n], y);
    }
    y = fmaf(uv, Dv, y);
    float gate = zv/(1.f + __expf(-zv));
    yg[(long)(roff + b*s + t)*512 + d] = f2bf(y*gate);
  }
}

// ================== tail kernels ==========================================
template<int M, int ACT, int RES>
__global__ __launch_bounds__(256) void k_tw(
    const float* __restrict__ A, const float* __restrict__ W,
    const float* __restrict__ bias, float* __restrict__ out,
    const float* __restrict__ resid, int N, int K, int ostride, int ocoff)
{
  extern __shared__ float sx[];
  int tid = threadIdx.x;
  for (int e = tid*4; e < M*K; e += 1024)
    *(float4*)&sx[e] = *(const float4*)(A + e);
  __syncthreads();
  int wave = tid >> 6, lane = tid & 63;
  int c = blockIdx.x*4 + wave;
  if (c >= N) return;
  float acc[M];
  #pragma unroll
  for (int r = 0; r < M; r++) acc[r] = 0.f;
  for (int k = lane*4; k < K; k += 256){
    float4 w4 = *(const float4*)(W + c*K + k);
    #pragma unroll
    for (int r = 0; r < M; r++){
      float4 x4 = *(float4*)&sx[r*K + k];
      acc[r] = fmaf(x4.x,w4.x,fmaf(x4.y,w4.y,fmaf(x4.z,w4.z,fmaf(x4.w,w4.w,acc[r]))));
    }
  }
  #pragma unroll
  for (int r = 0; r < M; r++){
    #pragma unroll
    for (int o = 32; o > 0; o >>= 1) acc[r] += __shfl_down(acc[r], o, 64);
  }
  if (lane == 0){
    float bv = bias[c];
    #pragma unroll
    for (int r = 0; r < M; r++){
      float v = acc[r] + bv;
      if (ACT == 1) v = geluf(v);
      if (RES == 1) v += resid[r*256 + c];
      out[r*ostride + ocoff + c] = v;
    }
  }
}

// merged QKV: blocks 0-191 fus (stack), 192-383 sa (lnbuf)
__global__ __launch_bounds__(256) void k_qkv2(
    const float* __restrict__ A0, const float* __restrict__ A1,
    const float* __restrict__ W0, const float* __restrict__ B0,
    const float* __restrict__ W1, const float* __restrict__ B1,
    float* __restrict__ O0, float* __restrict__ O1)
{
  __shared__ float sx[3072];
  int tid = threadIdx.x;
  int sel = blockIdx.x >= 192;
  const float* A = sel ? A1 : A0;
  for (int e = tid*4; e < 3072; e += 1024)
    *(float4*)&sx[e] = *(const float4*)(A + e);
  __syncthreads();
  int wave = tid >> 6, lane = tid & 63;
  int c = (blockIdx.x - (sel ? 192 : 0))*4 + wave;
  const float* W = sel ? W1 : W0;
  const float* B = sel ? B1 : B0;
  float* O = sel ? O1 : O0;
  float acc[12];
  #pragma unroll
  for (int r = 0; r < 12; r++) acc[r] = 0.f;
  {
    int k = lane*4;
    float4 w4 = *(const float4*)(W + c*256 + k);
    #pragma unroll
    for (int r = 0; r < 12; r++){
      float4 x4 = *(float4*)&sx[r*256 + k];
      acc[r] = fmaf(x4.x,w4.x,fmaf(x4.y,w4.y,fmaf(x4.z,w4.z,fmaf(x4.w,w4.w,acc[r]))));
    }
  }
  #pragma unroll
  for (int r = 0; r < 12; r++){
    #pragma unroll
    for (int o = 32; o > 0; o >>= 1) acc[r] += __shfl_down(acc[r], o, 64);
  }
  if (lane == 0){
    float bv = B[c];
    #pragma unroll
    for (int r = 0; r < 12; r++) O[r*768 + c] = acc[r] + bv;
  }
}

// merged attention: 8 blocks = {fus,sa} x 4 batches
__global__ __launch_bounds__(256) void k_att2(
    const float* __restrict__ qkvF, float* __restrict__ ovF,
    const float* __restrict__ qkvS, float* __restrict__ ovS)
{
  __shared__ float att[36];
  int sel = blockIdx.x >> 2, b = blockIdx.x & 3, tid = threadIdx.x;
  const float* qkv = sel ? qkvS : qkvF;
  float* ov = sel ? ovS : ovF;
  if (tid < 36){
    int hh = tid/9, r = (tid%9)/3, c = tid%3;
    float s = 0.f;
    const float* qp = qkv + (b*3 + r)*768 + hh*64;
    const float* kp = qkv + (b*3 + c)*768 + 256 + hh*64;
    for (int k = 0; k < 64; k++) s += qp[k]*kp[k];
    att[hh*9 + r*3 + c] = s*0.125f;
  }
  __syncthreads();
  if (tid < 12){
    int hh = tid/3, r = tid%3;
    float a0 = att[hh*9+r*3+0], a1 = att[hh*9+r*3+1], a2 = att[hh*9+r*3+2];
    float m = fmaxf(a0, fmaxf(a1, a2));
    float e0 = expf(a0-m), e1 = expf(a1-m), e2 = expf(a2-m);
    float s = e0+e1+e2;
    att[hh*9+r*3+0] = e0/s; att[hh*9+r*3+1] = e1/s; att[hh*9+r*3+2] = e2/s;
  }
  __syncthreads();
  for (int e = tid; e < 768; e += 256){
    int p = e >> 8, i = e & 255, hh = i >> 6;
    ov[(b*3 + p)*256 + i] = att[hh*9+p*3+0]*qkv[(b*3+0)*768+512+i]
                          + att[hh*9+p*3+1]*qkv[(b*3+1)*768+512+i]
                          + att[hh*9+p*3+2]*qkv[(b*3+2)*768+512+i];
  }
}

// merged out-proj: blocks 0-63 fus (moF), 64-127 sa (+stack resid -> s2)
__global__ __launch_bounds__(256) void k_out2(
    const float* __restrict__ ovF, const float* __restrict__ ovS,
    const float* __restrict__ fow, const float* __restrict__ fob,
    const float* __restrict__ sow, const float* __restrict__ sob,
    const float* __restrict__ stack, float* __restrict__ moF, float* __restrict__ s2)
{
  __shared__ float sx[3072];
  int tid = threadIdx.x;
  int sel = blockIdx.x >= 64;
  const float* A = sel ? ovS : ovF;
  for (int e = tid*4; e < 3072; e += 1024)
    *(float4*)&sx[e] = *(const float4*)(A + e);
  __syncthreads();
  int wave = tid >> 6, lane = tid & 63;
  int c = (blockIdx.x - (sel ? 64 : 0))*4 + wave;
  const float* W = sel ? sow : fow;
  const float* B = sel ? sob : fob;
  float acc[12];
  #pragma unroll
  for (int r = 0; r < 12; r++) acc[r] = 0.f;
  {
    int k = lane*4;
    float4 w4 = *(const float4*)(W + c*256 + k);
    #pragma unroll
    for (int r = 0; r < 12; r++){
      float4 x4 = *(float4*)&sx[r*256 + k];
      acc[r] = fmaf(x4.x,w4.x,fmaf(x4.y,w4.y,fmaf(x4.z,w4.z,fmaf(x4.w,w4.w,acc[r]))));
    }
  }
  #pragma unroll
  for (int r = 0; r < 12; r++){
    #pragma unroll
    for (int o = 32; o > 0; o >>= 1) acc[r] += __shfl_down(acc[r], o, 64);
  }
  if (lane == 0){
    float bv = B[c];
    #pragma unroll
    for (int r = 0; r < 12; r++){
      float v = acc[r] + bv;
      if (sel) s2[r*256 + c] = v + stack[r*256 + c];
      else     moF[r*256 + c] = v;
    }
  }
}

// merged heads: 0-63 ev1(gelu,256), 64-95 ttf1(gelu,128), 96-127 emb(128)
__global__ __launch_bounds__(256) void k_heads(
    const float* __restrict__ finalv,
    const float* __restrict__ e1w, const float* __restrict__ e1b, float* __restrict__ evh,
    const float* __restrict__ t1w, const float* __restrict__ t1b, float* __restrict__ tth,
    const float* __restrict__ ew, const float* __restrict__ eb, float* __restrict__ dout)
{
  __shared__ float sx[1024];
  int tid = threadIdx.x;
  if (tid < 256){
    float4 v = *(const float4*)(finalv + tid*4);
    *(float4*)&sx[tid*4] = v;
  }
  __syncthreads();
  int wave = tid >> 6, lane = tid & 63;
  int blk = blockIdx.x;
  const float* W; const float* B; int c; int which;
  if (blk < 64){ which = 0; c = blk*4 + wave; W = e1w; B = e1b; }
  else if (blk < 96){ which = 1; c = (blk - 64)*4 + wave; W = t1w; B = t1b; }
  else { which = 2; c = (blk - 96)*4 + wave; W = ew; B = eb; }
  float acc[4] = {0.f,0.f,0.f,0.f};
  {
    int k = lane*4;
    float4 w4 = *(const float4*)(W + c*256 + k);
    #pragma unroll
    for (int r = 0; r < 4; r++){
      float4 x4 = *(float4*)&sx[r*256 + k];
      acc[r] = fmaf(x4.x,w4.x,fmaf(x4.y,w4.y,fmaf(x4.z,w4.z,fmaf(x4.w,w4.w,acc[r]))));
    }
  }
  #pragma unroll
  for (int r = 0; r < 4; r++){
    #pragma unroll
    for (int o = 32; o > 0; o >>= 1) acc[r] += __shfl_down(acc[r], o, 64);
  }
  if (lane == 0){
    float bv = B[c];
    #pragma unroll
    for (int r = 0; r < 4; r++){
      float v = acc[r] + bv;
      if (which == 0) evh[r*256 + c] = geluf(v);
      else if (which == 1) tth[r*128 + c] = geluf(v);
      else dout[r*162 + 34 + c] = v;
    }
  }
}

__global__ __launch_bounds__(256) void k_t_ln(
    const float* __restrict__ src, const float* __restrict__ g, const float* __restrict__ b,
    float* __restrict__ dst)
{
  __shared__ float r1[4], r2[4];
  int r = blockIdx.x, tid = threadIdx.x;
  float v = src[r*256 + tid];
  float s1 = v, s2 = v*v;
  #pragma unroll
  for (int o = 32; o > 0; o >>= 1){ s1 += __shfl_down(s1,o,64); s2 += __shfl_down(s2,o,64); }
  if ((tid & 63) == 0){ r1[tid>>6] = s1; r2[tid>>6] = s2; }
  __syncthreads();
  float S1 = r1[0]+r1[1]+r1[2]+r1[3];
  float S2 = r2[0]+r2[1]+r2[2]+r2[3];
  float m = S1*(1.f/256.f);
  float var = S2*(1.f/256.f) - m*m;
  dst[r*256 + tid] = (v - m)*rsqrtf(var + 1e-5f)*g[tid] + b[tid];
}

__global__ __launch_bounds__(256) void k_t_final(
    const float* __restrict__ fusedv, const float* __restrict__ s2f, float* __restrict__ finalv)
{
  int b = blockIdx.x, c = threadIdx.x;
  finalv[b*256 + c] = fusedv[b*256 + c] +
    (s2f[(b*3+0)*256 + c] + s2f[(b*3+1)*256 + c] + s2f[(b*3+2)*256 + c])*(1.f/3.f);
}

__global__ __launch_bounds__(64) void k_t_fin(
    const float* __restrict__ evraw, const float* __restrict__ ttraw, float* __restrict__ out)
{
  __shared__ float ev[7];
  __shared__ float S;
  int b = blockIdx.x, tid = threadIdx.x;
  if (tid < 7) ev[tid] = softplusf_(evraw[b*7 + tid]);
  __syncthreads();
  if (tid == 0){
    float s = 0.f;
    for (int j = 0; j < 7; j++) s += ev[j] + 1.f;
    S = s;
  }
  __syncthreads();
  float* ob = out + b*162;
  if (tid < 7){
    float al = ev[tid] + 1.f;
    ob[tid] = al / S;
    ob[7 + tid] = ev[tid];
    ob[14 + tid] = al;
  }
  if (tid == 0) ob[21] = 7.f / S;
  if (tid < 6){
    ob[22 + tid] = softplusf_(ttraw[b*12 + tid]);
    ob[28 + tid] = expf(0.5f*ttraw[b*12 + 6 + tid]);
  }
}

// ---------------------------------------------------------------------------
extern "C" void kernel_launch(void* const* d_in, const int* in_sizes, int n_in,
                              void* d_out, int out_size, void* d_ws, size_t ws_size,
                              hipStream_t stream)
{
  const float* x         = (const float*)d_in[0];
  const float* in_w      = (const float*)d_in[1];
  const float* in_b      = (const float*)d_in[2];
  const float* in_ln_g   = (const float*)d_in[3];
  const float* in_ln_b   = (const float*)d_in[4];
  const float* mb_ln_g   = (const float*)d_in[5];
  const float* mb_ln_b   = (const float*)d_in[6];
  const float* mb_in_w   = (const float*)d_in[7];
  const float* mb_conv_w = (const float*)d_in[8];
  const float* mb_conv_b = (const float*)d_in[9];
  const float* mb_xp_w   = (const float*)d_in[10];
  const float* mb_dt_w   = (const float*)d_in[11];
  const float* mb_dt_b   = (const float*)d_in[12];
  const float* mb_Alog   = (const float*)d_in[13];
  const float* mb_D      = (const float*)d_in[14];
  const float* mb_out_w  = (const float*)d_in[15];
  const float* sc_ln_g   = (const float*)d_in[16];
  const float* sc_ln_b   = (const float*)d_in[17];
  const float* sc_in_w   = (const float*)d_in[18];
  const float* sc_conv_w = (const float*)d_in[19];
  const float* sc_conv_b = (const float*)d_in[20];
  const float* sc_xp_w   = (const float*)d_in[21];
  const float* sc_dt_w   = (const float*)d_in[22];
  const float* sc_dt_b   = (const float*)d_in[23];
  const float* sc_Alog   = (const float*)d_in[24];
  const float* sc_D      = (const float*)d_in[25];
  const float* sc_out_w  = (const float*)d_in[26];
  const float* fus_qkv_w = (const float*)d_in[27];
  const float* fus_qkv_b = (const float*)d_in[28];
  const float* fus_out_w = (const float*)d_in[29];
  const float* fus_out_b = (const float*)d_in[30];
  const float* ms_out_w  = (const float*)d_in[31];
  const float* ms_out_b  = (const float*)d_in[32];
  const float* sa_ln1_g  = (const float*)d_in[33];
  const float* sa_ln1_b  = (const float*)d_in[34];
  const float* sa_ln2_g  = (const float*)d_in[35];
  const float* sa_ln2_b  = (const float*)d_in[36];
  const float* sa_qkv_w  = (const float*)d_in[37];
  const float* sa_qkv_b  = (const float*)d_in[38];
  const float* sa_out_w  = (const float*)d_in[39];
  const float* sa_out_b  = (const float*)d_in[40];
  const float* sa_ff1_w  = (const float*)d_in[41];
  const float* sa_ff1_b  = (const float*)d_in[42];
  const float* sa_ff2_w  = (const float*)d_in[43];
  const float* sa_ff2_b  = (const float*)d_in[44];
  const float* ev1_w     = (const float*)d_in[45];
  const float* ev1_b     = (const float*)d_in[46];
  const float* ev2_w     = (const float*)d_in[47];
  const float* ev2_b     = (const float*)d_in[48];
  const float* ttf1_w    = (const float*)d_in[49];
  const float* ttf1_b    = (const float*)d_in[50];
  const float* ttf2_w    = (const float*)d_in[51];
  const float* ttf2_b    = (const float*)d_in[52];
  const float* emb_w     = (const float*)d_in[53];
  const float* emb_b     = (const float*)d_in[54];

  float* ws = (float*)d_ws;
  float* h     = ws;                        // 1,048,576
  float* uu    = h    + 1048576;            // 2,097,152 (u half, fp32, stride 512)
  float* dtb_  = uu   + 2097152;            // 2,097,152
  float* xd    = dtb_ + 2097152;            // 196,608
  float* stack = xd   + 196608;             // 4,096
  float* hend   = stack + 4096;          // 524,288
  float* hstart = hend + 524288;         // 524,288
  float* sdtb   = hstart + 524288;       // 32,768
  float* yloc   = sdtb + 32768;          // 2,097,152
  float* Scum   = yloc + 2097152;        // 2,097,152
  float* Aneg   = Scum + 2097152;        // 8,192
  float* qkvF   = Aneg + 8192;   // 9216
  float* ovF    = qkvF + 9216;   // 3072
  float* moF    = ovF  + 3072;   // 3072
  float* fusedv = moF  + 3072;   // 1024
  float* lnbuf  = fusedv + 1024; // 3072
  float* qkvS   = lnbuf + 3072;  // 9216
  float* ovS    = qkvS + 9216;   // 3072
  float* s2     = ovS  + 3072;   // 3072
  float* ln2r   = s2   + 3072;   // 3072
  float* hid    = ln2r + 3072;   // 12288
  float* s2f    = hid  + 12288;  // 3072
  float* finalv = s2f  + 3072;   // 1024
  float* evh    = finalv + 1024; // 1024
  float* tth    = evh  + 1024;   // 512
  float* evraw  = tth  + 512;    // 32
  float* ttraw  = evraw + 32;    // 64
  float* fp32_end = ttraw + 64;
  unsigned short* bfb = (unsigned short*)fp32_end;
  unsigned short* xnb    = bfb;                  // 1,048,576
  unsigned short* ucb    = xnb + 1048576;        // 2,097,152
  unsigned short* zgb    = ucb + 2097152;        // 2,097,152 (z half, bf16)
  unsigned short* ygb    = zgb + 2097152;        // 2,097,152
  unsigned short* wmbin  = ygb + 2097152;        // 1,048,576
  unsigned short* wmbout = wmbin + 1048576;      // 524,288
  unsigned short* wmbxp  = wmbout + 524288;      // 98,304
  unsigned short* wscin  = wmbxp + 98304;        // 786,432
  unsigned short* wscout = wscin + 786432;       // 393,216
  unsigned short* wscxp  = wscout + 393216;      // 49,152

  k_f2b_all<<<2832, 256, 0, stream>>>(mb_in_w, wmbin, mb_out_w, wmbout, mb_xp_w, wmbxp,
                                      sc_in_w, wscin, sc_out_w, wscout, sc_xp_w, wscxp);

  k_inproj<<<4096, 256, 0, stream>>>(x, in_w, in_b, in_ln_g, in_ln_b, h);

  for (int l = 0; l < 4; l++){
    const float* Al = mb_Alog + l*8192;
    k_ln<<<4096, 256, 0, stream>>>(h, mb_ln_g + l*256, mb_ln_b + l*256, xnb);
    {
      dim3 g(16, 64);
      k_mm64<0,0><<<g, 256, 0, stream>>>(xnb, wmbin + l*262144, uu,
                                         nullptr, nullptr, zgb, 4096, 1024, 256, 0);
    }
    k_conv<<<4096, 256, 0, stream>>>(uu, mb_conv_w + l*2048, mb_conv_b + l*512, ucb);
    k_xpdt<3,0><<<256, 512, 0, stream>>>(ucb, wmbxp + l*24576, xd,
                                         mb_dt_w + l*8192, mb_dt_b + l*512, dtb_, 4096);
    {
      dim3 g(8, 4, 16);
      k_scan_p1y<<<g, 256, 0, stream>>>(dtb_, ucb, xd, Al, hend, sdtb, yloc, Scum);
      k_scomb<<<128, 256, 0, stream>>>(hend, sdtb, Al, hstart, Aneg);
      k_corr<<<4096, 256, 0, stream>>>(yloc, Scum, hstart, Aneg, xd, ucb, zgb,
                                       mb_D + l*512, ygb);
    }
    {
      dim3 g(4, 64);
      k_mm64<1,0><<<g, 256, 0, stream>>>(ygb, wmbout + l*131072, h,
                                         h, nullptr, nullptr, 4096, 256, 512, 0);
    }
  }

  // ---- scale mambas (batched), pooled -> stack ----
  k_ln_sc<<<460, 256, 0, stream>>>(h, sc_ln_g, sc_ln_b, xnb, stack);
  {
    dim3 g(16, 7);
    k_mm64<0,1><<<g, 256, 0, stream>>>(xnb, wscin, uu, nullptr, nullptr, zgb,
                                       448, 1024, 256, 262144);
  }
  k_conv_sc<<<448, 256, 0, stream>>>(uu, sc_conv_w, sc_conv_b, ucb);
  k_xpdt<2,1><<<28, 512, 0, stream>>>(ucb, wscxp, xd, sc_dt_w, sc_dt_b, dtb_, 448);
  {
    dim3 g(8, 4, 3);
    k_scan_sc<<<g, 64, 0, stream>>>(dtb_, ucb, zgb, xd, sc_Alog, sc_D, ygb);
  }
  {
    dim3 g(4, 7);
    k_mm64<2,1><<<g, 256, 0, stream>>>(ygb, wscout, nullptr, h, stack, nullptr,
                                       448, 256, 512, 131072);
  }

  // ---- tail (merged wide multi-kernel) ----
  float* dout = (float*)d_out;
  k_t_ln<<<12, 256, 0, stream>>>(stack, sa_ln1_g, sa_ln1_b, lnbuf);
  k_qkv2<<<384, 256, 0, stream>>>(stack, lnbuf, fus_qkv_w, fus_qkv_b,
                                  sa_qkv_w, sa_qkv_b, qkvF, qkvS);
  k_att2<<<8, 256, 0, stream>>>(qkvF, ovF, qkvS, ovS);
  k_out2<<<128, 256, 0, stream>>>(ovF, ovS, fus_out_w, fus_out_b,
                                  sa_out_w, sa_out_b, stack, moF, s2);
  k_tw<4,0,0><<<64, 256, 4*768*4, stream>>>(moF, ms_out_w, ms_out_b, fusedv, nullptr, 256, 768, 256, 0);
  k_t_ln<<<12, 256, 0, stream>>>(s2, sa_ln2_g, sa_ln2_b, ln2r);
  k_tw<12,1,0><<<256, 256, 12*256*4, stream>>>(ln2r, sa_ff1_w, sa_ff1_b, hid, nullptr, 1024, 256, 1024, 0);
  k_tw<12,0,1><<<64, 256, 12*1024*4, stream>>>(hid, sa_ff2_w, sa_ff2_b, s2f, s2, 256, 1024, 256, 0);
  k_t_final<<<4, 256, 0, stream>>>(fusedv, s2f, finalv);
  k_heads<<<128, 256, 0, stream>>>(finalv, ev1_w, ev1_b, evh, ttf1_w, ttf1_b, tth,
                                   emb_w, emb_b, dout);
  k_tw<4,0,0><<<2, 256, 4*256*4, stream>>>(evh, ev2_w, ev2_b, evraw, nullptr, 7, 256, 7, 0);
  k_tw<4,0,0><<<3, 256, 4*128*4, stream>>>(tth, ttf2_w, ttf2_b, ttraw, nullptr, 12, 128, 12, 0);
  k_t_fin<<<4, 64, 0, stream>>>(evraw, ttraw, dout);
}

// Round 17
// 607.994 us; speedup vs baseline: 1.3149x; 1.0209x over previous
//
#include <hip/hip_runtime.h>
#include <math.h>

// ---------------------------------------------------------------------------
// MambaPredictor forward. R16: LN fused into in-proj GEMM (k_lnmm) -- each
// block computes LN stats for its 64 rows (wave-per-row shfl reduce), stages
// the bf16 A-tile in LDS, then does the MFMA loop. Removes 4 k_ln launches +
// xnb round-trip on the main path. Everything else = R16 (passing, 621 us).
// B=4 L=1024 NF=64 DM=256 DS=16 SCS=8 NL=4 DI=512 DTR=16 DC=4 NFM=6 NH=4
// ---------------------------------------------------------------------------

typedef short short8v __attribute__((ext_vector_type(8)));
typedef float f32x4   __attribute__((ext_vector_type(4)));

__device__ __forceinline__ float geluf(float x){ return 0.5f*x*(1.0f + erff(x*0.70710678118654752f)); }
__device__ __forceinline__ float softplusf_(float x){ return (x > 20.f) ? x : log1pf(expf(x)); }
__device__ __forceinline__ unsigned short f2bf(float f){
  unsigned int u = __float_as_uint(f);
  unsigned int r = (u + 0x7FFFu + ((u >> 16) & 1u)) >> 16;
  return (unsigned short)r;
}
__device__ __forceinline__ float bf2f(unsigned short u){
  return __uint_as_float(((unsigned int)u) << 16);
}

__device__ __forceinline__ void sc_region(int r, int& z, int& roff, int& s){
  if (r < 64){ z=0; roff=0; s=5; }
  else if (r < 192){ z=1; roff=64; s=20; }
  else { z=2; roff=192; s=50; }
}

// ---------------- merged fp32 -> bf16 weight convert (6 segments) ----------
__global__ __launch_bounds__(256) void k_f2b_all(
    const float* s0, unsigned short* d0,
    const float* s1, unsigned short* d1,
    const float* s2, unsigned short* d2,
    const float* s3, unsigned short* d3,
    const float* s4, unsigned short* d4,
    const float* s5, unsigned short* d5)
{
  int blk = blockIdx.x;
  const float* s; unsigned short* d; int base;
  if      (blk < 1024){ s=s0; d=d0; base=0; }
  else if (blk < 1536){ s=s1; d=d1; base=1024; }
  else if (blk < 1632){ s=s2; d=d2; base=1536; }
  else if (blk < 2400){ s=s3; d=d3; base=1632; }
  else if (blk < 2784){ s=s4; d=d4; base=2400; }
  else                { s=s5; d=d5; base=2784; }
  int i = ((blk - base)*256 + threadIdx.x)*4;
  float4 v = *(const float4*)(s + i);
  *(ushort4*)(d + i) = make_ushort4(f2bf(v.x), f2bf(v.y), f2bf(v.z), f2bf(v.w));
}

// ---------------- initial: h = gelu(LN(x @ in_w^T + in_b)) -----------------
__global__ __launch_bounds__(256) void k_inproj(
    const float* __restrict__ x, const float* __restrict__ w,
    const float* __restrict__ b, const float* __restrict__ g,
    const float* __restrict__ beta, float* __restrict__ h)
{
  __shared__ float xr[64];
  __shared__ float r1[4], r2[4];
  int row = blockIdx.x;
  int tid = threadIdx.x;
  if (tid < 64) xr[tid] = x[row*64 + tid];
  __syncthreads();
  float acc = b[tid];
  const float* wr = w + tid*64;
  #pragma unroll
  for (int k = 0; k < 64; k++) acc += xr[k]*wr[k];
  float s1 = acc, s2 = acc*acc;
  #pragma unroll
  for (int o = 32; o > 0; o >>= 1){ s1 += __shfl_down(s1,o,64); s2 += __shfl_down(s2,o,64); }
  if ((tid & 63) == 0){ r1[tid>>6] = s1; r2[tid>>6] = s2; }
  __syncthreads();
  float S1 = r1[0]+r1[1]+r1[2]+r1[3];
  float S2 = r2[0]+r2[1]+r2[2]+r2[3];
  float m = S1*(1.f/256.f);
  float var = S2*(1.f/256.f) - m*m;
  float xn = (acc - m)*rsqrtf(var + 1e-5f)*g[tid] + beta[tid];
  h[row*256 + tid] = geluf(xn);
}

// ---------------- scale LN (grid 460: 448 LN rows + 12 stack-zero blocks) --
__global__ __launch_bounds__(256) void k_ln_sc(
    const float* __restrict__ h, const float* __restrict__ gb, const float* __restrict__ bb,
    unsigned short* __restrict__ dst, float* __restrict__ stack)
{
  __shared__ float r1[4], r2[4];
  int r = blockIdx.x, tid = threadIdx.x;
  if (r >= 448){
    int idx = (r - 448)*256 + tid;
    if (idx < 3072) stack[idx] = 0.f;
    return;
  }
  int z, roff, s; sc_region(r, z, roff, s);
  int local = r - roff;
  if (local >= 4*s) return;
  int b = local / s, t = local % s;
  float v = h[(b*1024 + (1024 - s) + t)*256 + tid];
  const float* g = gb + z*256; const float* be = bb + z*256;
  float s1 = v, s2 = v*v;
  #pragma unroll
  for (int o = 32; o > 0; o >>= 1){ s1 += __shfl_down(s1,o,64); s2 += __shfl_down(s2,o,64); }
  if ((tid & 63) == 0){ r1[tid>>6] = s1; r2[tid>>6] = s2; }
  __syncthreads();
  float S1 = r1[0]+r1[1]+r1[2]+r1[3];
  float S2 = r2[0]+r2[1]+r2[2]+r2[3];
  float m = S1*(1.f/256.f);
  float var = S2*(1.f/256.f) - m*m;
  dst[r*256 + tid] = f2bf((v - m)*rsqrtf(var + 1e-5f)*g[tid] + be[tid]);
}

// ---------------- fused LN + in-proj GEMM (main layers) --------------------
// grid (16,64), 256 thr. Phase A: wave-per-row LN of 64 rows of h -> bf16
// LDS tile (padded [64][264], 2-way bank alias). Phase B: MFMA, A from LDS,
// epilogue splits u (fp32, stride 512) / z (bf16).
__global__ __launch_bounds__(256) void k_lnmm(
    const float* __restrict__ h, const float* __restrict__ g, const float* __restrict__ be,
    const unsigned short* __restrict__ W,
    float* __restrict__ uu, unsigned short* __restrict__ zgb)
{
  __shared__ unsigned short sA[64][264];
  __shared__ float sg[256], sb[256];
  int tid = threadIdx.x;
  int wave = tid >> 6, lane = tid & 63;
  int m0 = blockIdx.y*64;
  int n0 = blockIdx.x*64 + (wave >> 1)*32;
  sg[tid] = g[tid]; sb[tid] = be[tid];
  __syncthreads();
  // Phase A: LN rows (wave w handles rows w, w+4, ...)
  #pragma unroll 4
  for (int i = 0; i < 16; i++){
    int r = wave + i*4;
    float4 v = *(const float4*)(h + (long)(m0 + r)*256 + lane*4);
    float s1 = v.x + v.y + v.z + v.w;
    float s2 = v.x*v.x + v.y*v.y + v.z*v.z + v.w*v.w;
    #pragma unroll
    for (int o = 32; o > 0; o >>= 1){ s1 += __shfl_down(s1,o,64); s2 += __shfl_down(s2,o,64); }
    s1 = __shfl(s1, 0, 64);
    s2 = __shfl(s2, 0, 64);
    float m = s1*(1.f/256.f);
    float rstd = rsqrtf(s2*(1.f/256.f) - m*m + 1e-5f);
    int c = lane*4;
    sA[r][c+0] = f2bf((v.x - m)*rstd*sg[c+0] + sb[c+0]);
    sA[r][c+1] = f2bf((v.y - m)*rstd*sg[c+1] + sb[c+1]);
    sA[r][c+2] = f2bf((v.z - m)*rstd*sg[c+2] + sb[c+2]);
    sA[r][c+3] = f2bf((v.w - m)*rstd*sg[c+3] + sb[c+3]);
  }
  __syncthreads();
  // Phase B: GEMM
  int mh = wave & 1;
  int mw0 = mh*32;
  int lrow = lane & 15, kc = lane >> 4;
  f32x4 acc[2][2] = {{{0.f,0.f,0.f,0.f},{0.f,0.f,0.f,0.f}},{{0.f,0.f,0.f,0.f},{0.f,0.f,0.f,0.f}}};
  for (int k0 = 0; k0 < 256; k0 += 32){
    short8v a[2], b2[2];
    #pragma unroll
    for (int mi = 0; mi < 2; mi++)
      a[mi] = *(const short8v*)&sA[mw0 + mi*16 + lrow][k0 + kc*8];
    #pragma unroll
    for (int ni = 0; ni < 2; ni++){
      int c = n0 + ni*16 + lrow;
      b2[ni] = *(const short8v*)(W + c*256 + k0 + kc*8);
    }
    #pragma unroll
    for (int mi = 0; mi < 2; mi++)
      #pragma unroll
      for (int ni = 0; ni < 2; ni++)
        acc[mi][ni] = __builtin_amdgcn_mfma_f32_16x16x32_bf16(a[mi], b2[ni], acc[mi][ni], 0, 0, 0);
  }
  int rb = kc*4;
  #pragma unroll
  for (int mi = 0; mi < 2; mi++){
    #pragma unroll
    for (int rr = 0; rr < 4; rr++){
      int grow = m0 + mw0 + mi*16 + rb + rr;
      #pragma unroll
      for (int ni = 0; ni < 2; ni++){
        int gcol = n0 + ni*16 + lrow;
        float v = acc[mi][ni][rr];
        if (gcol < 512) uu[(long)grow*512 + gcol] = v;
        else zgb[(long)grow*512 + (gcol - 512)] = f2bf(v);
      }
    }
  }
}

// ---------------- MFMA GEMM (out-proj / scale variants) --------------------
template<int MODE, int SCB>
__global__ __launch_bounds__(256) void k_mm64(
    const unsigned short* __restrict__ A, const unsigned short* __restrict__ Wb,
    float* __restrict__ C,
    const float* __restrict__ resid,
    float* __restrict__ pool_out,
    unsigned short* __restrict__ zgb,
    int M, int N, int K, int wstr)
{
  int tid = threadIdx.x;
  int wave = tid >> 6, lane = tid & 63;
  int mh = wave & 1, nh = wave >> 1;
  int m0 = blockIdx.y*64 + mh*32;
  int n0 = blockIdx.x*64 + nh*32;
  int z = 0, roff = 0, sc = 0;
  const unsigned short* W = Wb;
  if (SCB){ sc_region(blockIdx.y*64, z, roff, sc); W += z*wstr; }
  int lrow = lane & 15, kc = lane >> 4;
  f32x4 acc[2][2] = {{{0.f,0.f,0.f,0.f},{0.f,0.f,0.f,0.f}},{{0.f,0.f,0.f,0.f},{0.f,0.f,0.f,0.f}}};
  for (int k0 = 0; k0 < K; k0 += 32){
    short8v a[2], b[2];
    #pragma unroll
    for (int mi = 0; mi < 2; mi++){
      int r = m0 + mi*16 + lrow; r = min(r, M-1);
      a[mi] = *(const short8v*)(A + r*K + k0 + kc*8);
    }
    #pragma unroll
    for (int ni = 0; ni < 2; ni++){
      int c = n0 + ni*16 + lrow;
      b[ni] = *(const short8v*)(W + c*K + k0 + kc*8);
    }
    #pragma unroll
    for (int mi = 0; mi < 2; mi++)
      #pragma unroll
      for (int ni = 0; ni < 2; ni++)
        acc[mi][ni] = __builtin_amdgcn_mfma_f32_16x16x32_bf16(a[mi], b[ni], acc[mi][ni], 0, 0, 0);
  }
  int rb = kc*4;
  #pragma unroll
  for (int mi = 0; mi < 2; mi++){
    #pragma unroll
    for (int rr = 0; rr < 4; rr++){
      int grow = m0 + mi*16 + rb + rr;
      if (grow >= M) continue;
      #pragma unroll
      for (int ni = 0; ni < 2; ni++){
        int gcol = n0 + ni*16 + lrow;
        float v = acc[mi][ni][rr];
        if (MODE == 0){
          if (gcol < 512) C[(long)grow*512 + gcol] = v;
          else zgb[(long)grow*512 + (gcol - 512)] = f2bf(v);
        } else if (MODE == 1){
          C[grow*N + gcol] = resid[grow*256 + gcol] + v;
        } else {
          int local = grow - roff;
          if (local < 4*sc){
            int bb2 = local / sc, t = local % sc;
            float rv = resid[(bb2*1024 + (1024 - sc) + t)*256 + gcol] + v;
            atomicAdd(&pool_out[bb2*768 + z*256 + gcol], rv*(1.f/(float)sc));
          }
        }
      }
    }
  }
}

// ---------------- depthwise causal conv (DC=4) + SiLU -> bf16 only ---------
__global__ __launch_bounds__(256) void k_conv(
    const float* __restrict__ uu, const float* __restrict__ cw, const float* __restrict__ cb,
    unsigned short* __restrict__ ucb)
{
  int row = blockIdx.x;
  int t = row & 1023;
  int tid = threadIdx.x;
  for (int d = tid; d < 512; d += 256){
    float acc = cb[d];
    const float* w = cw + d*4;
    #pragma unroll
    for (int k = 0; k < 4; k++){
      int ts = t - 3 + k;
      if (ts >= 0) acc += uu[(long)(row - (3-k))*512 + d]*w[k];
    }
    float s = acc/(1.f + expf(-acc));
    ucb[(long)row*512 + d] = f2bf(s);
  }
}

__global__ __launch_bounds__(256) void k_conv_sc(
    const float* __restrict__ uu, const float* __restrict__ cwb, const float* __restrict__ cbb,
    unsigned short* __restrict__ ucb)
{
  int row = blockIdx.x;
  int z, roff, s; sc_region(row, z, roff, s);
  int local = row - roff;
  if (local >= 4*s) return;
  int t = local % s;
  const float* cw = cwb + z*2048;
  const float* cb = cbb + z*512;
  int tid = threadIdx.x;
  for (int d = tid; d < 512; d += 256){
    float acc = cb[d];
    const float* w = cw + d*4;
    #pragma unroll
    for (int k = 0; k < 4; k++){
      int ts = t - 3 + k;
      if (ts >= 0) acc += uu[(long)(row - (3-k))*512 + d]*w[k];
    }
    float sv = acc/(1.f + expf(-acc));
    ucb[(long)row*512 + d] = f2bf(sv);
  }
}

// ---- split-K wide xp GEMM + fused dt (8-wave, K=64 per wave) ---------------
template<int NT, int SCB>
__global__ __launch_bounds__(512) void k_xpdt(
    const unsigned short* __restrict__ A, const unsigned short* __restrict__ Wb,
    float* __restrict__ xdout,
    const float* __restrict__ dtwb, const float* __restrict__ dtbb,
    float* __restrict__ dtout, int M)
{
  const int K = 512;
  const int NC = NT*16;
  __shared__ float pacc[8][16][NC];
  __shared__ float sxd[16][16];
  int tid = threadIdx.x;
  int wave = tid >> 6, lane = tid & 63;
  int bm0 = blockIdx.x*16;
  const unsigned short* W = Wb;
  const float* dtw = dtwb;
  const float* dtb = dtbb;
  if (SCB){
    int z, roff, s; sc_region(bm0, z, roff, s);
    W += z*(NC*K); dtw += z*8192; dtb += z*512;
  }
  int lrow = lane & 15, kc = lane >> 4;
  int kbase = wave*64;
  f32x4 acc[NT];
  #pragma unroll
  for (int ni = 0; ni < NT; ni++) acc[ni] = (f32x4){0.f,0.f,0.f,0.f};
  #pragma unroll
  for (int k0 = 0; k0 < 64; k0 += 32){
    short8v a = *(const short8v*)(A + (long)(bm0 + lrow)*K + kbase + k0 + kc*8);
    #pragma unroll
    for (int ni = 0; ni < NT; ni++){
      short8v b = *(const short8v*)(W + (ni*16 + lrow)*K + kbase + k0 + kc*8);
      acc[ni] = __builtin_amdgcn_mfma_f32_16x16x32_bf16(a, b, acc[ni], 0, 0, 0);
    }
  }
  int rb = kc*4;
  #pragma unroll
  for (int rr = 0; rr < 4; rr++)
    #pragma unroll
    for (int ni = 0; ni < NT; ni++)
      pacc[wave][rb + rr][ni*16 + lrow] = acc[ni][rr];
  __syncthreads();
  for (int e = tid; e < 16*NC; e += 512){
    int r = e / NC, c = e % NC;
    float v = pacc[0][r][c] + pacc[1][r][c] + pacc[2][r][c] + pacc[3][r][c]
            + pacc[4][r][c] + pacc[5][r][c] + pacc[6][r][c] + pacc[7][r][c];
    xdout[(bm0 + r)*NC + c] = v;
    if (c < 16) sxd[r][c] = v;
  }
  __syncthreads();
  int d0 = tid;
  float w0[16];
  #pragma unroll
  for (int j = 0; j < 16; j++) w0[j] = dtw[d0*16 + j];
  float b0 = dtb[d0];
  #pragma unroll
  for (int r = 0; r < 16; r++){
    float a0 = b0;
    #pragma unroll
    for (int j = 0; j < 16; j++)
      a0 = fmaf(sxd[r][j], w0[j], a0);
    dtout[(bm0 + r)*512 + d0] = softplusf_(a0);
  }
}

// ============ chunked scan: p1 (256-thr staging, bf16 uc) + p2 + corr ======
__global__ __launch_bounds__(256) void k_scan_p1y(
    const float* __restrict__ dt, const unsigned short* __restrict__ ucb,
    const float* __restrict__ xd, const float* __restrict__ Alog,
    float* __restrict__ hend, float* __restrict__ sdtb,
    float* __restrict__ yloc, float* __restrict__ Scum)
{
  const int CL = 64, NCH = 16;
  __shared__ float sdt[64][64], suc[64][64];
  __shared__ float sBC[64][32];
  int tid = threadIdx.x;
  int dblk = blockIdx.x;
  int b = blockIdx.y, ch = blockIdx.z;
  int t0 = ch*CL;
  for (int e = tid; e < CL*16; e += 256){
    int t = e >> 4, q = (e & 15)*4;
    long off = (long)(b*1024 + t0 + t)*512 + dblk*64 + q;
    *(float4*)&sdt[t][q] = *(const float4*)(dt + off);
  }
  for (int e = tid; e < CL*8; e += 256){
    int t = e >> 3, q = (e & 7)*8;
    long off = (long)(b*1024 + t0 + t)*512 + dblk*64 + q;
    short8v u8 = *(const short8v*)(ucb + off);
    #pragma unroll
    for (int j = 0; j < 8; j++) suc[t][q + j] = bf2f((unsigned short)u8[j]);
  }
  for (int e = tid; e < CL*8; e += 256){
    int t = e >> 3, q = (e & 7)*4;
    *(float4*)&sBC[t][q] = *(const float4*)(xd + (long)(b*1024 + t0 + t)*48 + 16 + q);
  }
  __syncthreads();
  if (tid < 64){
    int d = dblk*64 + tid;
    float A[16];
    #pragma unroll
    for (int n = 0; n < 16; n++) A[n] = -__expf(Alog[d*16 + n]);
    float h[16];
    #pragma unroll
    for (int n = 0; n < 16; n++) h[n] = 0.f;
    float Ss = 0.f;
    #pragma unroll 2
    for (int t = 0; t < CL; t++){
      float dtv = sdt[t][tid];
      float uv  = suc[t][tid];
      Ss += dtv;
      float du = dtv*uv;
      float y = 0.f;
      #pragma unroll
      for (int n = 0; n < 16; n++){
        h[n] = fmaf(__expf(dtv*A[n]), h[n], du*sBC[t][n]);
        y = fmaf(h[n], sBC[t][16+n], y);
      }
      long row = (long)(b*1024 + t0 + t);
      yloc[row*512 + d] = y;
      Scum[row*512 + d] = Ss;
    }
    int base = ((b*NCH + ch)*512 + d)*16;
    #pragma unroll
    for (int q = 0; q < 4; q++)
      *(float4*)(hend + base + q*4) = make_float4(h[q*4], h[q*4+1], h[q*4+2], h[q*4+3]);
    sdtb[(b*NCH + ch)*512 + d] = Ss;
  }
}

__global__ __launch_bounds__(256) void k_scomb(
    const float* __restrict__ hend, const float* __restrict__ sdtb,
    const float* __restrict__ Alog, float* __restrict__ hstart,
    float* __restrict__ Aneg)
{
  const int NCH = 16;
  int idx = blockIdx.x*256 + threadIdx.x;
  int low = idx & 8191;
  int d = (idx >> 4) & 511, b = idx >> 13;
  float A = -__expf(Alog[low]);
  if (b == 0) Aneg[low] = A;
  float hs = 0.f;
  hstart[(b*NCH)*8192 + low] = 0.f;
  for (int c = 0; c < NCH-1; c++){
    float S  = sdtb[(b*NCH + c)*512 + d];
    float he = hend[(b*NCH + c)*8192 + low];
    hs = fmaf(__expf(A*S), hs, he);
    hstart[(b*NCH + c + 1)*8192 + low] = hs;
  }
}

__global__ __launch_bounds__(256) void k_corr(
    const float* __restrict__ yloc, const float* __restrict__ Scum,
    const float* __restrict__ hstart, const float* __restrict__ Aneg,
    const float* __restrict__ xd, const unsigned short* __restrict__ ucb,
    const unsigned short* __restrict__ zgb, const float* __restrict__ Dp,
    unsigned short* __restrict__ yg)
{
  __shared__ float sC[16];
  int row = blockIdx.x, tid = threadIdx.x;
  int b = row >> 10, t = row & 1023, ch = t >> 6;
  if (tid < 16) sC[tid] = xd[row*48 + 32 + tid];
  __syncthreads();
  #pragma unroll
  for (int rep = 0; rep < 2; rep++){
    int d = tid + rep*256;
    float Ss = Scum[row*512 + d];
    float y  = yloc[row*512 + d];
    const float* hs = hstart + ((b*16 + ch)*512 + d)*16;
    const float* An = Aneg + d*16;
    #pragma unroll
    for (int n = 0; n < 16; n++)
      y = fmaf(__expf(An[n]*Ss)*hs[n], sC[n], y);
    float uv = bf2f(ucb[(long)row*512 + d]);
    y = fmaf(uv, Dp[d], y);
    float zv = bf2f(zgb[(long)row*512 + d]);
    yg[row*512 + d] = f2bf(y*(zv/(1.f + __expf(-zv))));
  }
}

// ---------------- scale scan (DS=8, z-batched, bf16 u/z) -------------------
__global__ __launch_bounds__(64) void k_scan_sc(
    const float* __restrict__ dt, const unsigned short* __restrict__ ucb,
    const unsigned short* __restrict__ zgb, const float* __restrict__ xd,
    const float* __restrict__ Alogb, const float* __restrict__ Dpb,
    unsigned short* __restrict__ yg)
{
  __shared__ float sdt[52][64], suc[52][64], sz[52][64];
  __shared__ float sBC[52][16];
  int tid = threadIdx.x;
  int dblk = blockIdx.x;
  int d = dblk*64 + tid;
  int b = blockIdx.y, z = blockIdx.z;
  int s = (z==0) ? 5 : (z==1) ? 20 : 50;
  int roff = (z==0) ? 0 : (z==1) ? 64 : 192;
  const float* Alog = Alogb + z*4096;
  const float* Dp   = Dpb + z*512;
  float A[8];
  #pragma unroll
  for (int n = 0; n < 8; n++) A[n] = -__expf(Alog[d*8 + n]);
  float Dv = Dp[d];
  for (int e = tid; e < s*16; e += 64){
    int t = e >> 4, q = (e & 15)*4;
    long row = (long)(roff + b*s + t);
    *(float4*)&sdt[t][q] = *(const float4*)(dt + row*512 + dblk*64 + q);
  }
  for (int e = tid; e < s*8; e += 64){
    int t = e >> 3, q = (e & 7)*8;
    long row = (long)(roff + b*s + t);
    short8v u8 = *(const short8v*)(ucb + row*512 + dblk*64 + q);
    short8v z8 = *(const short8v*)(zgb + row*512 + dblk*64 + q);
    #pragma unroll
    for (int j = 0; j < 8; j++){
      suc[t][q + j] = bf2f((unsigned short)u8[j]);
      sz[t][q + j]  = bf2f((unsigned short)z8[j]);
    }
  }
  for (int e = tid; e < s*4; e += 64){
    int t = e >> 2, q = (e & 3)*4;
    long row = (long)(roff + b*s + t);
    *(float4*)&sBC[t][q] = *(const float4*)(xd + row*32 + 16 + q);
  }
  __syncthreads();
  float h[8];
  #pragma unroll
  for (int n = 0; n < 8; n++) h[n] = 0.f;
  for (int t = 0; t < s; t++){
    float dtv = sdt[t][tid];
    float uv  = suc[t][tid];
    float zv  = sz[t][tid];
    float du = dtv*uv;
    float y = 0.f;
    #pragma unroll
    for (int n = 0; n < 8; n++){
      h[n] = fmaf(__expf(dtv*A[n]), h[n], du*sBC[t][n]);
      y = fmaf(h[n], sBC[t][8+n], y);
    }
    y = fmaf(uv, Dv, y);
    float gate = zv/(1.f + __expf(-zv));
    yg[(long)(roff + b*s + t)*512 + d] = f2bf(y*gate);
  }
}

// ================== tail kernels ==========================================
template<int M, int ACT, int RES>
__global__ __launch_bounds__(256) void k_tw(
    const float* __restrict__ A, const float* __restrict__ W,
    const float* __restrict__ bias, float* __restrict__ out,
    const float* __restrict__ resid, int N, int K, int ostride, int ocoff)
{
  extern __shared__ float sx[];
  int tid = threadIdx.x;
  for (int e = tid*4; e < M*K; e += 1024)
    *(float4*)&sx[e] = *(const float4*)(A + e);
  __syncthreads();
  int wave = tid >> 6, lane = tid & 63;
  int c = blockIdx.x*4 + wave;
  if (c >= N) return;
  float acc[M];
  #pragma unroll
  for (int r = 0; r < M; r++) acc[r] = 0.f;
  for (int k = lane*4; k < K; k += 256){
    float4 w4 = *(const float4*)(W + c*K + k);
    #pragma unroll
    for (int r = 0; r < M; r++){
      float4 x4 = *(float4*)&sx[r*K + k];
      acc[r] = fmaf(x4.x,w4.x,fmaf(x4.y,w4.y,fmaf(x4.z,w4.z,fmaf(x4.w,w4.w,acc[r]))));
    }
  }
  #pragma unroll
  for (int r = 0; r < M; r++){
    #pragma unroll
    for (int o = 32; o > 0; o >>= 1) acc[r] += __shfl_down(acc[r], o, 64);
  }
  if (lane == 0){
    float bv = bias[c];
    #pragma unroll
    for (int r = 0; r < M; r++){
      float v = acc[r] + bv;
      if (ACT == 1) v = geluf(v);
      if (RES == 1) v += resid[r*256 + c];
      out[r*ostride + ocoff + c] = v;
    }
  }
}

// merged QKV: blocks 0-191 fus (stack), 192-383 sa (lnbuf)
__global__ __launch_bounds__(256) void k_qkv2(
    const float* __restrict__ A0, const float* __restrict__ A1,
    const float* __restrict__ W0, const float* __restrict__ B0,
    const float* __restrict__ W1, const float* __restrict__ B1,
    float* __restrict__ O0, float* __restrict__ O1)
{
  __shared__ float sx[3072];
  int tid = threadIdx.x;
  int sel = blockIdx.x >= 192;
  const float* A = sel ? A1 : A0;
  for (int e = tid*4; e < 3072; e += 1024)
    *(float4*)&sx[e] = *(const float4*)(A + e);
  __syncthreads();
  int wave = tid >> 6, lane = tid & 63;
  int c = (blockIdx.x - (sel ? 192 : 0))*4 + wave;
  const float* W = sel ? W1 : W0;
  const float* B = sel ? B1 : B0;
  float* O = sel ? O1 : O0;
  float acc[12];
  #pragma unroll
  for (int r = 0; r < 12; r++) acc[r] = 0.f;
  {
    int k = lane*4;
    float4 w4 = *(const float4*)(W + c*256 + k);
    #pragma unroll
    for (int r = 0; r < 12; r++){
      float4 x4 = *(float4*)&sx[r*256 + k];
      acc[r] = fmaf(x4.x,w4.x,fmaf(x4.y,w4.y,fmaf(x4.z,w4.z,fmaf(x4.w,w4.w,acc[r]))));
    }
  }
  #pragma unroll
  for (int r = 0; r < 12; r++){
    #pragma unroll
    for (int o = 32; o > 0; o >>= 1) acc[r] += __shfl_down(acc[r], o, 64);
  }
  if (lane == 0){
    float bv = B[c];
    #pragma unroll
    for (int r = 0; r < 12; r++) O[r*768 + c] = acc[r] + bv;
  }
}

// merged attention: 8 blocks = {fus,sa} x 4 batches
__global__ __launch_bounds__(256) void k_att2(
    const float* __restrict__ qkvF, float* __restrict__ ovF,
    const float* __restrict__ qkvS, float* __restrict__ ovS)
{
  __shared__ float att[36];
  int sel = blockIdx.x >> 2, b = blockIdx.x & 3, tid = threadIdx.x;
  const float* qkv = sel ? qkvS : qkvF;
  float* ov = sel ? ovS : ovF;
  if (tid < 36){
    int hh = tid/9, r = (tid%9)/3, c = tid%3;
    float s = 0.f;
    const float* qp = qkv + (b*3 + r)*768 + hh*64;
    const float* kp = qkv + (b*3 + c)*768 + 256 + hh*64;
    for (int k = 0; k < 64; k++) s += qp[k]*kp[k];
    att[hh*9 + r*3 + c] = s*0.125f;
  }
  __syncthreads();
  if (tid < 12){
    int hh = tid/3, r = tid%3;
    float a0 = att[hh*9+r*3+0], a1 = att[hh*9+r*3+1], a2 = att[hh*9+r*3+2];
    float m = fmaxf(a0, fmaxf(a1, a2));
    float e0 = expf(a0-m), e1 = expf(a1-m), e2 = expf(a2-m);
    float s = e0+e1+e2;
    att[hh*9+r*3+0] = e0/s; att[hh*9+r*3+1] = e1/s; att[hh*9+r*3+2] = e2/s;
  }
  __syncthreads();
  for (int e = tid; e < 768; e += 256){
    int p = e >> 8, i = e & 255, hh = i >> 6;
    ov[(b*3 + p)*256 + i] = att[hh*9+p*3+0]*qkv[(b*3+0)*768+512+i]
                          + att[hh*9+p*3+1]*qkv[(b*3+1)*768+512+i]
                          + att[hh*9+p*3+2]*qkv[(b*3+2)*768+512+i];
  }
}

// merged out-proj: blocks 0-63 fus (moF), 64-127 sa (+stack resid -> s2)
__global__ __launch_bounds__(256) void k_out2(
    const float* __restrict__ ovF, const float* __restrict__ ovS,
    const float* __restrict__ fow, const float* __restrict__ fob,
    const float* __restrict__ sow, const float* __restrict__ sob,
    const float* __restrict__ stack, float* __restrict__ moF, float* __restrict__ s2)
{
  __shared__ float sx[3072];
  int tid = threadIdx.x;
  int sel = blockIdx.x >= 64;
  const float* A = sel ? ovS : ovF;
  for (int e = tid*4; e < 3072; e += 1024)
    *(float4*)&sx[e] = *(const float4*)(A + e);
  __syncthreads();
  int wave = tid >> 6, lane = tid & 63;
  int c = (blockIdx.x - (sel ? 64 : 0))*4 + wave;
  const float* W = sel ? sow : fow;
  const float* B = sel ? sob : fob;
  float acc[12];
  #pragma unroll
  for (int r = 0; r < 12; r++) acc[r] = 0.f;
  {
    int k = lane*4;
    float4 w4 = *(const float4*)(W + c*256 + k);
    #pragma unroll
    for (int r = 0; r < 12; r++){
      float4 x4 = *(float4*)&sx[r*256 + k];
      acc[r] = fmaf(x4.x,w4.x,fmaf(x4.y,w4.y,fmaf(x4.z,w4.z,fmaf(x4.w,w4.w,acc[r]))));
    }
  }
  #pragma unroll
  for (int r = 0; r < 12; r++){
    #pragma unroll
    for (int o = 32; o > 0; o >>= 1) acc[r] += __shfl_down(acc[r], o, 64);
  }
  if (lane == 0){
    float bv = B[c];
    #pragma unroll
    for (int r = 0; r < 12; r++){
      float v = acc[r] + bv;
      if (sel) s2[r*256 + c] = v + stack[r*256 + c];
      else     moF[r*256 + c] = v;
    }
  }
}

// merged heads: 0-63 ev1(gelu,256), 64-95 ttf1(gelu,128), 96-127 emb(128)
__global__ __launch_bounds__(256) void k_heads(
    const float* __restrict__ finalv,
    const float* __restrict__ e1w, const float* __restrict__ e1b, float* __restrict__ evh,
    const float* __restrict__ t1w, const float* __restrict__ t1b, float* __restrict__ tth,
    const float* __restrict__ ew, const float* __restrict__ eb, float* __restrict__ dout)
{
  __shared__ float sx[1024];
  int tid = threadIdx.x;
  if (tid < 256){
    float4 v = *(const float4*)(finalv + tid*4);
    *(float4*)&sx[tid*4] = v;
  }
  __syncthreads();
  int wave = tid >> 6, lane = tid & 63;
  int blk = blockIdx.x;
  const float* W; const float* B; int c; int which;
  if (blk < 64){ which = 0; c = blk*4 + wave; W = e1w; B = e1b; }
  else if (blk < 96){ which = 1; c = (blk - 64)*4 + wave; W = t1w; B = t1b; }
  else { which = 2; c = (blk - 96)*4 + wave; W = ew; B = eb; }
  float acc[4] = {0.f,0.f,0.f,0.f};
  {
    int k = lane*4;
    float4 w4 = *(const float4*)(W + c*256 + k);
    #pragma unroll
    for (int r = 0; r < 4; r++){
      float4 x4 = *(float4*)&sx[r*256 + k];
      acc[r] = fmaf(x4.x,w4.x,fmaf(x4.y,w4.y,fmaf(x4.z,w4.z,fmaf(x4.w,w4.w,acc[r]))));
    }
  }
  #pragma unroll
  for (int r = 0; r < 4; r++){
    #pragma unroll
    for (int o = 32; o > 0; o >>= 1) acc[r] += __shfl_down(acc[r], o, 64);
  }
  if (lane == 0){
    float bv = B[c];
    #pragma unroll
    for (int r = 0; r < 4; r++){
      float v = acc[r] + bv;
      if (which == 0) evh[r*256 + c] = geluf(v);
      else if (which == 1) tth[r*128 + c] = geluf(v);
      else dout[r*162 + 34 + c] = v;
    }
  }
}

__global__ __launch_bounds__(256) void k_t_ln(
    const float* __restrict__ src, const float* __restrict__ g, const float* __restrict__ b,
    float* __restrict__ dst)
{
  __shared__ float r1[4], r2[4];
  int r = blockIdx.x, tid = threadIdx.x;
  float v = src[r*256 + tid];
  float s1 = v, s2 = v*v;
  #pragma unroll
  for (int o = 32; o > 0; o >>= 1){ s1 += __shfl_down(s1,o,64); s2 += __shfl_down(s2,o,64); }
  if ((tid & 63) == 0){ r1[tid>>6] = s1; r2[tid>>6] = s2; }
  __syncthreads();
  float S1 = r1[0]+r1[1]+r1[2]+r1[3];
  float S2 = r2[0]+r2[1]+r2[2]+r2[3];
  float m = S1*(1.f/256.f);
  float var = S2*(1.f/256.f) - m*m;
  dst[r*256 + tid] = (v - m)*rsqrtf(var + 1e-5f)*g[tid] + b[tid];
}

__global__ __launch_bounds__(256) void k_t_final(
    const float* __restrict__ fusedv, const float* __restrict__ s2f, float* __restrict__ finalv)
{
  int b = blockIdx.x, c = threadIdx.x;
  finalv[b*256 + c] = fusedv[b*256 + c] +
    (s2f[(b*3+0)*256 + c] + s2f[(b*3+1)*256 + c] + s2f[(b*3+2)*256 + c])*(1.f/3.f);
}

__global__ __launch_bounds__(64) void k_t_fin(
    const float* __restrict__ evraw, const float* __restrict__ ttraw, float* __restrict__ out)
{
  __shared__ float ev[7];
  __shared__ float S;
  int b = blockIdx.x, tid = threadIdx.x;
  if (tid < 7) ev[tid] = softplusf_(evraw[b*7 + tid]);
  __syncthreads();
  if (tid == 0){
    float s = 0.f;
    for (int j = 0; j < 7; j++) s += ev[j] + 1.f;
    S = s;
  }
  __syncthreads();
  float* ob = out + b*162;
  if (tid < 7){
    float al = ev[tid] + 1.f;
    ob[tid] = al / S;
    ob[7 + tid] = ev[tid];
    ob[14 + tid] = al;
  }
  if (tid == 0) ob[21] = 7.f / S;
  if (tid < 6){
    ob[22 + tid] = softplusf_(ttraw[b*12 + tid]);
    ob[28 + tid] = expf(0.5f*ttraw[b*12 + 6 + tid]);
  }
}

// ---------------------------------------------------------------------------
extern "C" void kernel_launch(void* const* d_in, const int* in_sizes, int n_in,
                              void* d_out, int out_size, void* d_ws, size_t ws_size,
                              hipStream_t stream)
{
  const float* x         = (const float*)d_in[0];
  const float* in_w      = (const float*)d_in[1];
  const float* in_b      = (const float*)d_in[2];
  const float* in_ln_g   = (const float*)d_in[3];
  const float* in_ln_b   = (const float*)d_in[4];
  const float* mb_ln_g   = (const float*)d_in[5];
  const float* mb_ln_b   = (const float*)d_in[6];
  const float* mb_in_w   = (const float*)d_in[7];
  const float* mb_conv_w = (const float*)d_in[8];
  const float* mb_conv_b = (const float*)d_in[9];
  const float* mb_xp_w   = (const float*)d_in[10];
  const float* mb_dt_w   = (const float*)d_in[11];
  const float* mb_dt_b   = (const float*)d_in[12];
  const float* mb_Alog   = (const float*)d_in[13];
  const float* mb_D      = (const float*)d_in[14];
  const float* mb_out_w  = (const float*)d_in[15];
  const float* sc_ln_g   = (const float*)d_in[16];
  const float* sc_ln_b   = (const float*)d_in[17];
  const float* sc_in_w   = (const float*)d_in[18];
  const float* sc_conv_w = (const float*)d_in[19];
  const float* sc_conv_b = (const float*)d_in[20];
  const float* sc_xp_w   = (const float*)d_in[21];
  const float* sc_dt_w   = (const float*)d_in[22];
  const float* sc_dt_b   = (const float*)d_in[23];
  const float* sc_Alog   = (const float*)d_in[24];
  const float* sc_D      = (const float*)d_in[25];
  const float* sc_out_w  = (const float*)d_in[26];
  const float* fus_qkv_w = (const float*)d_in[27];
  const float* fus_qkv_b = (const float*)d_in[28];
  const float* fus_out_w = (const float*)d_in[29];
  const float* fus_out_b = (const float*)d_in[30];
  const float* ms_out_w  = (const float*)d_in[31];
  const float* ms_out_b  = (const float*)d_in[32];
  const float* sa_ln1_g  = (const float*)d_in[33];
  const float* sa_ln1_b  = (const float*)d_in[34];
  const float* sa_ln2_g  = (const float*)d_in[35];
  const float* sa_ln2_b  = (const float*)d_in[36];
  const float* sa_qkv_w  = (const float*)d_in[37];
  const float* sa_qkv_b  = (const float*)d_in[38];
  const float* sa_out_w  = (const float*)d_in[39];
  const float* sa_out_b  = (const float*)d_in[40];
  const float* sa_ff1_w  = (const float*)d_in[41];
  const float* sa_ff1_b  = (const float*)d_in[42];
  const float* sa_ff2_w  = (const float*)d_in[43];
  const float* sa_ff2_b  = (const float*)d_in[44];
  const float* ev1_w     = (const float*)d_in[45];
  const float* ev1_b     = (const float*)d_in[46];
  const float* ev2_w     = (const float*)d_in[47];
  const float* ev2_b     = (const float*)d_in[48];
  const float* ttf1_w    = (const float*)d_in[49];
  const float* ttf1_b    = (const float*)d_in[50];
  const float* ttf2_w    = (const float*)d_in[51];
  const float* ttf2_b    = (const float*)d_in[52];
  const float* emb_w     = (const float*)d_in[53];
  const float* emb_b     = (const float*)d_in[54];

  float* ws = (float*)d_ws;
  float* h     = ws;                        // 1,048,576
  float* uu    = h    + 1048576;            // 2,097,152
  float* dtb_  = uu   + 2097152;            // 2,097,152
  float* xd    = dtb_ + 2097152;            // 196,608
  float* stack = xd   + 196608;             // 4,096
  float* hend   = stack + 4096;          // 524,288
  float* hstart = hend + 524288;         // 524,288
  float* sdtb   = hstart + 524288;       // 32,768
  float* yloc   = sdtb + 32768;          // 2,097,152
  float* Scum   = yloc + 2097152;        // 2,097,152
  float* Aneg   = Scum + 2097152;        // 8,192
  float* qkvF   = Aneg + 8192;   // 9216
  float* ovF    = qkvF + 9216;   // 3072
  float* moF    = ovF  + 3072;   // 3072
  float* fusedv = moF  + 3072;   // 1024
  float* lnbuf  = fusedv + 1024; // 3072
  float* qkvS   = lnbuf + 3072;  // 9216
  float* ovS    = qkvS + 9216;   // 3072
  float* s2     = ovS  + 3072;   // 3072
  float* ln2r   = s2   + 3072;   // 3072
  float* hid    = ln2r + 3072;   // 12288
  float* s2f    = hid  + 12288;  // 3072
  float* finalv = s2f  + 3072;   // 1024
  float* evh    = finalv + 1024; // 1024
  float* tth    = evh  + 1024;   // 512
  float* evraw  = tth  + 512;    // 32
  float* ttraw  = evraw + 32;    // 64
  float* fp32_end = ttraw + 64;
  unsigned short* bfb = (unsigned short*)fp32_end;
  unsigned short* xnb    = bfb;                  // 1,048,576 (scale path only)
  unsigned short* ucb    = xnb + 1048576;        // 2,097,152
  unsigned short* zgb    = ucb + 2097152;        // 2,097,152
  unsigned short* ygb    = zgb + 2097152;        // 2,097,152
  unsigned short* wmbin  = ygb + 2097152;        // 1,048,576
  unsigned short* wmbout = wmbin + 1048576;      // 524,288
  unsigned short* wmbxp  = wmbout + 524288;      // 98,304
  unsigned short* wscin  = wmbxp + 98304;        // 786,432
  unsigned short* wscout = wscin + 786432;       // 393,216
  unsigned short* wscxp  = wscout + 393216;      // 49,152

  k_f2b_all<<<2832, 256, 0, stream>>>(mb_in_w, wmbin, mb_out_w, wmbout, mb_xp_w, wmbxp,
                                      sc_in_w, wscin, sc_out_w, wscout, sc_xp_w, wscxp);

  k_inproj<<<4096, 256, 0, stream>>>(x, in_w, in_b, in_ln_g, in_ln_b, h);

  for (int l = 0; l < 4; l++){
    const float* Al = mb_Alog + l*8192;
    {
      dim3 g(16, 64);
      k_lnmm<<<g, 256, 0, stream>>>(h, mb_ln_g + l*256, mb_ln_b + l*256,
                                    wmbin + l*262144, uu, zgb);
    }
    k_conv<<<4096, 256, 0, stream>>>(uu, mb_conv_w + l*2048, mb_conv_b + l*512, ucb);
    k_xpdt<3,0><<<256, 512, 0, stream>>>(ucb, wmbxp + l*24576, xd,
                                         mb_dt_w + l*8192, mb_dt_b + l*512, dtb_, 4096);
    {
      dim3 g(8, 4, 16);
      k_scan_p1y<<<g, 256, 0, stream>>>(dtb_, ucb, xd, Al, hend, sdtb, yloc, Scum);
      k_scomb<<<128, 256, 0, stream>>>(hend, sdtb, Al, hstart, Aneg);
      k_corr<<<4096, 256, 0, stream>>>(yloc, Scum, hstart, Aneg, xd, ucb, zgb,
                                       mb_D + l*512, ygb);
    }
    {
      dim3 g(4, 64);
      k_mm64<1,0><<<g, 256, 0, stream>>>(ygb, wmbout + l*131072, h,
                                         h, nullptr, nullptr, 4096, 256, 512, 0);
    }
  }

  // ---- scale mambas (batched), pooled -> stack ----
  k_ln_sc<<<460, 256, 0, stream>>>(h, sc_ln_g, sc_ln_b, xnb, stack);
  {
    dim3 g(16, 7);
    k_mm64<0,1><<<g, 256, 0, stream>>>(xnb, wscin, uu, nullptr, nullptr, zgb,
                                       448, 1024, 256, 262144);
  }
  k_conv_sc<<<448, 256, 0, stream>>>(uu, sc_conv_w, sc_conv_b, ucb);
  k_xpdt<2,1><<<28, 512, 0, stream>>>(ucb, wscxp, xd, sc_dt_w, sc_dt_b, dtb_, 448);
  {
    dim3 g(8, 4, 3);
    k_scan_sc<<<g, 64, 0, stream>>>(dtb_, ucb, zgb, xd, sc_Alog, sc_D, ygb);
  }
  {
    dim3 g(4, 7);
    k_mm64<2,1><<<g, 256, 0, stream>>>(ygb, wscout, nullptr, h, stack, nullptr,
                                       448, 256, 512, 131072);
  }

  // ---- tail (merged wide multi-kernel) ----
  float* dout = (float*)d_out;
  k_t_ln<<<12, 256, 0, stream>>>(stack, sa_ln1_g, sa_ln1_b, lnbuf);
  k_qkv2<<<384, 256, 0, stream>>>(stack, lnbuf, fus_qkv_w, fus_qkv_b,
                                  sa_qkv_w, sa_qkv_b, qkvF, qkvS);
  k_att2<<<8, 256, 0, stream>>>(qkvF, ovF, qkvS, ovS);
  k_out2<<<128, 256, 0, stream>>>(ovF, ovS, fus_out_w, fus_out_b,
                                  sa_out_w, sa_out_b, stack, moF, s2);
  k_tw<4,0,0><<<64, 256, 4*768*4, stream>>>(moF, ms_out_w, ms_out_b, fusedv, nullptr, 256, 768, 256, 0);
  k_t_ln<<<12, 256, 0, stream>>>(s2, sa_ln2_g, sa_ln2_b, ln2r);
  k_tw<12,1,0><<<256, 256, 12*256*4, stream>>>(ln2r, sa_ff1_w, sa_ff1_b, hid, nullptr, 1024, 256, 1024, 0);
  k_tw<12,0,1><<<64, 256, 12*1024*4, stream>>>(hid, sa_ff2_w, sa_ff2_b, s2f, s2, 256, 1024, 256, 0);
  k_t_final<<<4, 256, 0, stream>>>(fusedv, s2f, finalv);
  k_heads<<<128, 256, 0, stream>>>(finalv, ev1_w, ev1_b, evh, ttf1_w, ttf1_b, tth,
                                   emb_w, emb_b, dout);
  k_tw<4,0,0><<<2, 256, 4*256*4, stream>>>(evh, ev2_w, ev2_b, evraw, nullptr, 7, 256, 7, 0);
  k_tw<4,0,0><<<3, 256, 4*128*4, stream>>>(tth, ttf2_w, ttf2_b, ttraw, nullptr, 12, 128, 12, 0);
  k_t_fin<<<4, 64, 0, stream>>>(evraw, ttraw, dout);
}